// Round 7
// baseline (361.666 us; speedup 1.0000x reference)
//
#include <hip/hip_runtime.h>
#include <cstdint>
#include <cstddef>

#define B_DIM  16
#define S_BANK 8192
#define S_REF  32
#define S_TOT  8224   // S_BANK + S_REF
#define NMERGE 32     // S_TOT - MAX_SLOTS
#define D      512
#define NCH    129    // ceil(S_TOT / 64)
#define MREP   3      // INSTRUMENTATION: serial in-kernel reps to surface counters

typedef float vfloat4 __attribute__((ext_vector_type(4)));  // NT-store capable

// Raw workgroup barrier draining ONLY LDS (lgkmcnt), not vmcnt.
__device__ __forceinline__ void wg_barrier_lds() {
    asm volatile("s_waitcnt lgkmcnt(0)" ::: "memory");
    __builtin_amdgcn_s_barrier();
}

// ---------------- DPP wave64 reductions (VALU pipe, no ds_bpermute) ----------
__device__ __forceinline__ int d_lo(double d){ union{double d; int i[2];}u; u.d=d; return u.i[0]; }
__device__ __forceinline__ int d_hi(double d){ union{double d; int i[2];}u; u.d=d; return u.i[1]; }
__device__ __forceinline__ double d_mk(int hi,int lo){ union{double d; int i[2];}u; u.i[0]=lo;u.i[1]=hi; return u.d; }

template<int CTRL>
__device__ __forceinline__ void lex_level(double& v, int& j) {
    int lo2 = __builtin_amdgcn_update_dpp(d_lo(v), d_lo(v), CTRL, 0xF, 0xF, false);
    int hi2 = __builtin_amdgcn_update_dpp(d_hi(v), d_hi(v), CTRL, 0xF, 0xF, false);
    int j2  = __builtin_amdgcn_update_dpp(j,       j,       CTRL, 0xF, 0xF, false);
    double v2 = d_mk(hi2, lo2);
    if (v2 < v || (v2 == v && j2 < j)) { v = v2; j = j2; }
}
__device__ __forceinline__ void lexmin_wave(double& v, int& j) {
    lex_level<0x111>(v, j);
    lex_level<0x112>(v, j);
    lex_level<0x114>(v, j);
    lex_level<0x118>(v, j);
    lex_level<0x142>(v, j);
    lex_level<0x143>(v, j);
    int lo = __builtin_amdgcn_readlane(d_lo(v), 63);
    int hi = __builtin_amdgcn_readlane(d_hi(v), 63);
    j      = __builtin_amdgcn_readlane(j, 63);
    v = d_mk(hi, lo);
}
template<int CTRL>
__device__ __forceinline__ void sum_level(double& v) {
    int lo2 = __builtin_amdgcn_update_dpp(0, d_lo(v), CTRL, 0xF, 0xF, true);
    int hi2 = __builtin_amdgcn_update_dpp(0, d_hi(v), CTRL, 0xF, 0xF, true);
    v += d_mk(hi2, lo2);
}
__device__ __forceinline__ double sum_wave(double v) {
    sum_level<0x111>(v); sum_level<0x112>(v); sum_level<0x114>(v);
    sum_level<0x118>(v); sum_level<0x142>(v); sum_level<0x143>(v);
    int lo = __builtin_amdgcn_readlane(d_lo(v), 63);
    int hi = __builtin_amdgcn_readlane(d_hi(v), 63);
    return d_mk(hi, lo);
}

// ---------------- Kernel 1: per-slot L2 norms (f64), reverse order -----------
__global__ __launch_bounds__(256) void norms_kernel(const float* __restrict__ bank,
                                                    const float* __restrict__ refresh,
                                                    double* __restrict__ norms) {
    int gw_lin = (int)((blockIdx.x * 256 + threadIdx.x) >> 6);
    int gw   = B_DIM * S_TOT - 1 - gw_lin;
    int lane = threadIdx.x & 63;
    int b = gw / S_TOT;
    int s = gw - b * S_TOT;
    const float4* src = (const float4*)(s < S_BANK
        ? bank    + ((size_t)b * S_BANK + s) * D
        : refresh + ((size_t)b * S_REF + (s - S_BANK)) * D);
    float4 f0 = src[lane];
    float4 f1 = src[lane + 64];
    double acc = 0.0;
    acc += (double)f0.x * f0.x + (double)f0.y * f0.y + (double)f0.z * f0.z + (double)f0.w * f0.w;
    acc += (double)f1.x * f1.x + (double)f1.y * f1.y + (double)f1.z * f1.z + (double)f1.w * f1.w;
    acc = sum_wave(acc);
    if (lane == 0) norms[gw] = sqrt(acc);
}

// ---------------- Kernel 2: merge-v9 x MREP (instrumented) -------------------
__device__ __forceinline__ const float* slot_gptr(int id, int b,
        const float* bank, const float* refresh) {
    return (id < S_BANK) ? bank    + ((size_t)b * S_BANK + id) * D
                         : refresh + ((size_t)b * S_REF + (id - S_BANK)) * D;
}

__global__ __launch_bounds__(256) void merge_kernel(const float* __restrict__ bank,
        const float* __restrict__ refresh, const double* __restrict__ norms,
        float* __restrict__ merged, unsigned short* __restrict__ idx_out) {
    __shared__ double         s_imp[S_TOT];      // >=1e300 == dead
    __shared__ unsigned short s_next[S_TOT];     // reused as id-LUT later
    __shared__ float          s_mvec[NMERGE][D]; // merged vectors
    __shared__ unsigned short s_mpos[NMERGE];
    __shared__ unsigned short s_dead[NMERGE];
    __shared__ double c_val[NCH];
    __shared__ int    c_idx[NCH];

    const int t    = threadIdx.x;
    const int b    = blockIdx.x;
    const int lane = t & 63;
    const int wid  = t >> 6;     // 4 waves
    const double INF = __builtin_inf();

    // INSTRUMENTATION: repeat the entire merge computation serially. Each rep
    // fully re-initializes LDS state and deterministically rewrites the same
    // merged/idx_out values => output identical to MREP==1 run.
    #pragma unroll 1
    for (int rep = 0; rep < MREP; ++rep) {

    int mpos_reg = -1;           // lane l: position of merge result l (register copy)

    int prev_p = -1, prev_pv = -1, prev_nk = -1;
    int pvok = 0, nkok = 0;
    float4 mm0, mm1;
    float4 pva0, pva1;
    float4 pnk0, pnk1;

    for (int j = t; j < S_TOT; j += 256) {
        s_imp[j]  = norms[b * S_TOT + j];
        s_next[j] = (unsigned short)((j + 1 < S_TOT) ? (j + 1) : 0xFFFF);
    }
    __syncthreads();

    if (t < NCH) {
        int j0 = t * 64;
        int jend = (j0 + 63 < S_TOT - 1) ? (j0 + 63) : (S_TOT - 2);
        double best = INF; int bj = 0x7FFFFFFF;
        for (int j = j0; j <= jend; ++j) {
            double sc = s_imp[j] + s_imp[j + 1];
            if (sc < best) { best = sc; bj = j; }
        }
        c_val[t] = best; c_idx[t] = bj;
    }
    __syncthreads();

    for (int step = 0; step < NMERGE; ++step) {
        // ======== phase A ====================================================
        double v = c_val[lane]; int j = c_idx[lane];
        {
            double v2 = c_val[lane + 64]; int j2 = c_idx[lane + 64];
            if (v2 < v || (v2 == v && j2 < j)) { v = v2; j = j2; }
        }
        if (lane == 0) {
            double v3 = c_val[128]; int j3 = c_idx[128];
            if (v3 < v || (v3 == v && j3 < j)) { v = v3; j = j3; }
        }
        lexmin_wave(v, j);
        const int p = j;

        const bool hitA = pvok && (p == prev_pv);
        const bool hitB = nkok && (p == prev_p);

        int k, nk;
        float4 a0, a1, b0, b1;
        if (hitA) {
            k  = prev_p;  nk = prev_nk;
            a0 = pva0; a1 = pva1; b0 = mm0; b1 = mm1;
        } else if (hitB) {
            k  = prev_nk; nk = s_next[k];
            a0 = mm0; a1 = mm1; b0 = pnk0; b1 = pnk1;
        } else {
            k  = s_next[p];
            nk = s_next[k];
            unsigned long long bA = __ballot((lane < step) && (mpos_reg == p));
            const int ia = bA ? (S_TOT + 63 - __clzll(bA)) : p;
            unsigned long long bB = __ballot((lane < step) && (mpos_reg == k));
            const int ib = bB ? (S_TOT + 63 - __clzll(bB)) : k;
            if (ia < S_TOT) { const float4* g = (const float4*)slot_gptr(ia, b, bank, refresh);
                              a0 = g[2 * lane]; a1 = g[2 * lane + 1]; }
            else            { const float4* g = (const float4*)&s_mvec[ia - S_TOT][0];
                              a0 = g[2 * lane]; a1 = g[2 * lane + 1]; }
            if (ib < S_TOT) { const float4* g = (const float4*)slot_gptr(ib, b, bank, refresh);
                              b0 = g[2 * lane]; b1 = g[2 * lane + 1]; }
            else            { const float4* g = (const float4*)&s_mvec[ib - S_TOT][0];
                              b0 = g[2 * lane]; b1 = g[2 * lane + 1]; }
        }

        int pv;
        if (hitB) {
            pv = prev_pv;
        } else {
            int jq = p - 1 - lane;
            bool plive = (jq >= 0) && (s_imp[jq] < 1e300);
            unsigned long long pb = __ballot(plive);
            pv = pb ? (p - __ffsll((unsigned long long)pb)) : -1;
        }

        float4 m0, m1;
        m0.x = 0.5f * (a0.x + b0.x); m0.y = 0.5f * (a0.y + b0.y);
        m0.z = 0.5f * (a0.z + b0.z); m0.w = 0.5f * (a0.w + b0.w);
        m1.x = 0.5f * (a1.x + b1.x); m1.y = 0.5f * (a1.y + b1.y);
        m1.z = 0.5f * (a1.z + b1.z); m1.w = 0.5f * (a1.w + b1.w);
        if (wid == 0) {
            float4* dst = (float4*)&s_mvec[step][0];
            dst[2 * lane] = m0; dst[2 * lane + 1] = m1;
        }

        if (lane == step) mpos_reg = p;

        // speculative prefetch of next step's likely parents (early issue)
        if (step + 1 < NMERGE) {
            prev_p  = p;
            prev_pv = pv;
            prev_nk = nk;
            mm0 = m0; mm1 = m1;
            pvok = (pv >= 0);
            nkok = (nk != 0xFFFF);
            unsigned long long bpv = __ballot((lane <= step) && (mpos_reg == pv));
            const int ipv = bpv ? (S_TOT + 63 - __clzll(bpv)) : pv;
            unsigned long long bnk = __ballot((lane <= step) && (mpos_reg == nk));
            const int ink = bnk ? (S_TOT + 63 - __clzll(bnk)) : nk;
            if (pvok) {
                if (ipv < S_TOT) { const float4* g = (const float4*)slot_gptr(ipv, b, bank, refresh);
                                   pva0 = g[2 * lane]; pva1 = g[2 * lane + 1]; }
                else             { const float4* g = (const float4*)&s_mvec[ipv - S_TOT][0];
                                   pva0 = g[2 * lane]; pva1 = g[2 * lane + 1]; }
            }
            if (nkok) {
                if (ink < S_TOT) { const float4* g = (const float4*)slot_gptr(ink, b, bank, refresh);
                                   pnk0 = g[2 * lane]; pnk1 = g[2 * lane + 1]; }
                else             { const float4* g = (const float4*)&s_mvec[ink - S_TOT][0];
                                   pnk0 = g[2 * lane]; pnk1 = g[2 * lane + 1]; }
            }
        }

        double ss = 0.0;
        ss += (double)m0.x * m0.x + (double)m0.y * m0.y + (double)m0.z * m0.z + (double)m0.w * m0.w;
        ss += (double)m1.x * m1.x + (double)m1.y * m1.y + (double)m1.z * m1.z + (double)m1.w * m1.w;
        const double nrm = sqrt(sum_wave(ss));
        wg_barrier_lds();                    // ---- B1 (lgkm only) ----

        // ======== phase B ====================================================
        if (wid == 3 && lane == 0) {
            s_next[p]    = (unsigned short)nk;
            s_imp[k]     = INF;
            s_imp[p]     = nrm;
            s_mpos[step] = (unsigned short)p;
            s_dead[step] = (unsigned short)k;
        }

        if (wid < 3) {
            int chp = p >> 6, chk = k >> 6;
            int chv = (pv >= 0) ? (pv >> 6) : -1;
            int cs = (wid == 0) ? chp
                   : (wid == 1) ? ((chk != chp) ? chk : -1)
                                : ((chv >= 0 && chv != chp && chv != chk) ? chv : -1);
            if (cs >= 0) {
                double sc = INF; int bj = 0x7FFFFFFF;
                int jj = cs * 64 + lane;
                if (jj < S_TOT && jj != k) {
                    int nxt = (jj == p) ? nk : (int)s_next[jj];
                    if (nxt != 0xFFFF) {
                        double a0d = (jj == p) ? nrm : s_imp[jj];
                        if (a0d < 1e300) {
                            double a1d = (nxt == p) ? nrm : s_imp[nxt];
                            sc = a0d + a1d; bj = jj;
                        }
                    }
                }
                lexmin_wave(sc, bj);
                if (lane == 0) { c_val[cs] = sc; c_idx[cs] = bj; }
            }
        }
        wg_barrier_lds();                    // ---- B2 (lgkm only) ----
    }

    __syncthreads();   // full barrier (vmcnt too) before epilogue reuse

    // ---- dump merged vectors to global for the gather ----
    {
        const float4* src = (const float4*)&s_mvec[0][0];
        float4* dst = (float4*)(merged + (size_t)b * NMERGE * D);
        for (int i = t; i < NMERGE * D / 4; i += 256) dst[i] = src[i];
    }

    // ---- identity LUT in s_next (dead after main loop) ----
    for (int j = t; j < S_TOT; j += 256) s_next[j] = 0xFFFF;
    __syncthreads();
    if (t == 0)
        for (int m2 = 0; m2 < NMERGE; ++m2) s_next[s_mpos[m2]] = (unsigned short)m2;
    __syncthreads();

    // ---- emit compacted index map ----
    for (int j = t; j < S_TOT; j += 256) {
        if (s_imp[j] < 1e300) {
            int r = j;
            #pragma unroll
            for (int m2 = 0; m2 < NMERGE; ++m2) r -= (s_dead[m2] < j) ? 1 : 0;
            unsigned short lut = s_next[j];
            idx_out[b * S_BANK + r] = (lut != 0xFFFF) ? (unsigned short)(S_TOT + lut)
                                                      : (unsigned short)j;
        }
    }
    __syncthreads();   // epilogue LDS reads done before next rep's prologue writes

    }  // rep
}

// ---------------- Kernel 3: gather/write output (float4, NT stores) ----------
__global__ __launch_bounds__(256) void gather_kernel(const vfloat4* __restrict__ bank,
        const vfloat4* __restrict__ refresh, const vfloat4* __restrict__ merged,
        const unsigned short* __restrict__ idx, vfloat4* __restrict__ out) {
    size_t tid = (size_t)blockIdx.x * 256 + threadIdx.x;
    int slot = (int)(tid >> 7);
    int c    = (int)(tid & 127);
    int b    = slot >> 13;
    int src  = idx[slot];
    const vfloat4* sp;
    if (src < S_BANK)     sp = bank    + ((size_t)b * S_BANK + src) * (D / 4);
    else if (src < S_TOT) sp = refresh + ((size_t)b * S_REF + (src - S_BANK)) * (D / 4);
    else                  sp = merged  + ((size_t)b * NMERGE + (src - S_TOT)) * (D / 4);
    vfloat4 v = sp[c];
    __builtin_nontemporal_store(v, &out[tid]);
}

// ------------------------------------------------------------------------------
extern "C" void kernel_launch(void* const* d_in, const int* in_sizes, int n_in,
                              void* d_out, int out_size, void* d_ws, size_t ws_size,
                              hipStream_t stream) {
    const float* bank    = (const float*)d_in[0];
    const float* refresh = (const float*)d_in[1];

    double*         norms  = (double*)d_ws;
    float*          merged = (float*)((char*)d_ws + (size_t)B_DIM * S_TOT * sizeof(double));
    unsigned short* idx    = (unsigned short*)((char*)merged + (size_t)B_DIM * NMERGE * D * sizeof(float));
    float*          out    = (float*)d_out;

    norms_kernel<<<(B_DIM * S_TOT) / 4, 256, 0, stream>>>(bank, refresh, norms);
    merge_kernel<<<B_DIM, 256, 0, stream>>>(bank, refresh, norms, merged, idx);
    gather_kernel<<<(size_t)B_DIM * S_BANK * (D / 4) / 256, 256, 0, stream>>>(
        (const vfloat4*)bank, (const vfloat4*)refresh, (const vfloat4*)merged, idx, (vfloat4*)out);
}

// Round 8
// 187.019 us; speedup vs baseline: 1.9339x; 1.9339x over previous
//
#include <hip/hip_runtime.h>
#include <cstdint>
#include <cstddef>

#define B_DIM  16
#define S_BANK 8192
#define S_REF  32
#define S_TOT  8224   // S_BANK + S_REF
#define NMERGE 32     // S_TOT - MAX_SLOTS
#define D      512
#define NCH    129    // ceil(S_TOT / 64)

typedef float vfloat4 __attribute__((ext_vector_type(4)));  // NT-store capable
typedef unsigned long long u64;
#define DEADPK 0xFFFFFFFFFFFFFFFFULL   // +inf sentinel in u64 ordering

// ---------------- bit helpers ------------------------------------------------
__device__ __forceinline__ int d_lo(double d){ union{double d; int i[2];}u; u.d=d; return u.i[0]; }
__device__ __forceinline__ int d_hi(double d){ union{double d; int i[2];}u; u.d=d; return u.i[1]; }
__device__ __forceinline__ double d_mk(int hi,int lo){ union{double d; int i[2];}u; u.i[0]=lo;u.i[1]=hi; return u.d; }
__device__ __forceinline__ int u_lo(u64 v){ return (int)(v & 0xFFFFFFFFULL); }
__device__ __forceinline__ int u_hi(u64 v){ return (int)(v >> 32); }
__device__ __forceinline__ u64 u_mk(int hi,int lo){ return ((u64)(unsigned)hi << 32) | (u64)(unsigned)lo; }
__device__ __forceinline__ u64 d_bits(double d){ union{double d; u64 u;}x; x.d=d; return x.u; }

// pack (positive f64 score, idx<16384) into one sortable u64:
// bit pattern of positive doubles is order-monotonic; low 14 mantissa bits
// replaced by idx => unsigned compare == lexicographic (score, idx) compare.
__device__ __forceinline__ u64 pack_score(double s, int j) {
    return (d_bits(s) & ~0x3FFFULL) | (u64)(unsigned)j;
}

// ---------------- DPP wave64 reductions (VALU pipe) --------------------------
template<int CTRL>
__device__ __forceinline__ void minu_level(u64& v) {
    // old = self, bound_ctrl = 0: invalid lanes keep own value (min idempotent)
    int lo2 = __builtin_amdgcn_update_dpp(u_lo(v), u_lo(v), CTRL, 0xF, 0xF, false);
    int hi2 = __builtin_amdgcn_update_dpp(u_hi(v), u_hi(v), CTRL, 0xF, 0xF, false);
    u64 v2 = u_mk(hi2, lo2);
    if (v2 < v) v = v2;
}
// packed lexmin over 64 lanes; result broadcast to all lanes
__device__ __forceinline__ u64 lexmin_wave_u64(u64 v) {
    minu_level<0x111>(v);  // row_shr:1
    minu_level<0x112>(v);  // row_shr:2
    minu_level<0x114>(v);  // row_shr:4
    minu_level<0x118>(v);  // row_shr:8
    minu_level<0x142>(v);  // row_bcast:15
    minu_level<0x143>(v);  // row_bcast:31  -> lane 63 holds min
    int lo = __builtin_amdgcn_readlane(u_lo(v), 63);
    int hi = __builtin_amdgcn_readlane(u_hi(v), 63);
    return u_mk(hi, lo);
}
template<int CTRL>
__device__ __forceinline__ void sum_level(double& v) {
    // bound_ctrl = 1: invalid lanes contribute +0.0
    int lo2 = __builtin_amdgcn_update_dpp(0, d_lo(v), CTRL, 0xF, 0xF, true);
    int hi2 = __builtin_amdgcn_update_dpp(0, d_hi(v), CTRL, 0xF, 0xF, true);
    v += d_mk(hi2, lo2);
}
__device__ __forceinline__ double sum_wave(double v) {
    sum_level<0x111>(v); sum_level<0x112>(v); sum_level<0x114>(v);
    sum_level<0x118>(v); sum_level<0x142>(v); sum_level<0x143>(v);
    int lo = __builtin_amdgcn_readlane(d_lo(v), 63);
    int hi = __builtin_amdgcn_readlane(d_hi(v), 63);
    return d_mk(hi, lo);
}

// ---------------- Kernel 1: per-slot L2 norms (f64), reverse order -----------
__global__ __launch_bounds__(256) void norms_kernel(const float* __restrict__ bank,
                                                    const float* __restrict__ refresh,
                                                    double* __restrict__ norms) {
    int gw_lin = (int)((blockIdx.x * 256 + threadIdx.x) >> 6);
    int gw   = B_DIM * S_TOT - 1 - gw_lin;
    int lane = threadIdx.x & 63;
    int b = gw / S_TOT;
    int s = gw - b * S_TOT;
    const float4* src = (const float4*)(s < S_BANK
        ? bank    + ((size_t)b * S_BANK + s) * D
        : refresh + ((size_t)b * S_REF + (s - S_BANK)) * D);
    float4 f0 = src[lane];
    float4 f1 = src[lane + 64];
    double acc = 0.0;
    acc += (double)f0.x * f0.x + (double)f0.y * f0.y + (double)f0.z * f0.z + (double)f0.w * f0.w;
    acc += (double)f1.x * f1.x + (double)f1.y * f1.y + (double)f1.z * f1.z + (double)f1.w * f1.w;
    acc = sum_wave(acc);
    if (lane == 0) norms[gw] = sqrt(acc);
}

// ---------------- Kernel 2: merge-v10 — packed u64 scores --------------------
__device__ __forceinline__ const float* slot_gptr(int id, int b,
        const float* bank, const float* refresh) {
    return (id < S_BANK) ? bank    + ((size_t)b * S_BANK + id) * D
                         : refresh + ((size_t)b * S_REF + (id - S_BANK)) * D;
}

__global__ __launch_bounds__(256) void merge_kernel(const float* __restrict__ bank,
        const float* __restrict__ refresh, const double* __restrict__ norms,
        float* merged, unsigned short* __restrict__ idx_out) {
    __shared__ double         s_imp[S_TOT];      // >=1e300 == dead
    __shared__ u64            s_pk[S_TOT];       // packed (score,idx); DEADPK = none
    __shared__ unsigned short s_next[S_TOT];     // reused as id-LUT later
    __shared__ unsigned short s_mpos[NMERGE];
    __shared__ unsigned short s_dead[NMERGE];
    __shared__ u64            c_pk[NCH];         // init only; registers thereafter

    const int t    = threadIdx.x;
    const int b    = blockIdx.x;
    const int lane = t & 63;
    const int wid  = t >> 6;     // 4 waves
    const double INF = __builtin_inf();

    int mpos_reg = -1;           // lane l: position of merge result l (register copy)

    // speculative-prefetch carried state (cascade fast path)
    int prev_p = -1, prev_pv = -1, prev_nk = -1;
    int pvok = 0, nkok = 0;
    float4 mm0, mm1;             // previous merged vector (slot prev_p's current vec)
    float4 pva0, pva1;           // prefetched vector of prev_pv
    float4 pnk0, pnk1;           // prefetched vector of prev_nk

    for (int j = t; j < S_TOT; j += 256) {
        s_imp[j]  = norms[b * S_TOT + j];
        s_next[j] = (unsigned short)((j + 1 < S_TOT) ? (j + 1) : 0xFFFF);
    }
    __syncthreads();
    // packed score array (f64 add order identical to v6: imp[j] + imp[j+1])
    for (int j = t; j < S_TOT; j += 256)
        s_pk[j] = (j + 1 < S_TOT) ? pack_score(s_imp[j] + s_imp[j + 1], j) : DEADPK;
    __syncthreads();

    // initial chunk minima: one thread per chunk, serial u64-min scan
    if (t < NCH) {
        int j0 = t * 64;
        u64 best = DEADPK;
        for (int x = 0; x < 64; ++x) {
            int j = j0 + x;
            if (j < S_TOT) { u64 v = s_pk[j]; if (v < best) best = v; }
        }
        c_pk[t] = best;
    }
    __syncthreads();

    // register-resident chunk minima, replicated on every wave
    u64 cv0 = c_pk[lane];
    u64 cv1 = c_pk[lane + 64];
    u64 cv2 = (lane == 0) ? c_pk[128] : DEADPK;

    for (int step = 0; step < NMERGE; ++step) {
        // ======== phase A: register argmin + one packed DPP lexmin ===========
        u64 m = (cv0 < cv1) ? cv0 : cv1;
        m = (m < cv2) ? m : cv2;
        m = lexmin_wave_u64(m);
        const int p = (int)(m & 0x3FFFULL);

        // cascade fast paths: winner involves last step's merged slot
        const bool hitA = pvok && (p == prev_pv);   // pair (prev_pv, prev_p)
        const bool hitB = nkok && (p == prev_p);    // pair (prev_p, prev_nk)

        int k, nk;
        float4 a0, a1, b0, b1;
        if (hitA) {
            k  = prev_p;                 // s_next[prev_pv] == prev_p (list invariant)
            nk = prev_nk;                // s_next[prev_p] == prev_nk (post-commit)
            a0 = pva0; a1 = pva1;        // pv vector: prefetched
            b0 = mm0;  b1 = mm1;         // prev_p vector: carried merged regs
        } else if (hitB) {
            k  = prev_nk;
            nk = s_next[k];              // stable entry (k != prev_p)
            a0 = mm0;  a1 = mm1;
            b0 = pnk0; b1 = pnk1;        // nk vector: prefetched
        } else {
            k  = s_next[p];              // uniform LDS broadcast
            nk = s_next[k];
            // identities from register mpos (no LDS read)
            unsigned long long bA = __ballot((lane < step) && (mpos_reg == p));
            const int ia = bA ? (S_TOT + 63 - __clzll(bA)) : p;
            unsigned long long bB = __ballot((lane < step) && (mpos_reg == k));
            const int ib = bB ? (S_TOT + 63 - __clzll(bB)) : k;
            if (ia < S_TOT) { const float4* g = (const float4*)slot_gptr(ia, b, bank, refresh);
                              a0 = g[2 * lane]; a1 = g[2 * lane + 1]; }
            else            { const float4* g = (const float4*)(merged +
                                  ((size_t)b * NMERGE + (ia - S_TOT)) * D);
                              a0 = g[2 * lane]; a1 = g[2 * lane + 1]; }
            if (ib < S_TOT) { const float4* g = (const float4*)slot_gptr(ib, b, bank, refresh);
                              b0 = g[2 * lane]; b1 = g[2 * lane + 1]; }
            else            { const float4* g = (const float4*)(merged +
                                  ((size_t)b * NMERGE + (ib - S_TOT)) * D);
                              b0 = g[2 * lane]; b1 = g[2 * lane + 1]; }
        }

        // prev-live slot before p (known when hitB; otherwise ballot scan)
        int pv;
        if (hitB) {
            pv = prev_pv;                // nothing between pv and p changed liveness
        } else {
            int jq = p - 1 - lane;
            bool plive = (jq >= 0) && (s_imp[jq] < 1e300);
            unsigned long long pb = __ballot(plive);
            pv = pb ? (p - __ffsll((unsigned long long)pb)) : -1;
        }

        // ---- early LDS reads (pre-B1 == pre-commit: race-free, stale-OK) ----
        const double imp_nk = s_imp[(nk != 0xFFFF) ? nk : 0];  // valid iff nk valid
        const double imp_pv = s_imp[(pv >= 0) ? pv : 0];       // valid iff pv valid
        const int chp = p >> 6, chk = k >> 6;
        const int chv = (pv >= 0) ? (pv >> 6) : -1;
        const int csB = (chk != chp) ? chk : -1;
        const int csC = (chv >= 0 && chv != chp && chv != chk) ? chv : -1;
        const int jjA = chp * 64 + lane;
        const int jjB = ((csB >= 0) ? csB : 0) * 64 + lane;
        const int jjC = ((csC >= 0) ? csC : 0) * 64 + lane;
        const u64 rawA = s_pk[(jjA < S_TOT) ? jjA : (S_TOT - 1)];
        const u64 rawB = s_pk[(jjB < S_TOT) ? jjB : (S_TOT - 1)];
        const u64 rawC = s_pk[(jjC < S_TOT) ? jjC : (S_TOT - 1)];

        // ---- merge + norm (identical arithmetic/order to v6) ----
        float4 m0, m1;
        m0.x = 0.5f * (a0.x + b0.x); m0.y = 0.5f * (a0.y + b0.y);
        m0.z = 0.5f * (a0.z + b0.z); m0.w = 0.5f * (a0.w + b0.w);
        m1.x = 0.5f * (a1.x + b1.x); m1.y = 0.5f * (a1.y + b1.y);
        m1.z = 0.5f * (a1.z + b1.z); m1.w = 0.5f * (a1.w + b1.w);
        if (wid == 0) {                  // merged vector straight to global (L2)
            float4* dst = (float4*)(merged + ((size_t)b * NMERGE + step) * D);
            dst[2 * lane] = m0; dst[2 * lane + 1] = m1;
        }

        if (lane == step) mpos_reg = p;      // register mpos update (all waves)

        // ---- speculative prefetch of NEXT step's likely parents (early issue)
        if (step + 1 < NMERGE) {
            prev_p  = p;
            prev_pv = pv;
            prev_nk = nk;
            mm0 = m0; mm1 = m1;
            pvok = (pv >= 0);
            nkok = (nk != 0xFFFF);
            // identity resolution incl. current step (mpos[step]==p != pv,nk)
            unsigned long long bpv = __ballot((lane <= step) && (mpos_reg == pv));
            const int ipv = bpv ? (S_TOT + 63 - __clzll(bpv)) : pv;
            unsigned long long bnk = __ballot((lane <= step) && (mpos_reg == nk));
            const int ink = bnk ? (S_TOT + 63 - __clzll(bnk)) : nk;
            if (pvok) {
                const float4* g = (ipv < S_TOT)
                    ? (const float4*)slot_gptr(ipv, b, bank, refresh)
                    : (const float4*)(merged + ((size_t)b * NMERGE + (ipv - S_TOT)) * D);
                pva0 = g[2 * lane]; pva1 = g[2 * lane + 1];
            }
            if (nkok) {
                const float4* g = (ink < S_TOT)
                    ? (const float4*)slot_gptr(ink, b, bank, refresh)
                    : (const float4*)(merged + ((size_t)b * NMERGE + (ink - S_TOT)) * D);
                pnk0 = g[2 * lane]; pnk1 = g[2 * lane + 1];
            }
        }

        double ss = 0.0;
        ss += (double)m0.x * m0.x + (double)m0.y * m0.y + (double)m0.z * m0.z + (double)m0.w * m0.w;
        ss += (double)m1.x * m1.x + (double)m1.y * m1.y + (double)m1.z * m1.z + (double)m1.w * m1.w;
        const double nrm = sqrt(sum_wave(ss));

        // new packed scores (same f64 operand order as a fresh v6 rescan)
        const u64 pk_p_new  = (nk != 0xFFFF) ? pack_score(nrm + imp_nk, p) : DEADPK;
        const u64 pk_pv_new = (pv >= 0)      ? pack_score(imp_pv + nrm, pv) : DEADPK;

        __syncthreads();                     // ---- B1: all old-state reads done ----

        // ======== phase B ====================================================
        if (wid == 3 && lane == 0) {         // commit (sole LDS writer this phase)
            s_next[p]    = (unsigned short)nk;
            s_imp[k]     = INF;
            s_imp[p]     = nrm;
            s_pk[k]      = DEADPK;
            s_pk[p]      = pk_p_new;
            if (pv >= 0) s_pk[pv] = pk_pv_new;
            s_mpos[step] = (unsigned short)p;
            s_dead[step] = (unsigned short)k;
        }

        // ---- rescan finalize: substitutions + packed lexmin, ALL waves ------
        {
            u64 sc = (jjA >= S_TOT || jjA == k) ? DEADPK : rawA;
            if (jjA == p) sc = pk_p_new;
            if (pv >= 0 && jjA == pv) sc = pk_pv_new;
            sc = lexmin_wave_u64(sc);
            if (chp < 64)       { if (lane == chp)      cv0 = sc; }
            else if (chp < 128) { if (lane == chp - 64) cv1 = sc; }
            else                { if (lane == 0)        cv2 = sc; }
        }
        if (csB >= 0) {
            u64 sc = (jjB >= S_TOT || jjB == k) ? DEADPK : rawB;
            if (jjB == p) sc = pk_p_new;
            if (pv >= 0 && jjB == pv) sc = pk_pv_new;
            sc = lexmin_wave_u64(sc);
            if (csB < 64)       { if (lane == csB)      cv0 = sc; }
            else if (csB < 128) { if (lane == csB - 64) cv1 = sc; }
            else                { if (lane == 0)        cv2 = sc; }
        }
        if (csC >= 0) {
            u64 sc = (jjC >= S_TOT || jjC == k) ? DEADPK : rawC;
            if (jjC == p) sc = pk_p_new;
            if (pv >= 0 && jjC == pv) sc = pk_pv_new;
            sc = lexmin_wave_u64(sc);
            if (csC < 64)       { if (lane == csC)      cv0 = sc; }
            else if (csC < 128) { if (lane == csC - 64) cv1 = sc; }
            else                { if (lane == 0)        cv2 = sc; }
        }
        __syncthreads();                     // ---- B2: commit visible next step ----
    }

    // ---- identity LUT in s_next (dead after main loop) ----
    for (int j = t; j < S_TOT; j += 256) s_next[j] = 0xFFFF;
    __syncthreads();
    if (t == 0)
        for (int m2 = 0; m2 < NMERGE; ++m2) s_next[s_mpos[m2]] = (unsigned short)m2;
    __syncthreads();

    // ---- emit compacted index map ----
    for (int j = t; j < S_TOT; j += 256) {
        if (s_imp[j] < 1e300) {
            int r = j;
            #pragma unroll
            for (int m2 = 0; m2 < NMERGE; ++m2) r -= (s_dead[m2] < j) ? 1 : 0;
            unsigned short lut = s_next[j];
            idx_out[b * S_BANK + r] = (lut != 0xFFFF) ? (unsigned short)(S_TOT + lut)
                                                      : (unsigned short)j;
        }
    }
}

// ---------------- Kernel 3: gather/write output (float4, NT stores) ----------
__global__ __launch_bounds__(256) void gather_kernel(const vfloat4* __restrict__ bank,
        const vfloat4* __restrict__ refresh, const vfloat4* __restrict__ merged,
        const unsigned short* __restrict__ idx, vfloat4* __restrict__ out) {
    size_t tid = (size_t)blockIdx.x * 256 + threadIdx.x;
    int slot = (int)(tid >> 7);
    int c    = (int)(tid & 127);
    int b    = slot >> 13;
    int src  = idx[slot];
    const vfloat4* sp;
    if (src < S_BANK)     sp = bank    + ((size_t)b * S_BANK + src) * (D / 4);
    else if (src < S_TOT) sp = refresh + ((size_t)b * S_REF + (src - S_BANK)) * (D / 4);
    else                  sp = merged  + ((size_t)b * NMERGE + (src - S_TOT)) * (D / 4);
    vfloat4 v = sp[c];
    __builtin_nontemporal_store(v, &out[tid]);
}

// ------------------------------------------------------------------------------
extern "C" void kernel_launch(void* const* d_in, const int* in_sizes, int n_in,
                              void* d_out, int out_size, void* d_ws, size_t ws_size,
                              hipStream_t stream) {
    const float* bank    = (const float*)d_in[0];
    const float* refresh = (const float*)d_in[1];

    double*         norms  = (double*)d_ws;
    float*          merged = (float*)((char*)d_ws + (size_t)B_DIM * S_TOT * sizeof(double));
    unsigned short* idx    = (unsigned short*)((char*)merged + (size_t)B_DIM * NMERGE * D * sizeof(float));
    float*          out    = (float*)d_out;

    norms_kernel<<<(B_DIM * S_TOT) / 4, 256, 0, stream>>>(bank, refresh, norms);
    merge_kernel<<<B_DIM, 256, 0, stream>>>(bank, refresh, norms, merged, idx);
    gather_kernel<<<(size_t)B_DIM * S_BANK * (D / 4) / 256, 256, 0, stream>>>(
        (const vfloat4*)bank, (const vfloat4*)refresh, (const vfloat4*)merged, idx, (vfloat4*)out);
}

// Round 9
// 181.762 us; speedup vs baseline: 1.9898x; 1.0289x over previous
//
#include <hip/hip_runtime.h>
#include <cstdint>
#include <cstddef>

#define B_DIM  16
#define S_BANK 8192
#define S_REF  32
#define S_TOT  8224   // S_BANK + S_REF
#define NMERGE 32     // S_TOT - MAX_SLOTS
#define D      512
#define NCH    129    // ceil(S_TOT / 64)

typedef float vfloat4 __attribute__((ext_vector_type(4)));  // NT-store capable
typedef unsigned long long u64;
#define DEADPK 0xFFFFFFFFFFFFFFFFULL   // +inf sentinel in u64 ordering

// ---------------- bit helpers ------------------------------------------------
__device__ __forceinline__ int d_lo(double d){ union{double d; int i[2];}u; u.d=d; return u.i[0]; }
__device__ __forceinline__ int d_hi(double d){ union{double d; int i[2];}u; u.d=d; return u.i[1]; }
__device__ __forceinline__ double d_mk(int hi,int lo){ union{double d; int i[2];}u; u.i[0]=lo;u.i[1]=hi; return u.d; }
__device__ __forceinline__ int u_lo(u64 v){ return (int)(v & 0xFFFFFFFFULL); }
__device__ __forceinline__ int u_hi(u64 v){ return (int)(v >> 32); }
__device__ __forceinline__ u64 u_mk(int hi,int lo){ return ((u64)(unsigned)hi << 32) | (u64)(unsigned)lo; }
__device__ __forceinline__ u64 d_bits(double d){ union{double d; u64 u;}x; x.d=d; return x.u; }

// pack (positive f64 score, idx<16384) into one sortable u64:
// bit pattern of positive doubles is order-monotonic; low 14 mantissa bits
// replaced by idx => unsigned compare == lexicographic (score, idx) compare.
__device__ __forceinline__ u64 pack_score(double s, int j) {
    return (d_bits(s) & ~0x3FFFULL) | (u64)(unsigned)j;
}

// ---------------- DPP wave64 reductions (VALU pipe) --------------------------
template<int CTRL>
__device__ __forceinline__ void minu_level(u64& v) {
    // old = self, bound_ctrl = 0: invalid lanes keep own value (min idempotent)
    int lo2 = __builtin_amdgcn_update_dpp(u_lo(v), u_lo(v), CTRL, 0xF, 0xF, false);
    int hi2 = __builtin_amdgcn_update_dpp(u_hi(v), u_hi(v), CTRL, 0xF, 0xF, false);
    u64 v2 = u_mk(hi2, lo2);
    if (v2 < v) v = v2;
}
// packed lexmin over 64 lanes; result broadcast to all lanes
__device__ __forceinline__ u64 lexmin_wave_u64(u64 v) {
    minu_level<0x111>(v);  // row_shr:1
    minu_level<0x112>(v);  // row_shr:2
    minu_level<0x114>(v);  // row_shr:4
    minu_level<0x118>(v);  // row_shr:8
    minu_level<0x142>(v);  // row_bcast:15
    minu_level<0x143>(v);  // row_bcast:31  -> lane 63 holds min
    int lo = __builtin_amdgcn_readlane(u_lo(v), 63);
    int hi = __builtin_amdgcn_readlane(u_hi(v), 63);
    return u_mk(hi, lo);
}
template<int CTRL>
__device__ __forceinline__ void sum_level(double& v) {
    // bound_ctrl = 1: invalid lanes contribute +0.0
    int lo2 = __builtin_amdgcn_update_dpp(0, d_lo(v), CTRL, 0xF, 0xF, true);
    int hi2 = __builtin_amdgcn_update_dpp(0, d_hi(v), CTRL, 0xF, 0xF, true);
    v += d_mk(hi2, lo2);
}
__device__ __forceinline__ double sum_wave(double v) {
    sum_level<0x111>(v); sum_level<0x112>(v); sum_level<0x114>(v);
    sum_level<0x118>(v); sum_level<0x142>(v); sum_level<0x143>(v);
    int lo = __builtin_amdgcn_readlane(d_lo(v), 63);
    int hi = __builtin_amdgcn_readlane(d_hi(v), 63);
    return d_mk(hi, lo);
}

// ---------------- Kernel 1: per-slot L2 norms (f64), reverse order -----------
__global__ __launch_bounds__(256) void norms_kernel(const float* __restrict__ bank,
                                                    const float* __restrict__ refresh,
                                                    double* __restrict__ norms) {
    int gw_lin = (int)((blockIdx.x * 256 + threadIdx.x) >> 6);
    int gw   = B_DIM * S_TOT - 1 - gw_lin;
    int lane = threadIdx.x & 63;
    int b = gw / S_TOT;
    int s = gw - b * S_TOT;
    const float4* src = (const float4*)(s < S_BANK
        ? bank    + ((size_t)b * S_BANK + s) * D
        : refresh + ((size_t)b * S_REF + (s - S_BANK)) * D);
    float4 f0 = src[lane];
    float4 f1 = src[lane + 64];
    double acc = 0.0;
    acc += (double)f0.x * f0.x + (double)f0.y * f0.y + (double)f0.z * f0.z + (double)f0.w * f0.w;
    acc += (double)f1.x * f1.x + (double)f1.y * f1.y + (double)f1.z * f1.z + (double)f1.w * f1.w;
    acc = sum_wave(acc);
    if (lane == 0) norms[gw] = sqrt(acc);
}

// ---------------- Kernel 2: merge-v11 — single-wave loop, zero in-loop barriers
__device__ __forceinline__ const float* slot_gptr(int id, int b,
        const float* bank, const float* refresh) {
    return (id < S_BANK) ? bank    + ((size_t)b * S_BANK + id) * D
                         : refresh + ((size_t)b * S_REF + (id - S_BANK)) * D;
}

__global__ __launch_bounds__(256) void merge_kernel(const float* __restrict__ bank,
        const float* __restrict__ refresh, const double* __restrict__ norms,
        float* __restrict__ merged, unsigned short* __restrict__ idx_out) {
    __shared__ double         s_imp[S_TOT];      // >=1e300 == dead
    __shared__ unsigned short s_next[S_TOT];     // reused as id-LUT later
    __shared__ float          s_mvec[NMERGE][D]; // merged vectors
    __shared__ unsigned short s_mpos[NMERGE];
    __shared__ unsigned short s_dead[NMERGE];
    __shared__ u64            c_pk[NCH];         // init only; registers thereafter

    const int t    = threadIdx.x;
    const int b    = blockIdx.x;
    const int lane = t & 63;
    const int wid  = t >> 6;     // 4 waves; only wave 0 runs the merge loop
    const double INF = __builtin_inf();

    // ---- prologue: all 4 waves ----
    for (int j = t; j < S_TOT; j += 256) {
        s_imp[j]  = norms[b * S_TOT + j];
        s_next[j] = (unsigned short)((j + 1 < S_TOT) ? (j + 1) : 0xFFFF);
    }
    __syncthreads();
    // initial chunk minima (packed; f64 add order imp[j] + imp[j+1] as always)
    if (t < NCH) {
        int j0 = t * 64;
        int jend = (j0 + 63 < S_TOT - 1) ? (j0 + 63) : (S_TOT - 2);
        u64 best = DEADPK;
        for (int j = j0; j <= jend; ++j) {
            u64 v = pack_score(s_imp[j] + s_imp[j + 1], j);
            if (v < best) best = v;
        }
        c_pk[t] = best;
    }
    __syncthreads();

    if (wid == 0) {
        // register-resident chunk minima (single wave)
        u64 cv0 = c_pk[lane];
        u64 cv1 = c_pk[lane + 64];
        u64 cv2 = (lane == 0) ? c_pk[128] : DEADPK;

        int mpos_reg = -1;           // lane l: position of merge result l
        int prev_p = -1, prev_pv = -1, prev_nk = -1;
        int pvok = 0, nkok = 0;
        float4 mm0, mm1;             // previous merged vector
        float4 pva0, pva1;           // prefetched vector of prev_pv
        float4 pnk0, pnk1;           // prefetched vector of prev_nk

        for (int step = 0; step < NMERGE; ++step) {
            // ======== phase A: register argmin + one packed DPP lexmin =======
            u64 m = (cv0 < cv1) ? cv0 : cv1;
            m = (m < cv2) ? m : cv2;
            m = lexmin_wave_u64(m);
            const int p = (int)(m & 0x3FFFULL);

            const bool hitA = pvok && (p == prev_pv);   // pair (prev_pv, prev_p)
            const bool hitB = nkok && (p == prev_p);    // pair (prev_p, prev_nk)

            int k, nk;
            float4 a0, a1, b0, b1;
            if (hitA) {
                k  = prev_p;  nk = prev_nk;
                a0 = pva0; a1 = pva1; b0 = mm0; b1 = mm1;
            } else if (hitB) {
                k  = prev_nk;
                nk = s_next[k];
                a0 = mm0; a1 = mm1; b0 = pnk0; b1 = pnk1;
            } else {
                k  = s_next[p];
                nk = s_next[k];
                unsigned long long bA = __ballot((lane < step) && (mpos_reg == p));
                const int ia = bA ? (S_TOT + 63 - __clzll(bA)) : p;
                unsigned long long bB = __ballot((lane < step) && (mpos_reg == k));
                const int ib = bB ? (S_TOT + 63 - __clzll(bB)) : k;
                if (ia < S_TOT) { const float4* g = (const float4*)slot_gptr(ia, b, bank, refresh);
                                  a0 = g[2 * lane]; a1 = g[2 * lane + 1]; }
                else            { const float4* g = (const float4*)&s_mvec[ia - S_TOT][0];
                                  a0 = g[2 * lane]; a1 = g[2 * lane + 1]; }
                if (ib < S_TOT) { const float4* g = (const float4*)slot_gptr(ib, b, bank, refresh);
                                  b0 = g[2 * lane]; b1 = g[2 * lane + 1]; }
                else            { const float4* g = (const float4*)&s_mvec[ib - S_TOT][0];
                                  b0 = g[2 * lane]; b1 = g[2 * lane + 1]; }
            }

            // prev-live slot before p (known when hitB; otherwise ballot scan)
            int pv;
            if (hitB) {
                pv = prev_pv;
            } else {
                int jq = p - 1 - lane;
                bool plive = (jq >= 0) && (s_imp[jq] < 1e300);
                unsigned long long pb = __ballot(plive);
                pv = pb ? (p - __ffsll((unsigned long long)pb)) : -1;
            }

            // ---- pre-issue rescan + aux LDS reads (old state; substituted) --
            const double imp_nk = s_imp[(nk != 0xFFFF) ? nk : 0];
            const double imp_pv = s_imp[(pv >= 0) ? pv : 0];
            const int chp = p >> 6, chk = k >> 6;
            const int chv = (pv >= 0) ? (pv >> 6) : -1;
            const int csB = (chk != chp) ? chk : -1;
            const int csC = (chv >= 0 && chv != chp && chv != chk) ? chv : -1;
            const int jjA = chp * 64 + lane;
            const bool validA = (jjA < S_TOT) && (jjA != k);
            const int rawNxtA = validA ? (int)s_next[jjA] : 0xFFFF;   // old
            const double impA = validA ? s_imp[jjA] : INF;            // old
            const int nxtA = (jjA == p) ? nk : rawNxtA;
            const double impNxtA = (nxtA != 0xFFFF) ? s_imp[nxtA] : INF;  // old

            // ---- merge (identical arithmetic/order) ----
            float4 m0, m1;
            m0.x = 0.5f * (a0.x + b0.x); m0.y = 0.5f * (a0.y + b0.y);
            m0.z = 0.5f * (a0.z + b0.z); m0.w = 0.5f * (a0.w + b0.w);
            m1.x = 0.5f * (a1.x + b1.x); m1.y = 0.5f * (a1.y + b1.y);
            m1.z = 0.5f * (a1.z + b1.z); m1.w = 0.5f * (a1.w + b1.w);
            {   // wave 0's 64 lanes cover the full 2 KB row
                float4* dst = (float4*)&s_mvec[step][0];
                dst[2 * lane] = m0; dst[2 * lane + 1] = m1;
            }

            if (lane == step) mpos_reg = p;

            // ---- speculative prefetch of next step's likely parents ---------
            if (step + 1 < NMERGE) {
                prev_p  = p; prev_pv = pv; prev_nk = nk;
                mm0 = m0; mm1 = m1;
                pvok = (pv >= 0); nkok = (nk != 0xFFFF);
                unsigned long long bpv = __ballot((lane <= step) && (mpos_reg == pv));
                const int ipv = bpv ? (S_TOT + 63 - __clzll(bpv)) : pv;
                unsigned long long bnk = __ballot((lane <= step) && (mpos_reg == nk));
                const int ink = bnk ? (S_TOT + 63 - __clzll(bnk)) : nk;
                if (pvok) {
                    if (ipv < S_TOT) { const float4* g = (const float4*)slot_gptr(ipv, b, bank, refresh);
                                       pva0 = g[2 * lane]; pva1 = g[2 * lane + 1]; }
                    else             { const float4* g = (const float4*)&s_mvec[ipv - S_TOT][0];
                                       pva0 = g[2 * lane]; pva1 = g[2 * lane + 1]; }
                }
                if (nkok) {
                    if (ink < S_TOT) { const float4* g = (const float4*)slot_gptr(ink, b, bank, refresh);
                                       pnk0 = g[2 * lane]; pnk1 = g[2 * lane + 1]; }
                    else             { const float4* g = (const float4*)&s_mvec[ink - S_TOT][0];
                                       pnk0 = g[2 * lane]; pnk1 = g[2 * lane + 1]; }
                }
            }

            // ---- norm (identical arithmetic/order) ----
            double ss = 0.0;
            ss += (double)m0.x * m0.x + (double)m0.y * m0.y + (double)m0.z * m0.z + (double)m0.w * m0.w;
            ss += (double)m1.x * m1.x + (double)m1.y * m1.y + (double)m1.z * m1.z + (double)m1.w * m1.w;
            const double nrm = sqrt(sum_wave(ss));

            const u64 pk_p_new  = (nk != 0xFFFF) ? pack_score(nrm + imp_nk, p)  : DEADPK;
            const u64 pk_pv_new = (pv >= 0)      ? pack_score(imp_pv + nrm, pv) : DEADPK;

            // ---- commit (lane 0; same-wave LDS ordering suffices) ----
            if (lane == 0) {
                s_next[p]    = (unsigned short)nk;
                s_imp[k]     = INF;
                s_imp[p]     = nrm;
                s_mpos[step] = (unsigned short)p;
                s_dead[step] = (unsigned short)k;
            }

            // ---- rescan finalize chunk A: substitutions over pre-issued raws
            {
                u64 sc = DEADPK;
                if (validA && nxtA != 0xFFFF) {
                    double a0d = (jjA == p) ? nrm : impA;
                    if (a0d < 1e300) {
                        double a1d = (nxtA == p) ? nrm : impNxtA;
                        sc = pack_score(a0d + a1d, jjA);
                    }
                }
                sc = lexmin_wave_u64(sc);
                if (chp < 64)       { if (lane == chp)      cv0 = sc; }
                else if (chp < 128) { if (lane == chp - 64) cv1 = sc; }
                else                { if (lane == 0)        cv2 = sc; }
            }
            // ---- chunks B/C (rare; post-commit reads see new state == correct)
            if (csB >= 0) {
                int jj = csB * 64 + lane;
                u64 sc = DEADPK;
                if (jj < S_TOT && jj != k) {
                    int nxt = (int)s_next[jj];
                    if (nxt != 0xFFFF) {
                        double a0d = s_imp[jj];
                        if (a0d < 1e300) sc = pack_score(a0d + s_imp[nxt], jj);
                    }
                }
                sc = lexmin_wave_u64(sc);
                if (csB < 64)       { if (lane == csB)      cv0 = sc; }
                else if (csB < 128) { if (lane == csB - 64) cv1 = sc; }
                else                { if (lane == 0)        cv2 = sc; }
            }
            if (csC >= 0) {
                int jj = csC * 64 + lane;
                u64 sc = DEADPK;
                if (jj < S_TOT && jj != k) {
                    int nxt = (int)s_next[jj];
                    if (nxt != 0xFFFF) {
                        double a0d = s_imp[jj];
                        if (a0d < 1e300) sc = pack_score(a0d + s_imp[nxt], jj);
                    }
                }
                sc = lexmin_wave_u64(sc);
                if (csC < 64)       { if (lane == csC)      cv0 = sc; }
                else if (csC < 128) { if (lane == csC - 64) cv1 = sc; }
                else                { if (lane == 0)        cv2 = sc; }
            }
        }
    }
    __syncthreads();   // rendezvous: waves 1-3 rejoin; wave-0 LDS state visible

    // ---- dump merged vectors to global for the gather (all 4 waves) ----
    {
        const float4* src = (const float4*)&s_mvec[0][0];
        float4* dst = (float4*)(merged + (size_t)b * NMERGE * D);
        for (int i = t; i < NMERGE * D / 4; i += 256) dst[i] = src[i];
    }

    // ---- identity LUT in s_next (dead after main loop) ----
    for (int j = t; j < S_TOT; j += 256) s_next[j] = 0xFFFF;
    __syncthreads();
    if (t == 0)
        for (int m2 = 0; m2 < NMERGE; ++m2) s_next[s_mpos[m2]] = (unsigned short)m2;
    __syncthreads();

    // ---- emit compacted index map ----
    for (int j = t; j < S_TOT; j += 256) {
        if (s_imp[j] < 1e300) {
            int r = j;
            #pragma unroll
            for (int m2 = 0; m2 < NMERGE; ++m2) r -= (s_dead[m2] < j) ? 1 : 0;
            unsigned short lut = s_next[j];
            idx_out[b * S_BANK + r] = (lut != 0xFFFF) ? (unsigned short)(S_TOT + lut)
                                                      : (unsigned short)j;
        }
    }
}

// ---------------- Kernel 3: gather/write output (float4, NT stores) ----------
__global__ __launch_bounds__(256) void gather_kernel(const vfloat4* __restrict__ bank,
        const vfloat4* __restrict__ refresh, const vfloat4* __restrict__ merged,
        const unsigned short* __restrict__ idx, vfloat4* __restrict__ out) {
    size_t tid = (size_t)blockIdx.x * 256 + threadIdx.x;
    int slot = (int)(tid >> 7);
    int c    = (int)(tid & 127);
    int b    = slot >> 13;
    int src  = idx[slot];
    const vfloat4* sp;
    if (src < S_BANK)     sp = bank    + ((size_t)b * S_BANK + src) * (D / 4);
    else if (src < S_TOT) sp = refresh + ((size_t)b * S_REF + (src - S_BANK)) * (D / 4);
    else                  sp = merged  + ((size_t)b * NMERGE + (src - S_TOT)) * (D / 4);
    vfloat4 v = sp[c];
    __builtin_nontemporal_store(v, &out[tid]);
}

// ------------------------------------------------------------------------------
extern "C" void kernel_launch(void* const* d_in, const int* in_sizes, int n_in,
                              void* d_out, int out_size, void* d_ws, size_t ws_size,
                              hipStream_t stream) {
    const float* bank    = (const float*)d_in[0];
    const float* refresh = (const float*)d_in[1];

    double*         norms  = (double*)d_ws;
    float*          merged = (float*)((char*)d_ws + (size_t)B_DIM * S_TOT * sizeof(double));
    unsigned short* idx    = (unsigned short*)((char*)merged + (size_t)B_DIM * NMERGE * D * sizeof(float));
    float*          out    = (float*)d_out;

    norms_kernel<<<(B_DIM * S_TOT) / 4, 256, 0, stream>>>(bank, refresh, norms);
    merge_kernel<<<B_DIM, 256, 0, stream>>>(bank, refresh, norms, merged, idx);
    gather_kernel<<<(size_t)B_DIM * S_BANK * (D / 4) / 256, 256, 0, stream>>>(
        (const vfloat4*)bank, (const vfloat4*)refresh, (const vfloat4*)merged, idx, (vfloat4*)out);
}

// Round 10
// 177.633 us; speedup vs baseline: 2.0360x; 1.0232x over previous
//
#include <hip/hip_runtime.h>
#include <cstdint>
#include <cstddef>

#define B_DIM  16
#define S_BANK 8192
#define S_REF  32
#define S_TOT  8224   // S_BANK + S_REF
#define NMERGE 32     // S_TOT - MAX_SLOTS
#define D      512
#define NCH    129    // ceil(S_TOT / 64)

typedef float vfloat4 __attribute__((ext_vector_type(4)));  // NT-store capable
typedef unsigned long long u64;
#define DEADPK 0xFFFFFFFFFFFFFFFFULL   // +inf sentinel in u64 ordering

// ---------------- bit helpers ------------------------------------------------
__device__ __forceinline__ int d_lo(double d){ union{double d; int i[2];}u; u.d=d; return u.i[0]; }
__device__ __forceinline__ int d_hi(double d){ union{double d; int i[2];}u; u.d=d; return u.i[1]; }
__device__ __forceinline__ double d_mk(int hi,int lo){ union{double d; int i[2];}u; u.i[0]=lo;u.i[1]=hi; return u.d; }
__device__ __forceinline__ int u_lo(u64 v){ return (int)(v & 0xFFFFFFFFULL); }
__device__ __forceinline__ int u_hi(u64 v){ return (int)(v >> 32); }
__device__ __forceinline__ u64 u_mk(int hi,int lo){ return ((u64)(unsigned)hi << 32) | (u64)(unsigned)lo; }
__device__ __forceinline__ u64 d_bits(double d){ union{double d; u64 u;}x; x.d=d; return x.u; }

// pack (positive f64 score, idx<16384) into one sortable u64 (low 14 mantissa
// bits replaced by idx => unsigned compare == lexicographic (score,idx)).
__device__ __forceinline__ u64 pack_score(double s, int j) {
    return (d_bits(s) & ~0x3FFFULL) | (u64)(unsigned)j;
}

// ---------------- DPP wave64 reductions / scans (VALU pipe) ------------------
template<int CTRL, int ROWM>
__device__ __forceinline__ u64 dpp_u64(u64 v) {
    int lo = __builtin_amdgcn_update_dpp(u_lo(v), u_lo(v), CTRL, ROWM, 0xF, false);
    int hi = __builtin_amdgcn_update_dpp(u_hi(v), u_hi(v), CTRL, ROWM, 0xF, false);
    return u_mk(hi, lo);
}
__device__ __forceinline__ u64 rl_u64(u64 v, int l) {
    int lo = __builtin_amdgcn_readlane(u_lo(v), l);
    int hi = __builtin_amdgcn_readlane(u_hi(v), l);
    return u_mk(hi, lo);
}
// reduction min over 64 lanes, broadcast
__device__ __forceinline__ u64 lexmin_wave_u64(u64 v) {
    u64 w;
    w = dpp_u64<0x111,0xF>(v); if (w < v) v = w;
    w = dpp_u64<0x112,0xF>(v); if (w < v) v = w;
    w = dpp_u64<0x114,0xF>(v); if (w < v) v = w;
    w = dpp_u64<0x118,0xF>(v); if (w < v) v = w;
    w = dpp_u64<0x142,0xF>(v); if (w < v) v = w;
    w = dpp_u64<0x143,0xF>(v); if (w < v) v = w;
    return rl_u64(v, 63);
}
// inclusive prefix-min scan (ascending lanes)
__device__ __forceinline__ u64 scan_min_incl(u64 v) {
    u64 w;
    w = dpp_u64<0x111,0xF>(v); if (w < v) v = w;   // row_shr:1
    w = dpp_u64<0x112,0xF>(v); if (w < v) v = w;
    w = dpp_u64<0x114,0xF>(v); if (w < v) v = w;
    w = dpp_u64<0x118,0xF>(v); if (w < v) v = w;
    w = dpp_u64<0x142,0xA>(v); if (w < v) v = w;   // bcast15 -> rows 1,3
    w = dpp_u64<0x143,0xC>(v); if (w < v) v = w;   // bcast31 -> rows 2,3
    return v;
}
// inclusive suffix-min scan (descending)
__device__ __forceinline__ u64 scan_min_suffix(u64 v, int lane) {
    u64 w;
    w = dpp_u64<0x101,0xF>(v); if (w < v) v = w;   // row_shl:1
    w = dpp_u64<0x102,0xF>(v); if (w < v) v = w;
    w = dpp_u64<0x104,0xF>(v); if (w < v) v = w;
    w = dpp_u64<0x108,0xF>(v); if (w < v) v = w;
    // v[l] = min over [l .. row_end]; fold in later rows:
    u64 t16 = rl_u64(v, 16), t32 = rl_u64(v, 32), t48 = rl_u64(v, 48);
    u64 s3 = t48;
    u64 s2 = (t32 < s3) ? t32 : s3;
    u64 s1 = (t16 < s2) ? t16 : s2;
    int row = lane >> 4;
    u64 add = (row == 0) ? s1 : (row == 1) ? s2 : (row == 2) ? s3 : DEADPK;
    if (add < v) v = add;
    return v;
}
template<int CTRL>
__device__ __forceinline__ void sum_level(double& v) {
    int lo2 = __builtin_amdgcn_update_dpp(0, d_lo(v), CTRL, 0xF, 0xF, true);
    int hi2 = __builtin_amdgcn_update_dpp(0, d_hi(v), CTRL, 0xF, 0xF, true);
    v += d_mk(hi2, lo2);
}
__device__ __forceinline__ double sum_wave(double v) {
    sum_level<0x111>(v); sum_level<0x112>(v); sum_level<0x114>(v);
    sum_level<0x118>(v); sum_level<0x142>(v); sum_level<0x143>(v);
    int lo = __builtin_amdgcn_readlane(d_lo(v), 63);
    int hi = __builtin_amdgcn_readlane(d_hi(v), 63);
    return d_mk(hi, lo);
}

// ---------------- Kernel 1: per-slot L2 norms (f64), reverse order -----------
__global__ __launch_bounds__(256) void norms_kernel(const float* __restrict__ bank,
                                                    const float* __restrict__ refresh,
                                                    double* __restrict__ norms) {
    int gw_lin = (int)((blockIdx.x * 256 + threadIdx.x) >> 6);
    int gw   = B_DIM * S_TOT - 1 - gw_lin;
    int lane = threadIdx.x & 63;
    int b = gw / S_TOT;
    int s = gw - b * S_TOT;
    const float4* src = (const float4*)(s < S_BANK
        ? bank    + ((size_t)b * S_BANK + s) * D
        : refresh + ((size_t)b * S_REF + (s - S_BANK)) * D);
    float4 f0 = src[lane];
    float4 f1 = src[lane + 64];
    double acc = 0.0;
    acc += (double)f0.x * f0.x + (double)f0.y * f0.y + (double)f0.z * f0.z + (double)f0.w * f0.w;
    acc += (double)f1.x * f1.x + (double)f1.y * f1.y + (double)f1.z * f1.z + (double)f1.w * f1.w;
    acc = sum_wave(acc);
    if (lane == 0) norms[gw] = sqrt(acc);
}

// ---------------- Kernel 2: merge-v12 — cascade walk + exact validation ------
__device__ __forceinline__ const float* slot_gptr(int id, int b,
        const float* bank, const float* refresh) {
    return (id < S_BANK) ? bank    + ((size_t)b * S_BANK + id) * D
                         : refresh + ((size_t)b * S_REF + (id - S_BANK)) * D;
}

struct FastLds {
    u64   pref[192];       // prefix-min of original pk over 3-chunk window
    u64   suf[192];        // suffix-min
    float stage[34][D];    // predicted absorbed slots' vectors
    int   s_pred[34];      // predicted slot positions (absorb order)
    int   s_map[80];       // position - (p0-40) -> stage row, or -1
};
struct FallLds {
    unsigned short s_next[S_TOT];
    float          s_mvec[NMERGE][D];
    unsigned short s_mpos[NMERGE];
    unsigned short s_dead[NMERGE];
};
union MergeLds { FastLds fast; FallLds fall; };

__global__ __launch_bounds__(256) void merge_kernel(const float* __restrict__ bank,
        const float* __restrict__ refresh, const double* __restrict__ norms,
        float* __restrict__ merged, unsigned short* __restrict__ idx_out) {
    __shared__ double  s_imp[S_TOT];   // never modified by fast path
    __shared__ u64     c_pk[NCH];      // original chunk minima (packed)
    __shared__ MergeLds u;
    __shared__ int     rec_L[NMERGE], rec_R[NMERGE];
    __shared__ u64     rec_chosen[NMERGE];
    __shared__ u64     s_PL, s_SR;
    __shared__ int     s_flag;

    const int t    = threadIdx.x;
    const int b    = blockIdx.x;
    const int lane = t & 63;
    const int wid  = t >> 6;
    const double INF = __builtin_inf();

    // ---- shared prologue: imp + original packed chunk minima ----
    for (int j = t; j < S_TOT; j += 256)
        s_imp[j] = norms[b * S_TOT + j];
    __syncthreads();
    if (t < NCH) {
        int j0 = t * 64;
        int jend = (j0 + 63 < S_TOT - 1) ? (j0 + 63) : (S_TOT - 2);
        u64 best = DEADPK;
        for (int j = j0; j <= jend; ++j) {
            u64 v = pack_score(s_imp[j] + s_imp[j + 1], j);
            if (v < best) best = v;
        }
        c_pk[t] = best;
    }
    __syncthreads();

    // ---- global argmin p0 (all waves redundantly; uniform) ----
    u64 pk_min0;
    {
        u64 a = c_pk[lane];
        u64 bq = c_pk[lane + 64];
        u64 c = (lane == 0) ? c_pk[128] : DEADPK;
        u64 m = (a < bq) ? a : bq;
        m = (m < c) ? m : c;
        pk_min0 = lexmin_wave_u64(m);
    }
    const int p0 = (int)(pk_min0 & 0x3FFFULL);

    int do_fall = 1;
    const bool fast_ok = (p0 >= 98) && (p0 <= 8180);   // window/chunk edge guard

    if (fast_ok) {
        FastLds& F = u.fast;
        const int mbase = p0 - 40;

        // ---- map init ----
        for (int j = t; j < 80; j += 256) F.s_map[j] = -1;
        __syncthreads();

        // ---- prewalk (prediction only; imp-compare, tie->left) ----
        if (t == 0) {
            int Lp = p0, Rp = p0 + 1;
            F.s_pred[0] = p0;     F.s_map[p0 - mbase] = 0;
            F.s_pred[1] = p0 + 1; F.s_map[p0 + 1 - mbase] = 1;
            for (int i = 2; i < 34; ++i) {
                double dl = s_imp[Lp - 1];
                double dr = s_imp[Rp + 1];
                bool goL = !(dr < dl);
                int pos = goL ? (Lp - 1) : (Rp + 1);
                if (goL) --Lp; else ++Rp;
                F.s_pred[i] = pos; F.s_map[pos - mbase] = i;
            }
        }
        __syncthreads();

        // ---- stage predicted slots (all waves) ----
        for (int s = wid; s < 34; s += 4) {
            int pos = F.s_pred[s];
            const float4* g = (const float4*)slot_gptr(pos, b, bank, refresh);
            float4 v0 = g[2 * lane], v1 = g[2 * lane + 1];
            float4* dstg = (float4*)&F.stage[s][0];
            dstg[2 * lane] = v0; dstg[2 * lane + 1] = v1;
        }
        __syncthreads();

        // ---- real walk (all waves redundantly; deterministic) ----
        float4 m0r, m1r;
        double nrm;
        int L = p0, R = p0 + 1;
        {
            const float4* ga = (const float4*)&F.stage[0][0];
            const float4* gb = (const float4*)&F.stage[1][0];
            float4 a0 = ga[2 * lane], a1 = ga[2 * lane + 1];
            float4 b0 = gb[2 * lane], b1 = gb[2 * lane + 1];
            m0r.x = 0.5f * (a0.x + b0.x); m0r.y = 0.5f * (a0.y + b0.y);
            m0r.z = 0.5f * (a0.z + b0.z); m0r.w = 0.5f * (a0.w + b0.w);
            m1r.x = 0.5f * (a1.x + b1.x); m1r.y = 0.5f * (a1.y + b1.y);
            m1r.z = 0.5f * (a1.z + b1.z); m1r.w = 0.5f * (a1.w + b1.w);
            double ss = 0.0;
            ss += (double)m0r.x * m0r.x + (double)m0r.y * m0r.y + (double)m0r.z * m0r.z + (double)m0r.w * m0r.w;
            ss += (double)m1r.x * m1r.x + (double)m1r.y * m1r.y + (double)m1r.z * m1r.z + (double)m1r.w * m1r.w;
            nrm = sqrt(sum_wave(ss));
            if (t == 0) { rec_L[0] = L; rec_R[0] = R; rec_chosen[0] = pk_min0; }
        }
        for (int step = 1; step < NMERGE; ++step) {
            const int cl = L - 1, cr = R + 1;
            const int rlm = F.s_map[cl - mbase];
            const int rrm = F.s_map[cr - mbase];
            float4 xl0, xl1, xr0, xr1;
            if (rlm >= 0) { const float4* g = (const float4*)&F.stage[rlm][0];
                            xl0 = g[2 * lane]; xl1 = g[2 * lane + 1]; }
            else          { const float4* g = (const float4*)slot_gptr(cl, b, bank, refresh);
                            xl0 = g[2 * lane]; xl1 = g[2 * lane + 1]; }
            if (rrm >= 0) { const float4* g = (const float4*)&F.stage[rrm][0];
                            xr0 = g[2 * lane]; xr1 = g[2 * lane + 1]; }
            else          { const float4* g = (const float4*)slot_gptr(cr, b, bank, refresh);
                            xr0 = g[2 * lane]; xr1 = g[2 * lane + 1]; }
            const double il = s_imp[cl], ir = s_imp[cr];
            const u64 pkL = pack_score(il + nrm, cl);   // (imp_pv + nrm, idx pv)
            const u64 pkR = pack_score(nrm + ir, L);    // (nrm + imp_nk, idx L)
            const bool goL = (pkL < pkR);
            const u64 chosen = goL ? pkL : pkR;
            float4 a0, a1, b0, b1;
            if (goL) { a0 = xl0; a1 = xl1; b0 = m0r; b1 = m1r; L = cl; }
            else     { a0 = m0r; a1 = m1r; b0 = xr0; b1 = xr1; R = cr; }
            m0r.x = 0.5f * (a0.x + b0.x); m0r.y = 0.5f * (a0.y + b0.y);
            m0r.z = 0.5f * (a0.z + b0.z); m0r.w = 0.5f * (a0.w + b0.w);
            m1r.x = 0.5f * (a1.x + b1.x); m1r.y = 0.5f * (a1.y + b1.y);
            m1r.z = 0.5f * (a1.z + b1.z); m1r.w = 0.5f * (a1.w + b1.w);
            double ss = 0.0;
            ss += (double)m0r.x * m0r.x + (double)m0r.y * m0r.y + (double)m0r.z * m0r.z + (double)m0r.w * m0r.w;
            ss += (double)m1r.x * m1r.x + (double)m1r.y * m1r.y + (double)m1r.z * m1r.z + (double)m1r.w * m1r.w;
            nrm = sqrt(sum_wave(ss));
            if (t == 0) { rec_L[step] = L; rec_R[step] = R; rec_chosen[step] = chosen; }
        }
        __syncthreads();

        // ---- validation precompute ----
        const int cmid = p0 >> 6;
        const int wlo  = (cmid - 1) * 64;
        if (wid < 3) {
            int c = cmid - 1 + wid;
            int idx = c * 64 + lane;
            u64 pk0 = (idx <= S_TOT - 2) ? pack_score(s_imp[idx] + s_imp[idx + 1], idx)
                                         : DEADPK;
            F.pref[idx - wlo] = scan_min_incl(pk0);
            F.suf[idx - wlo]  = scan_min_suffix(pk0, lane);
        }
        if (wid == 3) {
            u64 x0 = (lane <= cmid - 2) ? c_pk[lane] : DEADPK;
            u64 x1 = (lane + 64 <= cmid - 2) ? c_pk[lane + 64] : DEADPK;
            u64 pl = (x0 < x1) ? x0 : x1;
            pl = lexmin_wave_u64(pl);
            u64 y0 = (lane >= cmid + 2) ? c_pk[lane] : DEADPK;
            u64 y1 = (lane + 64 >= cmid + 2) ? c_pk[lane + 64] : DEADPK;
            u64 y2 = (lane == 0 && 128 >= cmid + 2) ? c_pk[128] : DEADPK;
            u64 sr = (y0 < y1) ? y0 : y1;
            sr = (sr < y2) ? sr : y2;
            sr = lexmin_wave_u64(sr);
            if (lane == 0) { s_PL = pl; s_SR = sr; }
        }
        __syncthreads();

        // ---- per-step exact checks (wave 0) ----
        if (wid == 0) {
            u64 cf0 = F.pref[63], cf1 = F.pref[127];
            u64 sf1 = F.suf[64],  sf2 = F.suf[128];
            u64 PL = s_PL, SR = s_SR;
            bool ok = true;
            if (lane >= 1 && lane < NMERGE) {
                int Lp = rec_L[lane - 1], Rp = rec_R[lane - 1];   // pre-state of step `lane`
                int q1 = Lp - 2 - wlo, q2 = Rp + 1 - wlo;
                int r1 = q1 >> 6, r2 = q2 >> 6;
                u64 ol = F.pref[q1];
                if (r1 >= 1 && cf0 < ol) ol = cf0;
                if (r1 >= 2 && cf1 < ol) ol = cf1;
                if (PL < ol) ol = PL;
                u64 orr = F.suf[q2];
                if (r2 <= 0 && sf1 < orr) orr = sf1;
                if (r2 <= 1 && sf2 < orr) orr = sf2;
                if (SR < orr) orr = SR;
                u64 O = (ol < orr) ? ol : orr;
                ok = rec_chosen[lane] < O;
            }
            if (lane == 0) ok = ok && (rec_R[NMERGE - 1] - rec_L[NMERGE - 1] == NMERGE);
            unsigned long long bad = __ballot(!ok);
            if (lane == 0) s_flag = (bad != 0ULL) ? 1 : 0;
        }
        __syncthreads();

        if (s_flag == 0) {
            // ---- fast epilogue ----
            if (wid == 0) {
                float4* dst = (float4*)(merged + ((size_t)b * NMERGE + (NMERGE - 1)) * D);
                dst[2 * lane] = m0r; dst[2 * lane + 1] = m1r;
            }
            const int Ls = rec_L[NMERGE - 1], Rs = rec_R[NMERGE - 1];
            for (int j = t; j < S_TOT; j += 256) {
                if (j < Ls)       idx_out[b * S_BANK + j] = (unsigned short)j;
                else if (j == Ls) idx_out[b * S_BANK + j] = (unsigned short)(S_TOT + NMERGE - 1);
                else if (j > Rs)  idx_out[b * S_BANK + j - NMERGE] = (unsigned short)j;
            }
            do_fall = 0;
        }
    }

    // ================= FALLBACK: full v11 path (verbatim) ====================
    if (do_fall) {
        FallLds& G = u.fall;
        for (int j = t; j < S_TOT; j += 256)
            G.s_next[j] = (unsigned short)((j + 1 < S_TOT) ? (j + 1) : 0xFFFF);
        __syncthreads();

        if (wid == 0) {
            u64 cv0 = c_pk[lane];
            u64 cv1 = c_pk[lane + 64];
            u64 cv2 = (lane == 0) ? c_pk[128] : DEADPK;

            int mpos_reg = -1;
            int prev_p = -1, prev_pv = -1, prev_nk = -1;
            int pvok = 0, nkok = 0;
            float4 mm0, mm1, pva0, pva1, pnk0, pnk1;

            for (int step = 0; step < NMERGE; ++step) {
                u64 m = (cv0 < cv1) ? cv0 : cv1;
                m = (m < cv2) ? m : cv2;
                m = lexmin_wave_u64(m);
                const int p = (int)(m & 0x3FFFULL);

                const bool hitA = pvok && (p == prev_pv);
                const bool hitB = nkok && (p == prev_p);

                int k, nk;
                float4 a0, a1, b0, b1;
                if (hitA) {
                    k = prev_p; nk = prev_nk;
                    a0 = pva0; a1 = pva1; b0 = mm0; b1 = mm1;
                } else if (hitB) {
                    k = prev_nk; nk = G.s_next[k];
                    a0 = mm0; a1 = mm1; b0 = pnk0; b1 = pnk1;
                } else {
                    k = G.s_next[p]; nk = G.s_next[k];
                    unsigned long long bA = __ballot((lane < step) && (mpos_reg == p));
                    const int ia = bA ? (S_TOT + 63 - __clzll(bA)) : p;
                    unsigned long long bB = __ballot((lane < step) && (mpos_reg == k));
                    const int ib = bB ? (S_TOT + 63 - __clzll(bB)) : k;
                    if (ia < S_TOT) { const float4* g = (const float4*)slot_gptr(ia, b, bank, refresh);
                                      a0 = g[2 * lane]; a1 = g[2 * lane + 1]; }
                    else            { const float4* g = (const float4*)&G.s_mvec[ia - S_TOT][0];
                                      a0 = g[2 * lane]; a1 = g[2 * lane + 1]; }
                    if (ib < S_TOT) { const float4* g = (const float4*)slot_gptr(ib, b, bank, refresh);
                                      b0 = g[2 * lane]; b1 = g[2 * lane + 1]; }
                    else            { const float4* g = (const float4*)&G.s_mvec[ib - S_TOT][0];
                                      b0 = g[2 * lane]; b1 = g[2 * lane + 1]; }
                }

                int pv;
                if (hitB) {
                    pv = prev_pv;
                } else {
                    int jq = p - 1 - lane;
                    bool plive = (jq >= 0) && (s_imp[jq] < 1e300);
                    unsigned long long pb = __ballot(plive);
                    pv = pb ? (p - __ffsll((unsigned long long)pb)) : -1;
                }

                const double imp_nk = s_imp[(nk != 0xFFFF) ? nk : 0];
                const double imp_pv = s_imp[(pv >= 0) ? pv : 0];
                const int chp = p >> 6, chk = k >> 6;
                const int chv = (pv >= 0) ? (pv >> 6) : -1;
                const int csB = (chk != chp) ? chk : -1;
                const int csC = (chv >= 0 && chv != chp && chv != chk) ? chv : -1;
                const int jjA = chp * 64 + lane;
                const bool validA = (jjA < S_TOT) && (jjA != k);
                const int rawNxtA = validA ? (int)G.s_next[jjA] : 0xFFFF;
                const double impA = validA ? s_imp[jjA] : INF;
                const int nxtA = (jjA == p) ? nk : rawNxtA;
                const double impNxtA = (nxtA != 0xFFFF) ? s_imp[nxtA] : INF;

                float4 m0, m1;
                m0.x = 0.5f * (a0.x + b0.x); m0.y = 0.5f * (a0.y + b0.y);
                m0.z = 0.5f * (a0.z + b0.z); m0.w = 0.5f * (a0.w + b0.w);
                m1.x = 0.5f * (a1.x + b1.x); m1.y = 0.5f * (a1.y + b1.y);
                m1.z = 0.5f * (a1.z + b1.z); m1.w = 0.5f * (a1.w + b1.w);
                {
                    float4* dst = (float4*)&G.s_mvec[step][0];
                    dst[2 * lane] = m0; dst[2 * lane + 1] = m1;
                }
                if (lane == step) mpos_reg = p;

                if (step + 1 < NMERGE) {
                    prev_p = p; prev_pv = pv; prev_nk = nk;
                    mm0 = m0; mm1 = m1;
                    pvok = (pv >= 0); nkok = (nk != 0xFFFF);
                    unsigned long long bpv = __ballot((lane <= step) && (mpos_reg == pv));
                    const int ipv = bpv ? (S_TOT + 63 - __clzll(bpv)) : pv;
                    unsigned long long bnk = __ballot((lane <= step) && (mpos_reg == nk));
                    const int ink = bnk ? (S_TOT + 63 - __clzll(bnk)) : nk;
                    if (pvok) {
                        if (ipv < S_TOT) { const float4* g = (const float4*)slot_gptr(ipv, b, bank, refresh);
                                           pva0 = g[2 * lane]; pva1 = g[2 * lane + 1]; }
                        else             { const float4* g = (const float4*)&G.s_mvec[ipv - S_TOT][0];
                                           pva0 = g[2 * lane]; pva1 = g[2 * lane + 1]; }
                    }
                    if (nkok) {
                        if (ink < S_TOT) { const float4* g = (const float4*)slot_gptr(ink, b, bank, refresh);
                                           pnk0 = g[2 * lane]; pnk1 = g[2 * lane + 1]; }
                        else             { const float4* g = (const float4*)&G.s_mvec[ink - S_TOT][0];
                                           pnk0 = g[2 * lane]; pnk1 = g[2 * lane + 1]; }
                    }
                }

                double ss = 0.0;
                ss += (double)m0.x * m0.x + (double)m0.y * m0.y + (double)m0.z * m0.z + (double)m0.w * m0.w;
                ss += (double)m1.x * m1.x + (double)m1.y * m1.y + (double)m1.z * m1.z + (double)m1.w * m1.w;
                const double nrm = sqrt(sum_wave(ss));

                const u64 pk_p_new  = (nk != 0xFFFF) ? pack_score(nrm + imp_nk, p)  : DEADPK;
                const u64 pk_pv_new = (pv >= 0)      ? pack_score(imp_pv + nrm, pv) : DEADPK;

                if (lane == 0) {
                    G.s_next[p]    = (unsigned short)nk;
                    s_imp[k]       = INF;
                    s_imp[p]       = nrm;
                    G.s_mpos[step] = (unsigned short)p;
                    G.s_dead[step] = (unsigned short)k;
                }

                {
                    u64 sc = DEADPK;
                    if (validA && nxtA != 0xFFFF) {
                        double a0d = (jjA == p) ? nrm : impA;
                        if (a0d < 1e300) {
                            double a1d = (nxtA == p) ? nrm : impNxtA;
                            sc = pack_score(a0d + a1d, jjA);
                        }
                    }
                    sc = lexmin_wave_u64(sc);
                    if (chp < 64)       { if (lane == chp)      cv0 = sc; }
                    else if (chp < 128) { if (lane == chp - 64) cv1 = sc; }
                    else                { if (lane == 0)        cv2 = sc; }
                }
                if (csB >= 0) {
                    int jj = csB * 64 + lane;
                    u64 sc = DEADPK;
                    if (jj < S_TOT && jj != k) {
                        int nxt = (int)G.s_next[jj];
                        if (nxt != 0xFFFF) {
                            double a0d = s_imp[jj];
                            if (a0d < 1e300) sc = pack_score(a0d + s_imp[nxt], jj);
                        }
                    }
                    sc = lexmin_wave_u64(sc);
                    if (csB < 64)       { if (lane == csB)      cv0 = sc; }
                    else if (csB < 128) { if (lane == csB - 64) cv1 = sc; }
                    else                { if (lane == 0)        cv2 = sc; }
                }
                if (csC >= 0) {
                    int jj = csC * 64 + lane;
                    u64 sc = DEADPK;
                    if (jj < S_TOT && jj != k) {
                        int nxt = (int)G.s_next[jj];
                        if (nxt != 0xFFFF) {
                            double a0d = s_imp[jj];
                            if (a0d < 1e300) sc = pack_score(a0d + s_imp[nxt], jj);
                        }
                    }
                    sc = lexmin_wave_u64(sc);
                    if (csC < 64)       { if (lane == csC)      cv0 = sc; }
                    else if (csC < 128) { if (lane == csC - 64) cv1 = sc; }
                    else                { if (lane == 0)        cv2 = sc; }
                }
            }
        }
        __syncthreads();

        {
            const float4* src = (const float4*)&G.s_mvec[0][0];
            float4* dst = (float4*)(merged + (size_t)b * NMERGE * D);
            for (int i = t; i < NMERGE * D / 4; i += 256) dst[i] = src[i];
        }
        for (int j = t; j < S_TOT; j += 256) G.s_next[j] = 0xFFFF;
        __syncthreads();
        if (t == 0)
            for (int m2 = 0; m2 < NMERGE; ++m2) G.s_next[G.s_mpos[m2]] = (unsigned short)m2;
        __syncthreads();
        for (int j = t; j < S_TOT; j += 256) {
            if (s_imp[j] < 1e300) {
                int r = j;
                #pragma unroll
                for (int m2 = 0; m2 < NMERGE; ++m2) r -= (G.s_dead[m2] < j) ? 1 : 0;
                unsigned short lut = G.s_next[j];
                idx_out[b * S_BANK + r] = (lut != 0xFFFF) ? (unsigned short)(S_TOT + lut)
                                                          : (unsigned short)j;
            }
        }
    }
}

// ---------------- Kernel 3: gather/write output (float4, NT stores) ----------
__global__ __launch_bounds__(256) void gather_kernel(const vfloat4* __restrict__ bank,
        const vfloat4* __restrict__ refresh, const vfloat4* __restrict__ merged,
        const unsigned short* __restrict__ idx, vfloat4* __restrict__ out) {
    size_t tid = (size_t)blockIdx.x * 256 + threadIdx.x;
    int slot = (int)(tid >> 7);
    int c    = (int)(tid & 127);
    int b    = slot >> 13;
    int src  = idx[slot];
    const vfloat4* sp;
    if (src < S_BANK)     sp = bank    + ((size_t)b * S_BANK + src) * (D / 4);
    else if (src < S_TOT) sp = refresh + ((size_t)b * S_REF + (src - S_BANK)) * (D / 4);
    else                  sp = merged  + ((size_t)b * NMERGE + (src - S_TOT)) * (D / 4);
    vfloat4 v = sp[c];
    __builtin_nontemporal_store(v, &out[tid]);
}

// ------------------------------------------------------------------------------
extern "C" void kernel_launch(void* const* d_in, const int* in_sizes, int n_in,
                              void* d_out, int out_size, void* d_ws, size_t ws_size,
                              hipStream_t stream) {
    const float* bank    = (const float*)d_in[0];
    const float* refresh = (const float*)d_in[1];

    double*         norms  = (double*)d_ws;
    float*          merged = (float*)((char*)d_ws + (size_t)B_DIM * S_TOT * sizeof(double));
    unsigned short* idx    = (unsigned short*)((char*)merged + (size_t)B_DIM * NMERGE * D * sizeof(float));
    float*          out    = (float*)d_out;

    norms_kernel<<<(B_DIM * S_TOT) / 4, 256, 0, stream>>>(bank, refresh, norms);
    merge_kernel<<<B_DIM, 256, 0, stream>>>(bank, refresh, norms, merged, idx);
    gather_kernel<<<(size_t)B_DIM * S_BANK * (D / 4) / 256, 256, 0, stream>>>(
        (const vfloat4*)bank, (const vfloat4*)refresh, (const vfloat4*)merged, idx, (vfloat4*)out);
}

// Round 11
// 158.304 us; speedup vs baseline: 2.2846x; 1.1221x over previous
//
#include <hip/hip_runtime.h>
#include <cstdint>
#include <cstddef>

#define B_DIM  16
#define S_BANK 8192
#define S_REF  32
#define S_TOT  8224   // S_BANK + S_REF
#define NMERGE 32     // S_TOT - MAX_SLOTS
#define D      512
#define NCH    129    // ceil(S_TOT / 64)

typedef float vfloat4 __attribute__((ext_vector_type(4)));  // NT-store capable
typedef unsigned long long u64;
#define DEADPK 0xFFFFFFFFFFFFFFFFULL   // +inf sentinel in u64 ordering

// ---------------- bit helpers ------------------------------------------------
__device__ __forceinline__ int d_lo(double d){ union{double d; int i[2];}u; u.d=d; return u.i[0]; }
__device__ __forceinline__ int d_hi(double d){ union{double d; int i[2];}u; u.d=d; return u.i[1]; }
__device__ __forceinline__ double d_mk(int hi,int lo){ union{double d; int i[2];}u; u.i[0]=lo;u.i[1]=hi; return u.d; }
__device__ __forceinline__ int u_lo(u64 v){ return (int)(v & 0xFFFFFFFFULL); }
__device__ __forceinline__ int u_hi(u64 v){ return (int)(v >> 32); }
__device__ __forceinline__ u64 u_mk(int hi,int lo){ return ((u64)(unsigned)hi << 32) | (u64)(unsigned)lo; }
__device__ __forceinline__ u64 d_bits(double d){ union{double d; u64 u;}x; x.d=d; return x.u; }

// pack (positive f64 score, idx<16384) into one sortable u64 (low 14 mantissa
// bits replaced by idx => unsigned compare == lexicographic (score,idx)).
__device__ __forceinline__ u64 pack_score(double s, int j) {
    return (d_bits(s) & ~0x3FFFULL) | (u64)(unsigned)j;
}

// ---------------- DPP wave64 reductions / scans (VALU pipe) ------------------
template<int CTRL, int ROWM>
__device__ __forceinline__ u64 dpp_u64(u64 v) {
    int lo = __builtin_amdgcn_update_dpp(u_lo(v), u_lo(v), CTRL, ROWM, 0xF, false);
    int hi = __builtin_amdgcn_update_dpp(u_hi(v), u_hi(v), CTRL, ROWM, 0xF, false);
    return u_mk(hi, lo);
}
__device__ __forceinline__ u64 rl_u64(u64 v, int l) {
    int lo = __builtin_amdgcn_readlane(u_lo(v), l);
    int hi = __builtin_amdgcn_readlane(u_hi(v), l);
    return u_mk(hi, lo);
}
// reduction min over 64 lanes, broadcast
__device__ __forceinline__ u64 lexmin_wave_u64(u64 v) {
    u64 w;
    w = dpp_u64<0x111,0xF>(v); if (w < v) v = w;
    w = dpp_u64<0x112,0xF>(v); if (w < v) v = w;
    w = dpp_u64<0x114,0xF>(v); if (w < v) v = w;
    w = dpp_u64<0x118,0xF>(v); if (w < v) v = w;
    w = dpp_u64<0x142,0xF>(v); if (w < v) v = w;
    w = dpp_u64<0x143,0xF>(v); if (w < v) v = w;
    return rl_u64(v, 63);
}
// inclusive prefix-min scan (ascending lanes)
__device__ __forceinline__ u64 scan_min_incl(u64 v) {
    u64 w;
    w = dpp_u64<0x111,0xF>(v); if (w < v) v = w;   // row_shr:1
    w = dpp_u64<0x112,0xF>(v); if (w < v) v = w;
    w = dpp_u64<0x114,0xF>(v); if (w < v) v = w;
    w = dpp_u64<0x118,0xF>(v); if (w < v) v = w;
    w = dpp_u64<0x142,0xA>(v); if (w < v) v = w;   // bcast15 -> rows 1,3
    w = dpp_u64<0x143,0xC>(v); if (w < v) v = w;   // bcast31 -> rows 2,3
    return v;
}
// inclusive suffix-min scan (descending)
__device__ __forceinline__ u64 scan_min_suffix(u64 v, int lane) {
    u64 w;
    w = dpp_u64<0x101,0xF>(v); if (w < v) v = w;   // row_shl:1
    w = dpp_u64<0x102,0xF>(v); if (w < v) v = w;
    w = dpp_u64<0x104,0xF>(v); if (w < v) v = w;
    w = dpp_u64<0x108,0xF>(v); if (w < v) v = w;
    // v[l] = min over [l .. row_end]; fold in later rows:
    u64 t16 = rl_u64(v, 16), t32 = rl_u64(v, 32), t48 = rl_u64(v, 48);
    u64 s3 = t48;
    u64 s2 = (t32 < s3) ? t32 : s3;
    u64 s1 = (t16 < s2) ? t16 : s2;
    int row = lane >> 4;
    u64 add = (row == 0) ? s1 : (row == 1) ? s2 : (row == 2) ? s3 : DEADPK;
    if (add < v) v = add;
    return v;
}
template<int CTRL>
__device__ __forceinline__ void sum_level(double& v) {
    int lo2 = __builtin_amdgcn_update_dpp(0, d_lo(v), CTRL, 0xF, 0xF, true);
    int hi2 = __builtin_amdgcn_update_dpp(0, d_hi(v), CTRL, 0xF, 0xF, true);
    v += d_mk(hi2, lo2);
}
__device__ __forceinline__ double sum_wave(double v) {
    sum_level<0x111>(v); sum_level<0x112>(v); sum_level<0x114>(v);
    sum_level<0x118>(v); sum_level<0x142>(v); sum_level<0x143>(v);
    int lo = __builtin_amdgcn_readlane(d_lo(v), 63);
    int hi = __builtin_amdgcn_readlane(d_hi(v), 63);
    return d_mk(hi, lo);
}

// ---------------- Kernel 1: per-slot L2 norms (f64), reverse order -----------
__global__ __launch_bounds__(256) void norms_kernel(const float* __restrict__ bank,
                                                    const float* __restrict__ refresh,
                                                    double* __restrict__ norms) {
    int gw_lin = (int)((blockIdx.x * 256 + threadIdx.x) >> 6);
    int gw   = B_DIM * S_TOT - 1 - gw_lin;
    int lane = threadIdx.x & 63;
    int b = gw / S_TOT;
    int s = gw - b * S_TOT;
    const float4* src = (const float4*)(s < S_BANK
        ? bank    + ((size_t)b * S_BANK + s) * D
        : refresh + ((size_t)b * S_REF + (s - S_BANK)) * D);
    float4 f0 = src[lane];
    float4 f1 = src[lane + 64];
    double acc = 0.0;
    acc += (double)f0.x * f0.x + (double)f0.y * f0.y + (double)f0.z * f0.z + (double)f0.w * f0.w;
    acc += (double)f1.x * f1.x + (double)f1.y * f1.y + (double)f1.z * f1.z + (double)f1.w * f1.w;
    acc = sum_wave(acc);
    if (lane == 0) norms[gw] = sqrt(acc);
}

// ---------------- Kernel 2: merge-v13 — edge-complete cascade walk -----------
__device__ __forceinline__ const float* slot_gptr(int id, int b,
        const float* bank, const float* refresh) {
    return (id < S_BANK) ? bank    + ((size_t)b * S_BANK + id) * D
                         : refresh + ((size_t)b * S_REF + (id - S_BANK)) * D;
}

struct FastLds {
    u64   pref[192];       // prefix-min of original pk over 3-chunk window
    u64   suf[192];        // suffix-min
    float stage[34][D];    // predicted absorbed slots' vectors
    int   s_pred[34];      // predicted slot positions (absorb order)
    int   s_map[80];       // position - mbase -> stage row, or -1
};
struct FallLds {
    unsigned short s_next[S_TOT];
    float          s_mvec[NMERGE][D];
    unsigned short s_mpos[NMERGE];
    unsigned short s_dead[NMERGE];
};
union MergeLds { FastLds fast; FallLds fall; };

__global__ __launch_bounds__(256) void merge_kernel(const float* __restrict__ bank,
        const float* __restrict__ refresh, const double* __restrict__ norms,
        float* __restrict__ merged, unsigned short* __restrict__ idx_out) {
    __shared__ double  s_imp[S_TOT];   // never modified by fast path
    __shared__ u64     c_pk[NCH];      // original chunk minima (packed)
    __shared__ MergeLds u;
    __shared__ int     rec_L[NMERGE], rec_R[NMERGE];
    __shared__ u64     rec_chosen[NMERGE];
    __shared__ u64     s_PL, s_SR;
    __shared__ int     s_flag;

    const int t    = threadIdx.x;
    const int b    = blockIdx.x;
    const int lane = t & 63;
    const int wid  = t >> 6;
    const double INF = __builtin_inf();

    // ---- shared prologue: imp + original packed chunk minima ----
    for (int j = t; j < S_TOT; j += 256)
        s_imp[j] = norms[b * S_TOT + j];
    __syncthreads();
    if (t < NCH) {
        int j0 = t * 64;
        int jend = (j0 + 63 < S_TOT - 1) ? (j0 + 63) : (S_TOT - 2);
        u64 best = DEADPK;
        // lane-staggered order (min is order-independent): stride-8B lane
        // pattern => ~4-way LDS banking instead of 32-way at stride-512B.
        for (int x = 0; x < 64; ++x) {
            int j = j0 + ((x + lane) & 63);
            if (j <= jend) {
                u64 v = pack_score(s_imp[j] + s_imp[j + 1], j);
                if (v < best) best = v;
            }
        }
        c_pk[t] = best;
    }
    __syncthreads();

    // ---- global argmin p0 (all waves redundantly; uniform) ----
    u64 pk_min0;
    {
        u64 a = c_pk[lane];
        u64 bq = c_pk[lane + 64];
        u64 c = (lane == 0) ? c_pk[128] : DEADPK;
        u64 m = (a < bq) ? a : bq;
        m = (m < c) ? m : c;
        pk_min0 = lexmin_wave_u64(m);
    }
    const int p0 = (int)(pk_min0 & 0x3FFFULL);

    int do_fall = 1;
    {
        FastLds& F = u.fast;
        int mb = p0 - 40;
        if (mb < 0) mb = 0;
        if (mb > S_TOT - 80) mb = S_TOT - 80;
        const int mbase = mb;

        // ---- map init ----
        for (int j = t; j < 80; j += 256) F.s_map[j] = -1;
        __syncthreads();

        // ---- prewalk (prediction only; imp-compare, edge => +inf) ----
        if (t == 0) {
            int Lp = p0, Rp = p0 + 1;
            F.s_pred[0] = p0;     F.s_map[p0 - mbase] = 0;
            F.s_pred[1] = p0 + 1; F.s_map[p0 + 1 - mbase] = 1;
            for (int i = 2; i < 34; ++i) {
                double dl = (Lp >= 1)         ? s_imp[Lp - 1] : INF;
                double dr = (Rp + 1 < S_TOT)  ? s_imp[Rp + 1] : INF;
                bool goL = !(dr < dl);
                int pos = goL ? (Lp - 1) : (Rp + 1);
                if (goL) --Lp; else ++Rp;
                F.s_pred[i] = pos; F.s_map[pos - mbase] = i;
            }
        }
        __syncthreads();

        // ---- stage predicted slots (all waves) ----
        for (int s = wid; s < 34; s += 4) {
            int pos = F.s_pred[s];
            const float4* g = (const float4*)slot_gptr(pos, b, bank, refresh);
            float4 v0 = g[2 * lane], v1 = g[2 * lane + 1];
            float4* dstg = (float4*)&F.stage[s][0];
            dstg[2 * lane] = v0; dstg[2 * lane + 1] = v1;
        }
        __syncthreads();

        // ---- real walk (all waves redundantly; deterministic) ----
        float4 m0r, m1r;
        double nrm;
        int L = p0, R = p0 + 1;
        {
            const float4* ga = (const float4*)&F.stage[0][0];
            const float4* gb = (const float4*)&F.stage[1][0];
            float4 a0 = ga[2 * lane], a1 = ga[2 * lane + 1];
            float4 b0 = gb[2 * lane], b1 = gb[2 * lane + 1];
            m0r.x = 0.5f * (a0.x + b0.x); m0r.y = 0.5f * (a0.y + b0.y);
            m0r.z = 0.5f * (a0.z + b0.z); m0r.w = 0.5f * (a0.w + b0.w);
            m1r.x = 0.5f * (a1.x + b1.x); m1r.y = 0.5f * (a1.y + b1.y);
            m1r.z = 0.5f * (a1.z + b1.z); m1r.w = 0.5f * (a1.w + b1.w);
            double ss = 0.0;
            ss += (double)m0r.x * m0r.x + (double)m0r.y * m0r.y + (double)m0r.z * m0r.z + (double)m0r.w * m0r.w;
            ss += (double)m1r.x * m1r.x + (double)m1r.y * m1r.y + (double)m1r.z * m1r.z + (double)m1r.w * m1r.w;
            nrm = sqrt(sum_wave(ss));
            if (t == 0) { rec_L[0] = L; rec_R[0] = R; rec_chosen[0] = pk_min0; }
        }
        for (int step = 1; step < NMERGE; ++step) {
            const int cl = L - 1, cr = R + 1;
            const bool hasL = (cl >= 0);
            const bool hasR = (cr < S_TOT);
            float4 xl0 = {0,0,0,0}, xl1 = {0,0,0,0}, xr0 = {0,0,0,0}, xr1 = {0,0,0,0};
            double il = INF, ir = INF;
            if (hasL) {
                il = s_imp[cl];
                const int rlm = F.s_map[cl - mbase];
                if (rlm >= 0) { const float4* g = (const float4*)&F.stage[rlm][0];
                                xl0 = g[2 * lane]; xl1 = g[2 * lane + 1]; }
                else          { const float4* g = (const float4*)slot_gptr(cl, b, bank, refresh);
                                xl0 = g[2 * lane]; xl1 = g[2 * lane + 1]; }
            }
            if (hasR) {
                ir = s_imp[cr];
                const int rrm = F.s_map[cr - mbase];
                if (rrm >= 0) { const float4* g = (const float4*)&F.stage[rrm][0];
                                xr0 = g[2 * lane]; xr1 = g[2 * lane + 1]; }
                else          { const float4* g = (const float4*)slot_gptr(cr, b, bank, refresh);
                                xr0 = g[2 * lane]; xr1 = g[2 * lane + 1]; }
            }
            const u64 pkL = hasL ? pack_score(il + nrm, cl) : DEADPK;  // (imp_pv + nrm, pv)
            const u64 pkR = hasR ? pack_score(nrm + ir, L)  : DEADPK;  // (nrm + imp_nk, L)
            const bool goL = (pkL < pkR);
            const u64 chosen = goL ? pkL : pkR;
            float4 a0, a1, b0, b1;
            if (goL) { a0 = xl0; a1 = xl1; b0 = m0r; b1 = m1r; L = cl; }
            else     { a0 = m0r; a1 = m1r; b0 = xr0; b1 = xr1; R = cr; }
            m0r.x = 0.5f * (a0.x + b0.x); m0r.y = 0.5f * (a0.y + b0.y);
            m0r.z = 0.5f * (a0.z + b0.z); m0r.w = 0.5f * (a0.w + b0.w);
            m1r.x = 0.5f * (a1.x + b1.x); m1r.y = 0.5f * (a1.y + b1.y);
            m1r.z = 0.5f * (a1.z + b1.z); m1r.w = 0.5f * (a1.w + b1.w);
            double ss = 0.0;
            ss += (double)m0r.x * m0r.x + (double)m0r.y * m0r.y + (double)m0r.z * m0r.z + (double)m0r.w * m0r.w;
            ss += (double)m1r.x * m1r.x + (double)m1r.y * m1r.y + (double)m1r.z * m1r.z + (double)m1r.w * m1r.w;
            nrm = sqrt(sum_wave(ss));
            if (t == 0) { rec_L[step] = L; rec_R[step] = R; rec_chosen[step] = chosen; }
        }
        __syncthreads();

        // ---- validation precompute (window = chunks ws..ws+2, clamped) ------
        const int cmid = p0 >> 6;
        int wsx = cmid - 1;
        if (wsx < 0) wsx = 0;
        if (wsx > NCH - 3) wsx = NCH - 3;
        const int ws  = wsx;
        const int wlo = ws * 64;
        if (wid < 3) {
            int c = ws + wid;
            int idx = c * 64 + lane;
            u64 pk0 = (idx <= S_TOT - 2) ? pack_score(s_imp[idx] + s_imp[idx + 1], idx)
                                         : DEADPK;
            F.pref[idx - wlo] = scan_min_incl(pk0);
            F.suf[idx - wlo]  = scan_min_suffix(pk0, lane);
        }
        if (wid == 3) {
            // PL: chunks < ws ; SR: chunks > ws+2
            u64 x0 = (lane < ws) ? c_pk[lane] : DEADPK;
            u64 x1 = (lane + 64 < ws) ? c_pk[lane + 64] : DEADPK;
            u64 pl = (x0 < x1) ? x0 : x1;
            pl = lexmin_wave_u64(pl);
            u64 y0 = (lane > ws + 2) ? c_pk[lane] : DEADPK;
            u64 y1 = (lane + 64 > ws + 2) ? c_pk[lane + 64] : DEADPK;
            u64 y2 = (lane == 0 && 128 > ws + 2) ? c_pk[128] : DEADPK;
            u64 sr = (y0 < y1) ? y0 : y1;
            sr = (sr < y2) ? sr : y2;
            sr = lexmin_wave_u64(sr);
            if (lane == 0) { s_PL = pl; s_SR = sr; }
        }
        __syncthreads();

        // ---- per-step exact checks (wave 0) ----
        if (wid == 0) {
            u64 cf0 = F.pref[63], cf1 = F.pref[127];
            u64 sf1 = F.suf[64],  sf2 = F.suf[128];
            u64 PL = s_PL, SR = s_SR;
            bool ok = true;
            if (lane >= 1 && lane < NMERGE) {
                int Lp = rec_L[lane - 1], Rp = rec_R[lane - 1];   // pre-state of step `lane`
                int q1 = Lp - 2 - wlo;
                u64 ol = DEADPK;
                if (q1 >= 0) {
                    ol = F.pref[q1];
                    int r1 = q1 >> 6;
                    if (r1 >= 1 && cf0 < ol) ol = cf0;
                    if (r1 >= 2 && cf1 < ol) ol = cf1;
                }
                if (PL < ol) ol = PL;
                int q2 = Rp + 1 - wlo;                            // in [1, 192)
                u64 orr = F.suf[q2];
                int r2 = q2 >> 6;
                if (r2 <= 0 && sf1 < orr) orr = sf1;
                if (r2 <= 1 && sf2 < orr) orr = sf2;
                if (SR < orr) orr = SR;
                u64 O = (ol < orr) ? ol : orr;
                ok = rec_chosen[lane] < O;
            }
            if (lane == 0) ok = ok && (rec_R[NMERGE - 1] - rec_L[NMERGE - 1] == NMERGE);
            unsigned long long bad = __ballot(!ok);
            if (lane == 0) s_flag = (bad != 0ULL) ? 1 : 0;
        }
        __syncthreads();

        if (s_flag == 0) {
            // ---- fast epilogue ----
            if (wid == 0) {
                float4* dst = (float4*)(merged + ((size_t)b * NMERGE + (NMERGE - 1)) * D);
                dst[2 * lane] = m0r; dst[2 * lane + 1] = m1r;
            }
            const int Ls = rec_L[NMERGE - 1], Rs = rec_R[NMERGE - 1];
            for (int j = t; j < S_TOT; j += 256) {
                if (j < Ls)       idx_out[b * S_BANK + j] = (unsigned short)j;
                else if (j == Ls) idx_out[b * S_BANK + j] = (unsigned short)(S_TOT + NMERGE - 1);
                else if (j > Rs)  idx_out[b * S_BANK + j - NMERGE] = (unsigned short)j;
            }
            do_fall = 0;
        }
    }

    // ================= FALLBACK: full v11 path (verbatim) ====================
    if (do_fall) {
        FallLds& G = u.fall;
        for (int j = t; j < S_TOT; j += 256)
            G.s_next[j] = (unsigned short)((j + 1 < S_TOT) ? (j + 1) : 0xFFFF);
        __syncthreads();

        if (wid == 0) {
            u64 cv0 = c_pk[lane];
            u64 cv1 = c_pk[lane + 64];
            u64 cv2 = (lane == 0) ? c_pk[128] : DEADPK;

            int mpos_reg = -1;
            int prev_p = -1, prev_pv = -1, prev_nk = -1;
            int pvok = 0, nkok = 0;
            float4 mm0, mm1, pva0, pva1, pnk0, pnk1;

            for (int step = 0; step < NMERGE; ++step) {
                u64 m = (cv0 < cv1) ? cv0 : cv1;
                m = (m < cv2) ? m : cv2;
                m = lexmin_wave_u64(m);
                const int p = (int)(m & 0x3FFFULL);

                const bool hitA = pvok && (p == prev_pv);
                const bool hitB = nkok && (p == prev_p);

                int k, nk;
                float4 a0, a1, b0, b1;
                if (hitA) {
                    k = prev_p; nk = prev_nk;
                    a0 = pva0; a1 = pva1; b0 = mm0; b1 = mm1;
                } else if (hitB) {
                    k = prev_nk; nk = G.s_next[k];
                    a0 = mm0; a1 = mm1; b0 = pnk0; b1 = pnk1;
                } else {
                    k = G.s_next[p]; nk = G.s_next[k];
                    unsigned long long bA = __ballot((lane < step) && (mpos_reg == p));
                    const int ia = bA ? (S_TOT + 63 - __clzll(bA)) : p;
                    unsigned long long bB = __ballot((lane < step) && (mpos_reg == k));
                    const int ib = bB ? (S_TOT + 63 - __clzll(bB)) : k;
                    if (ia < S_TOT) { const float4* g = (const float4*)slot_gptr(ia, b, bank, refresh);
                                      a0 = g[2 * lane]; a1 = g[2 * lane + 1]; }
                    else            { const float4* g = (const float4*)&G.s_mvec[ia - S_TOT][0];
                                      a0 = g[2 * lane]; a1 = g[2 * lane + 1]; }
                    if (ib < S_TOT) { const float4* g = (const float4*)slot_gptr(ib, b, bank, refresh);
                                      b0 = g[2 * lane]; b1 = g[2 * lane + 1]; }
                    else            { const float4* g = (const float4*)&G.s_mvec[ib - S_TOT][0];
                                      b0 = g[2 * lane]; b1 = g[2 * lane + 1]; }
                }

                int pv;
                if (hitB) {
                    pv = prev_pv;
                } else {
                    int jq = p - 1 - lane;
                    bool plive = (jq >= 0) && (s_imp[jq] < 1e300);
                    unsigned long long pb = __ballot(plive);
                    pv = pb ? (p - __ffsll((unsigned long long)pb)) : -1;
                }

                const double imp_nk = s_imp[(nk != 0xFFFF) ? nk : 0];
                const double imp_pv = s_imp[(pv >= 0) ? pv : 0];
                const int chp = p >> 6, chk = k >> 6;
                const int chv = (pv >= 0) ? (pv >> 6) : -1;
                const int csB = (chk != chp) ? chk : -1;
                const int csC = (chv >= 0 && chv != chp && chv != chk) ? chv : -1;
                const int jjA = chp * 64 + lane;
                const bool validA = (jjA < S_TOT) && (jjA != k);
                const int rawNxtA = validA ? (int)G.s_next[jjA] : 0xFFFF;
                const double impA = validA ? s_imp[jjA] : INF;
                const int nxtA = (jjA == p) ? nk : rawNxtA;
                const double impNxtA = (nxtA != 0xFFFF) ? s_imp[nxtA] : INF;

                float4 m0, m1;
                m0.x = 0.5f * (a0.x + b0.x); m0.y = 0.5f * (a0.y + b0.y);
                m0.z = 0.5f * (a0.z + b0.z); m0.w = 0.5f * (a0.w + b0.w);
                m1.x = 0.5f * (a1.x + b1.x); m1.y = 0.5f * (a1.y + b1.y);
                m1.z = 0.5f * (a1.z + b1.z); m1.w = 0.5f * (a1.w + b1.w);
                {
                    float4* dst = (float4*)&G.s_mvec[step][0];
                    dst[2 * lane] = m0; dst[2 * lane + 1] = m1;
                }
                if (lane == step) mpos_reg = p;

                if (step + 1 < NMERGE) {
                    prev_p = p; prev_pv = pv; prev_nk = nk;
                    mm0 = m0; mm1 = m1;
                    pvok = (pv >= 0); nkok = (nk != 0xFFFF);
                    unsigned long long bpv = __ballot((lane <= step) && (mpos_reg == pv));
                    const int ipv = bpv ? (S_TOT + 63 - __clzll(bpv)) : pv;
                    unsigned long long bnk = __ballot((lane <= step) && (mpos_reg == nk));
                    const int ink = bnk ? (S_TOT + 63 - __clzll(bnk)) : nk;
                    if (pvok) {
                        if (ipv < S_TOT) { const float4* g = (const float4*)slot_gptr(ipv, b, bank, refresh);
                                           pva0 = g[2 * lane]; pva1 = g[2 * lane + 1]; }
                        else             { const float4* g = (const float4*)&G.s_mvec[ipv - S_TOT][0];
                                           pva0 = g[2 * lane]; pva1 = g[2 * lane + 1]; }
                    }
                    if (nkok) {
                        if (ink < S_TOT) { const float4* g = (const float4*)slot_gptr(ink, b, bank, refresh);
                                           pnk0 = g[2 * lane]; pnk1 = g[2 * lane + 1]; }
                        else             { const float4* g = (const float4*)&G.s_mvec[ink - S_TOT][0];
                                           pnk0 = g[2 * lane]; pnk1 = g[2 * lane + 1]; }
                    }
                }

                double ss = 0.0;
                ss += (double)m0.x * m0.x + (double)m0.y * m0.y + (double)m0.z * m0.z + (double)m0.w * m0.w;
                ss += (double)m1.x * m1.x + (double)m1.y * m1.y + (double)m1.z * m1.z + (double)m1.w * m1.w;
                const double nrm = sqrt(sum_wave(ss));

                if (lane == 0) {
                    G.s_next[p]    = (unsigned short)nk;
                    s_imp[k]       = INF;
                    s_imp[p]       = nrm;
                    G.s_mpos[step] = (unsigned short)p;
                    G.s_dead[step] = (unsigned short)k;
                }

                {
                    u64 sc = DEADPK;
                    if (validA && nxtA != 0xFFFF) {
                        double a0d = (jjA == p) ? nrm : impA;
                        if (a0d < 1e300) {
                            double a1d = (nxtA == p) ? nrm : impNxtA;
                            sc = pack_score(a0d + a1d, jjA);
                        }
                    }
                    sc = lexmin_wave_u64(sc);
                    if (chp < 64)       { if (lane == chp)      cv0 = sc; }
                    else if (chp < 128) { if (lane == chp - 64) cv1 = sc; }
                    else                { if (lane == 0)        cv2 = sc; }
                }
                if (csB >= 0) {
                    int jj = csB * 64 + lane;
                    u64 sc = DEADPK;
                    if (jj < S_TOT && jj != k) {
                        int nxt = (int)G.s_next[jj];
                        if (nxt != 0xFFFF) {
                            double a0d = s_imp[jj];
                            if (a0d < 1e300) sc = pack_score(a0d + s_imp[nxt], jj);
                        }
                    }
                    sc = lexmin_wave_u64(sc);
                    if (csB < 64)       { if (lane == csB)      cv0 = sc; }
                    else if (csB < 128) { if (lane == csB - 64) cv1 = sc; }
                    else                { if (lane == 0)        cv2 = sc; }
                }
                if (csC >= 0) {
                    int jj = csC * 64 + lane;
                    u64 sc = DEADPK;
                    if (jj < S_TOT && jj != k) {
                        int nxt = (int)G.s_next[jj];
                        if (nxt != 0xFFFF) {
                            double a0d = s_imp[jj];
                            if (a0d < 1e300) sc = pack_score(a0d + s_imp[nxt], jj);
                        }
                    }
                    sc = lexmin_wave_u64(sc);
                    if (csC < 64)       { if (lane == csC)      cv0 = sc; }
                    else if (csC < 128) { if (lane == csC - 64) cv1 = sc; }
                    else                { if (lane == 0)        cv2 = sc; }
                }
            }
        }
        __syncthreads();

        {
            const float4* src = (const float4*)&G.s_mvec[0][0];
            float4* dst = (float4*)(merged + (size_t)b * NMERGE * D);
            for (int i = t; i < NMERGE * D / 4; i += 256) dst[i] = src[i];
        }
        for (int j = t; j < S_TOT; j += 256) G.s_next[j] = 0xFFFF;
        __syncthreads();
        if (t == 0)
            for (int m2 = 0; m2 < NMERGE; ++m2) G.s_next[G.s_mpos[m2]] = (unsigned short)m2;
        __syncthreads();
        for (int j = t; j < S_TOT; j += 256) {
            if (s_imp[j] < 1e300) {
                int r = j;
                #pragma unroll
                for (int m2 = 0; m2 < NMERGE; ++m2) r -= (G.s_dead[m2] < j) ? 1 : 0;
                unsigned short lut = G.s_next[j];
                idx_out[b * S_BANK + r] = (lut != 0xFFFF) ? (unsigned short)(S_TOT + lut)
                                                          : (unsigned short)j;
            }
        }
    }
}

// ---------------- Kernel 3: gather/write output (float4, NT stores) ----------
__global__ __launch_bounds__(256) void gather_kernel(const vfloat4* __restrict__ bank,
        const vfloat4* __restrict__ refresh, const vfloat4* __restrict__ merged,
        const unsigned short* __restrict__ idx, vfloat4* __restrict__ out) {
    size_t tid = (size_t)blockIdx.x * 256 + threadIdx.x;
    int slot = (int)(tid >> 7);
    int c    = (int)(tid & 127);
    int b    = slot >> 13;
    int src  = idx[slot];
    const vfloat4* sp;
    if (src < S_BANK)     sp = bank    + ((size_t)b * S_BANK + src) * (D / 4);
    else if (src < S_TOT) sp = refresh + ((size_t)b * S_REF + (src - S_BANK)) * (D / 4);
    else                  sp = merged  + ((size_t)b * NMERGE + (src - S_TOT)) * (D / 4);
    vfloat4 v = sp[c];
    __builtin_nontemporal_store(v, &out[tid]);
}

// ------------------------------------------------------------------------------
extern "C" void kernel_launch(void* const* d_in, const int* in_sizes, int n_in,
                              void* d_out, int out_size, void* d_ws, size_t ws_size,
                              hipStream_t stream) {
    const float* bank    = (const float*)d_in[0];
    const float* refresh = (const float*)d_in[1];

    double*         norms  = (double*)d_ws;
    float*          merged = (float*)((char*)d_ws + (size_t)B_DIM * S_TOT * sizeof(double));
    unsigned short* idx    = (unsigned short*)((char*)merged + (size_t)B_DIM * NMERGE * D * sizeof(float));
    float*          out    = (float*)d_out;

    norms_kernel<<<(B_DIM * S_TOT) / 4, 256, 0, stream>>>(bank, refresh, norms);
    merge_kernel<<<B_DIM, 256, 0, stream>>>(bank, refresh, norms, merged, idx);
    gather_kernel<<<(size_t)B_DIM * S_BANK * (D / 4) / 256, 256, 0, stream>>>(
        (const vfloat4*)bank, (const vfloat4*)refresh, (const vfloat4*)merged, idx, (vfloat4*)out);
}

// Round 12
// 149.212 us; speedup vs baseline: 2.4238x; 1.0609x over previous
//
#include <hip/hip_runtime.h>
#include <cstdint>
#include <cstddef>

#define B_DIM  16
#define S_BANK 8192
#define S_REF  32
#define S_TOT  8224   // S_BANK + S_REF
#define NMERGE 32     // S_TOT - MAX_SLOTS
#define D      512
#define NCH    129    // ceil(S_TOT / 64)

typedef float vfloat4 __attribute__((ext_vector_type(4)));  // NT-store capable
typedef unsigned long long u64;
#define DEADPK 0xFFFFFFFFFFFFFFFFULL   // +inf sentinel in u64 ordering

// ---------------- bit helpers ------------------------------------------------
__device__ __forceinline__ int d_lo(double d){ union{double d; int i[2];}u; u.d=d; return u.i[0]; }
__device__ __forceinline__ int d_hi(double d){ union{double d; int i[2];}u; u.d=d; return u.i[1]; }
__device__ __forceinline__ double d_mk(int hi,int lo){ union{double d; int i[2];}u; u.i[0]=lo;u.i[1]=hi; return u.d; }
__device__ __forceinline__ int u_lo(u64 v){ return (int)(v & 0xFFFFFFFFULL); }
__device__ __forceinline__ int u_hi(u64 v){ return (int)(v >> 32); }
__device__ __forceinline__ u64 u_mk(int hi,int lo){ return ((u64)(unsigned)hi << 32) | (u64)(unsigned)lo; }
__device__ __forceinline__ u64 d_bits(double d){ union{double d; u64 u;}x; x.d=d; return x.u; }

// pack (positive f64 score, idx<16384) into one sortable u64 (low 14 mantissa
// bits replaced by idx => unsigned compare == lexicographic (score,idx)).
__device__ __forceinline__ u64 pack_score(double s, int j) {
    return (d_bits(s) & ~0x3FFFULL) | (u64)(unsigned)j;
}

// ---------------- DPP wave64 reductions / scans (VALU pipe) ------------------
template<int CTRL, int ROWM>
__device__ __forceinline__ u64 dpp_u64(u64 v) {
    int lo = __builtin_amdgcn_update_dpp(u_lo(v), u_lo(v), CTRL, ROWM, 0xF, false);
    int hi = __builtin_amdgcn_update_dpp(u_hi(v), u_hi(v), CTRL, ROWM, 0xF, false);
    return u_mk(hi, lo);
}
__device__ __forceinline__ u64 rl_u64(u64 v, int l) {
    int lo = __builtin_amdgcn_readlane(u_lo(v), l);
    int hi = __builtin_amdgcn_readlane(u_hi(v), l);
    return u_mk(hi, lo);
}
// reduction min over 64 lanes, broadcast
__device__ __forceinline__ u64 lexmin_wave_u64(u64 v) {
    u64 w;
    w = dpp_u64<0x111,0xF>(v); if (w < v) v = w;
    w = dpp_u64<0x112,0xF>(v); if (w < v) v = w;
    w = dpp_u64<0x114,0xF>(v); if (w < v) v = w;
    w = dpp_u64<0x118,0xF>(v); if (w < v) v = w;
    w = dpp_u64<0x142,0xF>(v); if (w < v) v = w;
    w = dpp_u64<0x143,0xF>(v); if (w < v) v = w;
    return rl_u64(v, 63);
}
// inclusive prefix-min scan (ascending lanes)
__device__ __forceinline__ u64 scan_min_incl(u64 v) {
    u64 w;
    w = dpp_u64<0x111,0xF>(v); if (w < v) v = w;   // row_shr:1
    w = dpp_u64<0x112,0xF>(v); if (w < v) v = w;
    w = dpp_u64<0x114,0xF>(v); if (w < v) v = w;
    w = dpp_u64<0x118,0xF>(v); if (w < v) v = w;
    w = dpp_u64<0x142,0xA>(v); if (w < v) v = w;   // bcast15 -> rows 1,3
    w = dpp_u64<0x143,0xC>(v); if (w < v) v = w;   // bcast31 -> rows 2,3
    return v;
}
// inclusive suffix-min scan (descending)
__device__ __forceinline__ u64 scan_min_suffix(u64 v, int lane) {
    u64 w;
    w = dpp_u64<0x101,0xF>(v); if (w < v) v = w;   // row_shl:1
    w = dpp_u64<0x102,0xF>(v); if (w < v) v = w;
    w = dpp_u64<0x104,0xF>(v); if (w < v) v = w;
    w = dpp_u64<0x108,0xF>(v); if (w < v) v = w;
    // v[l] = min over [l .. row_end]; fold in later rows:
    u64 t16 = rl_u64(v, 16), t32 = rl_u64(v, 32), t48 = rl_u64(v, 48);
    u64 s3 = t48;
    u64 s2 = (t32 < s3) ? t32 : s3;
    u64 s1 = (t16 < s2) ? t16 : s2;
    int row = lane >> 4;
    u64 add = (row == 0) ? s1 : (row == 1) ? s2 : (row == 2) ? s3 : DEADPK;
    if (add < v) v = add;
    return v;
}
template<int CTRL>
__device__ __forceinline__ void sum_level(double& v) {
    int lo2 = __builtin_amdgcn_update_dpp(0, d_lo(v), CTRL, 0xF, 0xF, true);
    int hi2 = __builtin_amdgcn_update_dpp(0, d_hi(v), CTRL, 0xF, 0xF, true);
    v += d_mk(hi2, lo2);
}
__device__ __forceinline__ double sum_wave(double v) {
    sum_level<0x111>(v); sum_level<0x112>(v); sum_level<0x114>(v);
    sum_level<0x118>(v); sum_level<0x142>(v); sum_level<0x143>(v);
    int lo = __builtin_amdgcn_readlane(d_lo(v), 63);
    int hi = __builtin_amdgcn_readlane(d_hi(v), 63);
    return d_mk(hi, lo);
}

// ---------------- Kernel 1: per-slot L2 norms (f64), reverse order -----------
__global__ __launch_bounds__(256) void norms_kernel(const float* __restrict__ bank,
                                                    const float* __restrict__ refresh,
                                                    double* __restrict__ norms) {
    int gw_lin = (int)((blockIdx.x * 256 + threadIdx.x) >> 6);
    int gw   = B_DIM * S_TOT - 1 - gw_lin;
    int lane = threadIdx.x & 63;
    int b = gw / S_TOT;
    int s = gw - b * S_TOT;
    const float4* src = (const float4*)(s < S_BANK
        ? bank    + ((size_t)b * S_BANK + s) * D
        : refresh + ((size_t)b * S_REF + (s - S_BANK)) * D);
    float4 f0 = src[lane];
    float4 f1 = src[lane + 64];
    double acc = 0.0;
    acc += (double)f0.x * f0.x + (double)f0.y * f0.y + (double)f0.z * f0.z + (double)f0.w * f0.w;
    acc += (double)f1.x * f1.x + (double)f1.y * f1.y + (double)f1.z * f1.z + (double)f1.w * f1.w;
    acc = sum_wave(acc);
    if (lane == 0) norms[gw] = sqrt(acc);
}

// ---------------- Kernel 1.5: packed chunk minima (parallel, whole chip) -----
// One wave per (batch, chunk): identical pair scores / pack / min set as the
// old in-block serial scan (min is order-independent) => bit-identical c_pk.
__global__ __launch_bounds__(256) void chunkmin_kernel(const double* __restrict__ norms,
                                                       u64* __restrict__ c_pk_g) {
    int w    = (int)((blockIdx.x * 256 + threadIdx.x) >> 6);
    int lane = threadIdx.x & 63;
    if (w >= B_DIM * NCH) return;
    int b = w / NCH;
    int c = w - b * NCH;
    int j = c * 64 + lane;
    u64 pk = DEADPK;
    if (j <= S_TOT - 2) {
        double a = norms[b * S_TOT + j];
        double d = norms[b * S_TOT + j + 1];
        pk = pack_score(a + d, j);
    }
    pk = lexmin_wave_u64(pk);
    if (lane == 0) c_pk_g[b * NCH + c] = pk;
}

// ---------------- Kernel 2: merge-v14 — window-only staging ------------------
__device__ __forceinline__ const float* slot_gptr(int id, int b,
        const float* bank, const float* refresh) {
    return (id < S_BANK) ? bank    + ((size_t)b * S_BANK + id) * D
                         : refresh + ((size_t)b * S_REF + (id - S_BANK)) * D;
}

struct FastLds {
    u64   pref[192];       // prefix-min of original pk over 3-chunk window
    u64   suf[192];        // suffix-min
    float stage[34][D];    // predicted absorbed slots' vectors
    int   s_pred[34];      // predicted slot positions (absorb order)
    int   s_map[80];       // position - mbase -> stage row, or -1
};
struct FallLds {
    unsigned short s_next[S_TOT];
    float          s_mvec[NMERGE][D];
    unsigned short s_mpos[NMERGE];
    unsigned short s_dead[NMERGE];
};
union MergeLds { FastLds fast; FallLds fall; };

__global__ __launch_bounds__(256) void merge_kernel(const float* __restrict__ bank,
        const float* __restrict__ refresh, const double* __restrict__ norms,
        const u64* __restrict__ c_pk_g,
        float* __restrict__ merged, unsigned short* __restrict__ idx_out) {
    __shared__ double  s_imp[S_TOT];   // fast path: only the window is populated
    __shared__ u64     c_pk[NCH];      // original packed chunk minima
    __shared__ MergeLds u;
    __shared__ int     rec_L[NMERGE], rec_R[NMERGE];
    __shared__ u64     rec_chosen[NMERGE];
    __shared__ u64     s_PL, s_SR;
    __shared__ int     s_flag;

    const int t    = threadIdx.x;
    const int b    = blockIdx.x;
    const int lane = t & 63;
    const int wid  = t >> 6;
    const double INF = __builtin_inf();

    // ---- prologue: chunk minima from global (tiny) ----
    if (t < NCH) c_pk[t] = c_pk_g[b * NCH + t];
    __syncthreads();

    // ---- global argmin p0 (all waves redundantly; uniform) ----
    u64 pk_min0;
    {
        u64 a = c_pk[lane];
        u64 bq = c_pk[lane + 64];
        u64 c = (lane == 0) ? c_pk[128] : DEADPK;
        u64 m = (a < bq) ? a : bq;
        m = (m < c) ? m : c;
        pk_min0 = lexmin_wave_u64(m);
    }
    const int p0 = (int)(pk_min0 & 0x3FFFULL);

    // window chunks (clamped) — fixed for this block
    const int cmid = p0 >> 6;
    int wsx = cmid - 1;
    if (wsx < 0) wsx = 0;
    if (wsx > NCH - 3) wsx = NCH - 3;
    const int ws  = wsx;
    const int wlo = ws * 64;

    int do_fall = 1;
    {
        FastLds& F = u.fast;
        int mb = p0 - 40;
        if (mb < 0) mb = 0;
        if (mb > S_TOT - 80) mb = S_TOT - 80;
        const int mbase = mb;

        // ---- stage ONLY the window imps (194 doubles) + map init ----
        for (int j = t; j < 194; j += 256) {
            int g = wlo + j;
            if (g < S_TOT) s_imp[g] = norms[b * S_TOT + g];
        }
        for (int j = t; j < 80; j += 256) F.s_map[j] = -1;
        __syncthreads();

        // ---- prewalk (prediction only; imp-compare, edge => +inf) ----
        if (t == 0) {
            int Lp = p0, Rp = p0 + 1;
            F.s_pred[0] = p0;     F.s_map[p0 - mbase] = 0;
            F.s_pred[1] = p0 + 1; F.s_map[p0 + 1 - mbase] = 1;
            for (int i = 2; i < 34; ++i) {
                double dl = (Lp >= 1)         ? s_imp[Lp - 1] : INF;
                double dr = (Rp + 1 < S_TOT)  ? s_imp[Rp + 1] : INF;
                bool goL = !(dr < dl);
                int pos = goL ? (Lp - 1) : (Rp + 1);
                if (goL) --Lp; else ++Rp;
                F.s_pred[i] = pos; F.s_map[pos - mbase] = i;
            }
        }
        __syncthreads();

        // ---- stage predicted slots (all waves) ----
        for (int s = wid; s < 34; s += 4) {
            int pos = F.s_pred[s];
            const float4* g = (const float4*)slot_gptr(pos, b, bank, refresh);
            float4 v0 = g[2 * lane], v1 = g[2 * lane + 1];
            float4* dstg = (float4*)&F.stage[s][0];
            dstg[2 * lane] = v0; dstg[2 * lane + 1] = v1;
        }
        __syncthreads();

        // ---- real walk (all waves redundantly; deterministic) ----
        float4 m0r, m1r;
        double nrm;
        int L = p0, R = p0 + 1;
        {
            const float4* ga = (const float4*)&F.stage[0][0];
            const float4* gb = (const float4*)&F.stage[1][0];
            float4 a0 = ga[2 * lane], a1 = ga[2 * lane + 1];
            float4 b0 = gb[2 * lane], b1 = gb[2 * lane + 1];
            m0r.x = 0.5f * (a0.x + b0.x); m0r.y = 0.5f * (a0.y + b0.y);
            m0r.z = 0.5f * (a0.z + b0.z); m0r.w = 0.5f * (a0.w + b0.w);
            m1r.x = 0.5f * (a1.x + b1.x); m1r.y = 0.5f * (a1.y + b1.y);
            m1r.z = 0.5f * (a1.z + b1.z); m1r.w = 0.5f * (a1.w + b1.w);
            double ss = 0.0;
            ss += (double)m0r.x * m0r.x + (double)m0r.y * m0r.y + (double)m0r.z * m0r.z + (double)m0r.w * m0r.w;
            ss += (double)m1r.x * m1r.x + (double)m1r.y * m1r.y + (double)m1r.z * m1r.z + (double)m1r.w * m1r.w;
            nrm = sqrt(sum_wave(ss));
            if (t == 0) { rec_L[0] = L; rec_R[0] = R; rec_chosen[0] = pk_min0; }
        }
        for (int step = 1; step < NMERGE; ++step) {
            const int cl = L - 1, cr = R + 1;
            const bool hasL = (cl >= 0);
            const bool hasR = (cr < S_TOT);
            float4 xl0 = {0,0,0,0}, xl1 = {0,0,0,0}, xr0 = {0,0,0,0}, xr1 = {0,0,0,0};
            double il = INF, ir = INF;
            if (hasL) {
                il = s_imp[cl];
                const int rlm = F.s_map[cl - mbase];
                if (rlm >= 0) { const float4* g = (const float4*)&F.stage[rlm][0];
                                xl0 = g[2 * lane]; xl1 = g[2 * lane + 1]; }
                else          { const float4* g = (const float4*)slot_gptr(cl, b, bank, refresh);
                                xl0 = g[2 * lane]; xl1 = g[2 * lane + 1]; }
            }
            if (hasR) {
                ir = s_imp[cr];
                const int rrm = F.s_map[cr - mbase];
                if (rrm >= 0) { const float4* g = (const float4*)&F.stage[rrm][0];
                                xr0 = g[2 * lane]; xr1 = g[2 * lane + 1]; }
                else          { const float4* g = (const float4*)slot_gptr(cr, b, bank, refresh);
                                xr0 = g[2 * lane]; xr1 = g[2 * lane + 1]; }
            }
            const u64 pkL = hasL ? pack_score(il + nrm, cl) : DEADPK;  // (imp_pv + nrm, pv)
            const u64 pkR = hasR ? pack_score(nrm + ir, L)  : DEADPK;  // (nrm + imp_nk, L)
            const bool goL = (pkL < pkR);
            const u64 chosen = goL ? pkL : pkR;
            float4 a0, a1, b0, b1;
            if (goL) { a0 = xl0; a1 = xl1; b0 = m0r; b1 = m1r; L = cl; }
            else     { a0 = m0r; a1 = m1r; b0 = xr0; b1 = xr1; R = cr; }
            m0r.x = 0.5f * (a0.x + b0.x); m0r.y = 0.5f * (a0.y + b0.y);
            m0r.z = 0.5f * (a0.z + b0.z); m0r.w = 0.5f * (a0.w + b0.w);
            m1r.x = 0.5f * (a1.x + b1.x); m1r.y = 0.5f * (a1.y + b1.y);
            m1r.z = 0.5f * (a1.z + b1.z); m1r.w = 0.5f * (a1.w + b1.w);
            double ss = 0.0;
            ss += (double)m0r.x * m0r.x + (double)m0r.y * m0r.y + (double)m0r.z * m0r.z + (double)m0r.w * m0r.w;
            ss += (double)m1r.x * m1r.x + (double)m1r.y * m1r.y + (double)m1r.z * m1r.z + (double)m1r.w * m1r.w;
            nrm = sqrt(sum_wave(ss));
            if (t == 0) { rec_L[step] = L; rec_R[step] = R; rec_chosen[step] = chosen; }
        }
        __syncthreads();

        // ---- validation precompute (window = chunks ws..ws+2) ----
        if (wid < 3) {
            int c = ws + wid;
            int idx = c * 64 + lane;
            u64 pk0 = (idx <= S_TOT - 2) ? pack_score(s_imp[idx] + s_imp[idx + 1], idx)
                                         : DEADPK;
            F.pref[idx - wlo] = scan_min_incl(pk0);
            F.suf[idx - wlo]  = scan_min_suffix(pk0, lane);
        }
        if (wid == 3) {
            // PL: chunks < ws ; SR: chunks > ws+2
            u64 x0 = (lane < ws) ? c_pk[lane] : DEADPK;
            u64 x1 = (lane + 64 < ws) ? c_pk[lane + 64] : DEADPK;
            u64 pl = (x0 < x1) ? x0 : x1;
            pl = lexmin_wave_u64(pl);
            u64 y0 = (lane > ws + 2) ? c_pk[lane] : DEADPK;
            u64 y1 = (lane + 64 > ws + 2) ? c_pk[lane + 64] : DEADPK;
            u64 y2 = (lane == 0 && 128 > ws + 2) ? c_pk[128] : DEADPK;
            u64 sr = (y0 < y1) ? y0 : y1;
            sr = (sr < y2) ? sr : y2;
            sr = lexmin_wave_u64(sr);
            if (lane == 0) { s_PL = pl; s_SR = sr; }
        }
        __syncthreads();

        // ---- per-step exact checks (wave 0) ----
        if (wid == 0) {
            u64 cf0 = F.pref[63], cf1 = F.pref[127];
            u64 sf1 = F.suf[64],  sf2 = F.suf[128];
            u64 PL = s_PL, SR = s_SR;
            bool ok = true;
            if (lane >= 1 && lane < NMERGE) {
                int Lp = rec_L[lane - 1], Rp = rec_R[lane - 1];   // pre-state of step `lane`
                int q1 = Lp - 2 - wlo;
                u64 ol = DEADPK;
                if (q1 >= 0) {
                    ol = F.pref[q1];
                    int r1 = q1 >> 6;
                    if (r1 >= 1 && cf0 < ol) ol = cf0;
                    if (r1 >= 2 && cf1 < ol) ol = cf1;
                }
                if (PL < ol) ol = PL;
                int q2 = Rp + 1 - wlo;                            // in [1, 192)
                u64 orr = F.suf[q2];
                int r2 = q2 >> 6;
                if (r2 <= 0 && sf1 < orr) orr = sf1;
                if (r2 <= 1 && sf2 < orr) orr = sf2;
                if (SR < orr) orr = SR;
                u64 O = (ol < orr) ? ol : orr;
                ok = rec_chosen[lane] < O;
            }
            if (lane == 0) ok = ok && (rec_R[NMERGE - 1] - rec_L[NMERGE - 1] == NMERGE);
            unsigned long long bad = __ballot(!ok);
            if (lane == 0) s_flag = (bad != 0ULL) ? 1 : 0;
        }
        __syncthreads();

        if (s_flag == 0) {
            // ---- fast epilogue ----
            if (wid == 0) {
                float4* dst = (float4*)(merged + ((size_t)b * NMERGE + (NMERGE - 1)) * D);
                dst[2 * lane] = m0r; dst[2 * lane + 1] = m1r;
            }
            const int Ls = rec_L[NMERGE - 1], Rs = rec_R[NMERGE - 1];
            for (int j = t; j < S_TOT; j += 256) {
                if (j < Ls)       idx_out[b * S_BANK + j] = (unsigned short)j;
                else if (j == Ls) idx_out[b * S_BANK + j] = (unsigned short)(S_TOT + NMERGE - 1);
                else if (j > Rs)  idx_out[b * S_BANK + j - NMERGE] = (unsigned short)j;
            }
            do_fall = 0;
        }
    }

    // ================= FALLBACK: full v11 path (verbatim) ====================
    if (do_fall) {
        FallLds& G = u.fall;
        // load the FULL imp array (fast path only staged the window)
        for (int j = t; j < S_TOT; j += 256)
            s_imp[j] = norms[b * S_TOT + j];
        for (int j = t; j < S_TOT; j += 256)
            G.s_next[j] = (unsigned short)((j + 1 < S_TOT) ? (j + 1) : 0xFFFF);
        __syncthreads();

        if (wid == 0) {
            u64 cv0 = c_pk[lane];
            u64 cv1 = c_pk[lane + 64];
            u64 cv2 = (lane == 0) ? c_pk[128] : DEADPK;

            int mpos_reg = -1;
            int prev_p = -1, prev_pv = -1, prev_nk = -1;
            int pvok = 0, nkok = 0;
            float4 mm0, mm1, pva0, pva1, pnk0, pnk1;

            for (int step = 0; step < NMERGE; ++step) {
                u64 m = (cv0 < cv1) ? cv0 : cv1;
                m = (m < cv2) ? m : cv2;
                m = lexmin_wave_u64(m);
                const int p = (int)(m & 0x3FFFULL);

                const bool hitA = pvok && (p == prev_pv);
                const bool hitB = nkok && (p == prev_p);

                int k, nk;
                float4 a0, a1, b0, b1;
                if (hitA) {
                    k = prev_p; nk = prev_nk;
                    a0 = pva0; a1 = pva1; b0 = mm0; b1 = mm1;
                } else if (hitB) {
                    k = prev_nk; nk = G.s_next[k];
                    a0 = mm0; a1 = mm1; b0 = pnk0; b1 = pnk1;
                } else {
                    k = G.s_next[p]; nk = G.s_next[k];
                    unsigned long long bA = __ballot((lane < step) && (mpos_reg == p));
                    const int ia = bA ? (S_TOT + 63 - __clzll(bA)) : p;
                    unsigned long long bB = __ballot((lane < step) && (mpos_reg == k));
                    const int ib = bB ? (S_TOT + 63 - __clzll(bB)) : k;
                    if (ia < S_TOT) { const float4* g = (const float4*)slot_gptr(ia, b, bank, refresh);
                                      a0 = g[2 * lane]; a1 = g[2 * lane + 1]; }
                    else            { const float4* g = (const float4*)&G.s_mvec[ia - S_TOT][0];
                                      a0 = g[2 * lane]; a1 = g[2 * lane + 1]; }
                    if (ib < S_TOT) { const float4* g = (const float4*)slot_gptr(ib, b, bank, refresh);
                                      b0 = g[2 * lane]; b1 = g[2 * lane + 1]; }
                    else            { const float4* g = (const float4*)&G.s_mvec[ib - S_TOT][0];
                                      b0 = g[2 * lane]; b1 = g[2 * lane + 1]; }
                }

                int pv;
                if (hitB) {
                    pv = prev_pv;
                } else {
                    int jq = p - 1 - lane;
                    bool plive = (jq >= 0) && (s_imp[jq] < 1e300);
                    unsigned long long pb = __ballot(plive);
                    pv = pb ? (p - __ffsll((unsigned long long)pb)) : -1;
                }

                const double imp_nk = s_imp[(nk != 0xFFFF) ? nk : 0];
                const double imp_pv = s_imp[(pv >= 0) ? pv : 0];
                const int chp = p >> 6, chk = k >> 6;
                const int chv = (pv >= 0) ? (pv >> 6) : -1;
                const int csB = (chk != chp) ? chk : -1;
                const int csC = (chv >= 0 && chv != chp && chv != chk) ? chv : -1;
                const int jjA = chp * 64 + lane;
                const bool validA = (jjA < S_TOT) && (jjA != k);
                const int rawNxtA = validA ? (int)G.s_next[jjA] : 0xFFFF;
                const double impA = validA ? s_imp[jjA] : INF;
                const int nxtA = (jjA == p) ? nk : rawNxtA;
                const double impNxtA = (nxtA != 0xFFFF) ? s_imp[nxtA] : INF;

                float4 m0, m1;
                m0.x = 0.5f * (a0.x + b0.x); m0.y = 0.5f * (a0.y + b0.y);
                m0.z = 0.5f * (a0.z + b0.z); m0.w = 0.5f * (a0.w + b0.w);
                m1.x = 0.5f * (a1.x + b1.x); m1.y = 0.5f * (a1.y + b1.y);
                m1.z = 0.5f * (a1.z + b1.z); m1.w = 0.5f * (a1.w + b1.w);
                {
                    float4* dst = (float4*)&G.s_mvec[step][0];
                    dst[2 * lane] = m0; dst[2 * lane + 1] = m1;
                }
                if (lane == step) mpos_reg = p;

                if (step + 1 < NMERGE) {
                    prev_p = p; prev_pv = pv; prev_nk = nk;
                    mm0 = m0; mm1 = m1;
                    pvok = (pv >= 0); nkok = (nk != 0xFFFF);
                    unsigned long long bpv = __ballot((lane <= step) && (mpos_reg == pv));
                    const int ipv = bpv ? (S_TOT + 63 - __clzll(bpv)) : pv;
                    unsigned long long bnk = __ballot((lane <= step) && (mpos_reg == nk));
                    const int ink = bnk ? (S_TOT + 63 - __clzll(bnk)) : nk;
                    if (pvok) {
                        if (ipv < S_TOT) { const float4* g = (const float4*)slot_gptr(ipv, b, bank, refresh);
                                           pva0 = g[2 * lane]; pva1 = g[2 * lane + 1]; }
                        else             { const float4* g = (const float4*)&G.s_mvec[ipv - S_TOT][0];
                                           pva0 = g[2 * lane]; pva1 = g[2 * lane + 1]; }
                    }
                    if (nkok) {
                        if (ink < S_TOT) { const float4* g = (const float4*)slot_gptr(ink, b, bank, refresh);
                                           pnk0 = g[2 * lane]; pnk1 = g[2 * lane + 1]; }
                        else             { const float4* g = (const float4*)&G.s_mvec[ink - S_TOT][0];
                                           pnk0 = g[2 * lane]; pnk1 = g[2 * lane + 1]; }
                    }
                }

                double ss = 0.0;
                ss += (double)m0.x * m0.x + (double)m0.y * m0.y + (double)m0.z * m0.z + (double)m0.w * m0.w;
                ss += (double)m1.x * m1.x + (double)m1.y * m1.y + (double)m1.z * m1.z + (double)m1.w * m1.w;
                const double nrm = sqrt(sum_wave(ss));

                if (lane == 0) {
                    G.s_next[p]    = (unsigned short)nk;
                    s_imp[k]       = INF;
                    s_imp[p]       = nrm;
                    G.s_mpos[step] = (unsigned short)p;
                    G.s_dead[step] = (unsigned short)k;
                }

                {
                    u64 sc = DEADPK;
                    if (validA && nxtA != 0xFFFF) {
                        double a0d = (jjA == p) ? nrm : impA;
                        if (a0d < 1e300) {
                            double a1d = (nxtA == p) ? nrm : impNxtA;
                            sc = pack_score(a0d + a1d, jjA);
                        }
                    }
                    sc = lexmin_wave_u64(sc);
                    if (chp < 64)       { if (lane == chp)      cv0 = sc; }
                    else if (chp < 128) { if (lane == chp - 64) cv1 = sc; }
                    else                { if (lane == 0)        cv2 = sc; }
                }
                if (csB >= 0) {
                    int jj = csB * 64 + lane;
                    u64 sc = DEADPK;
                    if (jj < S_TOT && jj != k) {
                        int nxt = (int)G.s_next[jj];
                        if (nxt != 0xFFFF) {
                            double a0d = s_imp[jj];
                            if (a0d < 1e300) sc = pack_score(a0d + s_imp[nxt], jj);
                        }
                    }
                    sc = lexmin_wave_u64(sc);
                    if (csB < 64)       { if (lane == csB)      cv0 = sc; }
                    else if (csB < 128) { if (lane == csB - 64) cv1 = sc; }
                    else                { if (lane == 0)        cv2 = sc; }
                }
                if (csC >= 0) {
                    int jj = csC * 64 + lane;
                    u64 sc = DEADPK;
                    if (jj < S_TOT && jj != k) {
                        int nxt = (int)G.s_next[jj];
                        if (nxt != 0xFFFF) {
                            double a0d = s_imp[jj];
                            if (a0d < 1e300) sc = pack_score(a0d + s_imp[nxt], jj);
                        }
                    }
                    sc = lexmin_wave_u64(sc);
                    if (csC < 64)       { if (lane == csC)      cv0 = sc; }
                    else if (csC < 128) { if (lane == csC - 64) cv1 = sc; }
                    else                { if (lane == 0)        cv2 = sc; }
                }
            }
        }
        __syncthreads();

        {
            const float4* src = (const float4*)&G.s_mvec[0][0];
            float4* dst = (float4*)(merged + (size_t)b * NMERGE * D);
            for (int i = t; i < NMERGE * D / 4; i += 256) dst[i] = src[i];
        }
        for (int j = t; j < S_TOT; j += 256) G.s_next[j] = 0xFFFF;
        __syncthreads();
        if (t == 0)
            for (int m2 = 0; m2 < NMERGE; ++m2) G.s_next[G.s_mpos[m2]] = (unsigned short)m2;
        __syncthreads();
        for (int j = t; j < S_TOT; j += 256) {
            if (s_imp[j] < 1e300) {
                int r = j;
                #pragma unroll
                for (int m2 = 0; m2 < NMERGE; ++m2) r -= (G.s_dead[m2] < j) ? 1 : 0;
                unsigned short lut = G.s_next[j];
                idx_out[b * S_BANK + r] = (lut != 0xFFFF) ? (unsigned short)(S_TOT + lut)
                                                          : (unsigned short)j;
            }
        }
    }
}

// ---------------- Kernel 3: gather/write output (float4, NT stores) ----------
__global__ __launch_bounds__(256) void gather_kernel(const vfloat4* __restrict__ bank,
        const vfloat4* __restrict__ refresh, const vfloat4* __restrict__ merged,
        const unsigned short* __restrict__ idx, vfloat4* __restrict__ out) {
    size_t tid = (size_t)blockIdx.x * 256 + threadIdx.x;
    int slot = (int)(tid >> 7);
    int c    = (int)(tid & 127);
    int b    = slot >> 13;
    int src  = idx[slot];
    const vfloat4* sp;
    if (src < S_BANK)     sp = bank    + ((size_t)b * S_BANK + src) * (D / 4);
    else if (src < S_TOT) sp = refresh + ((size_t)b * S_REF + (src - S_BANK)) * (D / 4);
    else                  sp = merged  + ((size_t)b * NMERGE + (src - S_TOT)) * (D / 4);
    vfloat4 v = sp[c];
    __builtin_nontemporal_store(v, &out[tid]);
}

// ------------------------------------------------------------------------------
extern "C" void kernel_launch(void* const* d_in, const int* in_sizes, int n_in,
                              void* d_out, int out_size, void* d_ws, size_t ws_size,
                              hipStream_t stream) {
    const float* bank    = (const float*)d_in[0];
    const float* refresh = (const float*)d_in[1];

    double*         norms  = (double*)d_ws;
    float*          merged = (float*)((char*)d_ws + (size_t)B_DIM * S_TOT * sizeof(double));
    unsigned short* idx    = (unsigned short*)((char*)merged + (size_t)B_DIM * NMERGE * D * sizeof(float));
    u64*            c_pk_g = (u64*)((char*)idx + (size_t)B_DIM * S_BANK * sizeof(unsigned short));
    float*          out    = (float*)d_out;

    norms_kernel<<<(B_DIM * S_TOT) / 4, 256, 0, stream>>>(bank, refresh, norms);
    chunkmin_kernel<<<(B_DIM * NCH * 64 + 255) / 256, 256, 0, stream>>>(norms, c_pk_g);
    merge_kernel<<<B_DIM, 256, 0, stream>>>(bank, refresh, norms, c_pk_g, merged, idx);
    gather_kernel<<<(size_t)B_DIM * S_BANK * (D / 4) / 256, 256, 0, stream>>>(
        (const vfloat4*)bank, (const vfloat4*)refresh, (const vfloat4*)merged, idx, (vfloat4*)out);
}

// Round 13
// 144.948 us; speedup vs baseline: 2.4951x; 1.0294x over previous
//
#include <hip/hip_runtime.h>
#include <cstdint>
#include <cstddef>

#define B_DIM  16
#define S_BANK 8192
#define S_REF  32
#define S_TOT  8224   // S_BANK + S_REF
#define NMERGE 32     // S_TOT - MAX_SLOTS
#define D      512
#define NCH    129    // ceil(S_TOT / 64)

typedef float vfloat4 __attribute__((ext_vector_type(4)));  // NT-store capable
typedef unsigned long long u64;
#define DEADPK 0xFFFFFFFFFFFFFFFFULL   // +inf sentinel in u64 ordering

// ---------------- bit helpers ------------------------------------------------
__device__ __forceinline__ int d_lo(double d){ union{double d; int i[2];}u; u.d=d; return u.i[0]; }
__device__ __forceinline__ int d_hi(double d){ union{double d; int i[2];}u; u.d=d; return u.i[1]; }
__device__ __forceinline__ double d_mk(int hi,int lo){ union{double d; int i[2];}u; u.i[0]=lo;u.i[1]=hi; return u.d; }
__device__ __forceinline__ int u_lo(u64 v){ return (int)(v & 0xFFFFFFFFULL); }
__device__ __forceinline__ int u_hi(u64 v){ return (int)(v >> 32); }
__device__ __forceinline__ u64 u_mk(int hi,int lo){ return ((u64)(unsigned)hi << 32) | (u64)(unsigned)lo; }
__device__ __forceinline__ u64 d_bits(double d){ union{double d; u64 u;}x; x.d=d; return x.u; }

// pack (positive f64 score, idx<16384) into one sortable u64 (low 14 mantissa
// bits replaced by idx => unsigned compare == lexicographic (score,idx)).
__device__ __forceinline__ u64 pack_score(double s, int j) {
    return (d_bits(s) & ~0x3FFFULL) | (u64)(unsigned)j;
}

// ---------------- DPP wave64 reductions / scans (VALU pipe) ------------------
template<int CTRL, int ROWM>
__device__ __forceinline__ u64 dpp_u64(u64 v) {
    int lo = __builtin_amdgcn_update_dpp(u_lo(v), u_lo(v), CTRL, ROWM, 0xF, false);
    int hi = __builtin_amdgcn_update_dpp(u_hi(v), u_hi(v), CTRL, ROWM, 0xF, false);
    return u_mk(hi, lo);
}
__device__ __forceinline__ u64 rl_u64(u64 v, int l) {
    int lo = __builtin_amdgcn_readlane(u_lo(v), l);
    int hi = __builtin_amdgcn_readlane(u_hi(v), l);
    return u_mk(hi, lo);
}
// reduction min over 64 lanes, broadcast
__device__ __forceinline__ u64 lexmin_wave_u64(u64 v) {
    u64 w;
    w = dpp_u64<0x111,0xF>(v); if (w < v) v = w;
    w = dpp_u64<0x112,0xF>(v); if (w < v) v = w;
    w = dpp_u64<0x114,0xF>(v); if (w < v) v = w;
    w = dpp_u64<0x118,0xF>(v); if (w < v) v = w;
    w = dpp_u64<0x142,0xF>(v); if (w < v) v = w;
    w = dpp_u64<0x143,0xF>(v); if (w < v) v = w;
    return rl_u64(v, 63);
}
// inclusive prefix-min scan (ascending lanes)
__device__ __forceinline__ u64 scan_min_incl(u64 v) {
    u64 w;
    w = dpp_u64<0x111,0xF>(v); if (w < v) v = w;   // row_shr:1
    w = dpp_u64<0x112,0xF>(v); if (w < v) v = w;
    w = dpp_u64<0x114,0xF>(v); if (w < v) v = w;
    w = dpp_u64<0x118,0xF>(v); if (w < v) v = w;
    w = dpp_u64<0x142,0xA>(v); if (w < v) v = w;   // bcast15 -> rows 1,3
    w = dpp_u64<0x143,0xC>(v); if (w < v) v = w;   // bcast31 -> rows 2,3
    return v;
}
// inclusive suffix-min scan (descending)
__device__ __forceinline__ u64 scan_min_suffix(u64 v, int lane) {
    u64 w;
    w = dpp_u64<0x101,0xF>(v); if (w < v) v = w;   // row_shl:1
    w = dpp_u64<0x102,0xF>(v); if (w < v) v = w;
    w = dpp_u64<0x104,0xF>(v); if (w < v) v = w;
    w = dpp_u64<0x108,0xF>(v); if (w < v) v = w;
    // v[l] = min over [l .. row_end]; fold in later rows:
    u64 t16 = rl_u64(v, 16), t32 = rl_u64(v, 32), t48 = rl_u64(v, 48);
    u64 s3 = t48;
    u64 s2 = (t32 < s3) ? t32 : s3;
    u64 s1 = (t16 < s2) ? t16 : s2;
    int row = lane >> 4;
    u64 add = (row == 0) ? s1 : (row == 1) ? s2 : (row == 2) ? s3 : DEADPK;
    if (add < v) v = add;
    return v;
}
template<int CTRL>
__device__ __forceinline__ void sum_level(double& v) {
    int lo2 = __builtin_amdgcn_update_dpp(0, d_lo(v), CTRL, 0xF, 0xF, true);
    int hi2 = __builtin_amdgcn_update_dpp(0, d_hi(v), CTRL, 0xF, 0xF, true);
    v += d_mk(hi2, lo2);
}
__device__ __forceinline__ double sum_wave(double v) {
    sum_level<0x111>(v); sum_level<0x112>(v); sum_level<0x114>(v);
    sum_level<0x118>(v); sum_level<0x142>(v); sum_level<0x143>(v);
    int lo = __builtin_amdgcn_readlane(d_lo(v), 63);
    int hi = __builtin_amdgcn_readlane(d_hi(v), 63);
    return d_mk(hi, lo);
}

// ---------------- Kernel 1: per-slot L2 norms (f64), reverse order -----------
__global__ __launch_bounds__(256) void norms_kernel(const float* __restrict__ bank,
                                                    const float* __restrict__ refresh,
                                                    double* __restrict__ norms) {
    int gw_lin = (int)((blockIdx.x * 256 + threadIdx.x) >> 6);
    int gw   = B_DIM * S_TOT - 1 - gw_lin;
    int lane = threadIdx.x & 63;
    int b = gw / S_TOT;
    int s = gw - b * S_TOT;
    const float4* src = (const float4*)(s < S_BANK
        ? bank    + ((size_t)b * S_BANK + s) * D
        : refresh + ((size_t)b * S_REF + (s - S_BANK)) * D);
    float4 f0 = src[lane];
    float4 f1 = src[lane + 64];
    double acc = 0.0;
    acc += (double)f0.x * f0.x + (double)f0.y * f0.y + (double)f0.z * f0.z + (double)f0.w * f0.w;
    acc += (double)f1.x * f1.x + (double)f1.y * f1.y + (double)f1.z * f1.z + (double)f1.w * f1.w;
    acc = sum_wave(acc);
    if (lane == 0) norms[gw] = sqrt(acc);
}

// ---------------- Kernel 1.5: packed chunk minima (parallel, whole chip) -----
__global__ __launch_bounds__(256) void chunkmin_kernel(const double* __restrict__ norms,
                                                       u64* __restrict__ c_pk_g) {
    int w    = (int)((blockIdx.x * 256 + threadIdx.x) >> 6);
    int lane = threadIdx.x & 63;
    if (w >= B_DIM * NCH) return;
    int b = w / NCH;
    int c = w - b * NCH;
    int j = c * 64 + lane;
    u64 pk = DEADPK;
    if (j <= S_TOT - 2) {
        double a = norms[b * S_TOT + j];
        double d = norms[b * S_TOT + j + 1];
        pk = pack_score(a + d, j);
    }
    pk = lexmin_wave_u64(pk);
    if (lane == 0) c_pk_g[b * NCH + c] = pk;
}

// ---------------- Kernel 2: merge-v15 — reg-prefetch walk, parallel valid ----
__device__ __forceinline__ const float* slot_gptr(int id, int b,
        const float* bank, const float* refresh) {
    return (id < S_BANK) ? bank    + ((size_t)b * S_BANK + id) * D
                         : refresh + ((size_t)b * S_REF + (id - S_BANK)) * D;
}

struct FastLds {
    u64 pref[192];       // prefix-min of original pk over 3-chunk window
    u64 suf[192];        // suffix-min
};
struct FallLds {
    unsigned short s_next[S_TOT];
    float          s_mvec[NMERGE][D];
    unsigned short s_mpos[NMERGE];
    unsigned short s_dead[NMERGE];
};
union MergeLds { FastLds fast; FallLds fall; };

__global__ __launch_bounds__(256) void merge_kernel(const float* __restrict__ bank,
        const float* __restrict__ refresh, const double* __restrict__ norms,
        const u64* __restrict__ c_pk_g,
        float* __restrict__ merged, unsigned short* __restrict__ idx_out) {
    __shared__ double  s_imp[S_TOT];   // fast path: only the window is populated
    __shared__ u64     c_pk[NCH];      // original packed chunk minima
    __shared__ MergeLds u;
    __shared__ int     rec_L[NMERGE], rec_R[NMERGE];
    __shared__ u64     rec_chosen[NMERGE];
    __shared__ u64     s_PL, s_SR;
    __shared__ int     s_flag;

    const int t    = threadIdx.x;
    const int b    = blockIdx.x;
    const int lane = t & 63;
    const int wid  = t >> 6;
    const double INF = __builtin_inf();

    // ---- prologue: chunk minima from global (tiny) ----
    if (t < NCH) c_pk[t] = c_pk_g[b * NCH + t];
    __syncthreads();

    // ---- global argmin p0 (all waves redundantly; uniform) ----
    u64 pk_min0;
    {
        u64 a = c_pk[lane];
        u64 bq = c_pk[lane + 64];
        u64 c = (lane == 0) ? c_pk[128] : DEADPK;
        u64 m = (a < bq) ? a : bq;
        m = (m < c) ? m : c;
        pk_min0 = lexmin_wave_u64(m);
    }
    const int p0 = (int)(pk_min0 & 0x3FFFULL);

    // window chunks (clamped) — fixed for this block
    const int cmid = p0 >> 6;
    int wsx = cmid - 1;
    if (wsx < 0) wsx = 0;
    if (wsx > NCH - 3) wsx = NCH - 3;
    const int ws  = wsx;
    const int wlo = ws * 64;

    // walk results (wave 0 registers; persist across barriers)
    float4 m0r, m1r;

    int do_fall = 1;
    {
        FastLds& F = u.fast;

        // ---- stage ONLY the window imps (194 doubles) ----
        for (int j = t; j < 194; j += 256) {
            int g = wlo + j;
            if (g < S_TOT) s_imp[g] = norms[b * S_TOT + g];
        }
        __syncthreads();

        if (wid == 0) {
            // ======== wave 0: the cascade walk (register prefetch pipeline) ==
            // initial pair vectors
            const float4* gA = (const float4*)slot_gptr(p0, b, bank, refresh);
            const float4* gB = (const float4*)slot_gptr(p0 + 1, b, bank, refresh);
            float4 a0 = gA[2 * lane], a1 = gA[2 * lane + 1];
            float4 b0 = gB[2 * lane], b1 = gB[2 * lane + 1];
            // candidate + in-flight prefetch buffers (clamped; unused at edges)
            int q;
            q = (p0 - 1 >= 0) ? p0 - 1 : 0;
            const float4* gq = (const float4*)slot_gptr(q, b, bank, refresh);
            float4 cL0 = gq[2 * lane], cL1 = gq[2 * lane + 1];     // vec(L-1)
            q = (p0 + 2 <= S_TOT - 1) ? p0 + 2 : S_TOT - 1;
            gq = (const float4*)slot_gptr(q, b, bank, refresh);
            float4 cR0 = gq[2 * lane], cR1 = gq[2 * lane + 1];     // vec(R+1)
            q = (p0 - 2 >= 0) ? p0 - 2 : 0;
            gq = (const float4*)slot_gptr(q, b, bank, refresh);
            float4 fL0 = gq[2 * lane], fL1 = gq[2 * lane + 1];     // vec(L-2)
            q = (p0 + 3 <= S_TOT - 1) ? p0 + 3 : S_TOT - 1;
            gq = (const float4*)slot_gptr(q, b, bank, refresh);
            float4 fR0 = gq[2 * lane], fR1 = gq[2 * lane + 1];     // vec(R+2)

            // step 0: merge (identical arithmetic/order)
            m0r.x = 0.5f * (a0.x + b0.x); m0r.y = 0.5f * (a0.y + b0.y);
            m0r.z = 0.5f * (a0.z + b0.z); m0r.w = 0.5f * (a0.w + b0.w);
            m1r.x = 0.5f * (a1.x + b1.x); m1r.y = 0.5f * (a1.y + b1.y);
            m1r.z = 0.5f * (a1.z + b1.z); m1r.w = 0.5f * (a1.w + b1.w);
            double ss = 0.0;
            ss += (double)m0r.x * m0r.x + (double)m0r.y * m0r.y + (double)m0r.z * m0r.z + (double)m0r.w * m0r.w;
            ss += (double)m1r.x * m1r.x + (double)m1r.y * m1r.y + (double)m1r.z * m1r.z + (double)m1r.w * m1r.w;
            double nrm = sqrt(sum_wave(ss));
            int L = p0, R = p0 + 1;
            if (t == 0) { rec_L[0] = L; rec_R[0] = R; rec_chosen[0] = pk_min0; }

            for (int step = 1; step < NMERGE; ++step) {
                const int cl = L - 1, cr = R + 1;
                const bool hasL = (cl >= 0);
                const bool hasR = (cr < S_TOT);
                const double il = hasL ? s_imp[cl] : INF;
                const double ir = hasR ? s_imp[cr] : INF;
                const u64 pkL = hasL ? pack_score(il + nrm, cl) : DEADPK;  // (imp_pv + nrm, pv)
                const u64 pkR = hasR ? pack_score(nrm + ir, L)  : DEADPK;  // (nrm + imp_nk, L)
                const bool goL = (pkL < pkR);
                const u64 chosen = goL ? pkL : pkR;
                float4 a0s, a1s, b0s, b1s;
                if (goL) { a0s = cL0; a1s = cL1; b0s = m0r; b1s = m1r; }
                else     { a0s = m0r; a1s = m1r; b0s = cR0; b1s = cR1; }
                m0r.x = 0.5f * (a0s.x + b0s.x); m0r.y = 0.5f * (a0s.y + b0s.y);
                m0r.z = 0.5f * (a0s.z + b0s.z); m0r.w = 0.5f * (a0s.w + b0s.w);
                m1r.x = 0.5f * (a1s.x + b1s.x); m1r.y = 0.5f * (a1s.y + b1s.y);
                m1r.z = 0.5f * (a1s.z + b1s.z); m1r.w = 0.5f * (a1s.w + b1s.w);
                // promote prefetch, issue next load (off the value chain)
                if (goL) {
                    L = cl;
                    cL0 = fL0; cL1 = fL1;
                    int nq = (L - 2 >= 0) ? L - 2 : 0;
                    const float4* gp = (const float4*)slot_gptr(nq, b, bank, refresh);
                    fL0 = gp[2 * lane]; fL1 = gp[2 * lane + 1];
                } else {
                    R = cr;
                    cR0 = fR0; cR1 = fR1;
                    int nq = (R + 2 <= S_TOT - 1) ? R + 2 : S_TOT - 1;
                    const float4* gp = (const float4*)slot_gptr(nq, b, bank, refresh);
                    fR0 = gp[2 * lane]; fR1 = gp[2 * lane + 1];
                }
                double ss2 = 0.0;
                ss2 += (double)m0r.x * m0r.x + (double)m0r.y * m0r.y + (double)m0r.z * m0r.z + (double)m0r.w * m0r.w;
                ss2 += (double)m1r.x * m1r.x + (double)m1r.y * m1r.y + (double)m1r.z * m1r.z + (double)m1r.w * m1r.w;
                nrm = sqrt(sum_wave(ss2));
                if (t == 0) { rec_L[step] = L; rec_R[step] = R; rec_chosen[step] = chosen; }
            }
        } else {
            // ======== waves 1-3: validation precompute, CONCURRENT with walk =
            // (reads only the staged window + c_pk — no race with the walk)
            int c = ws + (wid - 1);
            int idx = c * 64 + lane;
            u64 pk0 = (idx <= S_TOT - 2) ? pack_score(s_imp[idx] + s_imp[idx + 1], idx)
                                         : DEADPK;
            F.pref[idx - wlo] = scan_min_incl(pk0);
            F.suf[idx - wlo]  = scan_min_suffix(pk0, lane);
            if (wid == 1) {
                // PL: chunks < ws
                u64 x0 = (lane < ws) ? c_pk[lane] : DEADPK;
                u64 x1 = (lane + 64 < ws) ? c_pk[lane + 64] : DEADPK;
                u64 pl = (x0 < x1) ? x0 : x1;
                pl = lexmin_wave_u64(pl);
                if (lane == 0) s_PL = pl;
            }
            if (wid == 2) {
                // SR: chunks > ws+2
                u64 y0 = (lane > ws + 2) ? c_pk[lane] : DEADPK;
                u64 y1 = (lane + 64 > ws + 2) ? c_pk[lane + 64] : DEADPK;
                u64 y2 = (lane == 0 && 128 > ws + 2) ? c_pk[128] : DEADPK;
                u64 sr = (y0 < y1) ? y0 : y1;
                sr = (sr < y2) ? sr : y2;
                sr = lexmin_wave_u64(sr);
                if (lane == 0) s_SR = sr;
            }
        }
        __syncthreads();

        // ---- per-step exact checks (wave 0) ----
        if (wid == 0) {
            u64 cf0 = F.pref[63], cf1 = F.pref[127];
            u64 sf1 = F.suf[64],  sf2 = F.suf[128];
            u64 PL = s_PL, SR = s_SR;
            bool ok = true;
            if (lane >= 1 && lane < NMERGE) {
                int Lp = rec_L[lane - 1], Rp = rec_R[lane - 1];   // pre-state of step `lane`
                int q1 = Lp - 2 - wlo;
                u64 ol = DEADPK;
                if (q1 >= 0) {
                    ol = F.pref[q1];
                    int r1 = q1 >> 6;
                    if (r1 >= 1 && cf0 < ol) ol = cf0;
                    if (r1 >= 2 && cf1 < ol) ol = cf1;
                }
                if (PL < ol) ol = PL;
                int q2 = Rp + 1 - wlo;                            // in [1, 192)
                u64 orr = F.suf[q2];
                int r2 = q2 >> 6;
                if (r2 <= 0 && sf1 < orr) orr = sf1;
                if (r2 <= 1 && sf2 < orr) orr = sf2;
                if (SR < orr) orr = SR;
                u64 O = (ol < orr) ? ol : orr;
                ok = rec_chosen[lane] < O;
            }
            if (lane == 0) ok = ok && (rec_R[NMERGE - 1] - rec_L[NMERGE - 1] == NMERGE);
            unsigned long long bad = __ballot(!ok);
            if (lane == 0) s_flag = (bad != 0ULL) ? 1 : 0;
        }
        __syncthreads();

        if (s_flag == 0) {
            // ---- fast epilogue ----
            if (wid == 0) {
                float4* dst = (float4*)(merged + ((size_t)b * NMERGE + (NMERGE - 1)) * D);
                dst[2 * lane] = m0r; dst[2 * lane + 1] = m1r;
            }
            const int Ls = rec_L[NMERGE - 1], Rs = rec_R[NMERGE - 1];
            for (int j = t; j < S_TOT; j += 256) {
                if (j < Ls)       idx_out[b * S_BANK + j] = (unsigned short)j;
                else if (j == Ls) idx_out[b * S_BANK + j] = (unsigned short)(S_TOT + NMERGE - 1);
                else if (j > Rs)  idx_out[b * S_BANK + j - NMERGE] = (unsigned short)j;
            }
            do_fall = 0;
        }
    }

    // ================= FALLBACK: full v11 path (verbatim) ====================
    if (do_fall) {
        FallLds& G = u.fall;
        // load the FULL imp array (fast path only staged the window)
        for (int j = t; j < S_TOT; j += 256)
            s_imp[j] = norms[b * S_TOT + j];
        for (int j = t; j < S_TOT; j += 256)
            G.s_next[j] = (unsigned short)((j + 1 < S_TOT) ? (j + 1) : 0xFFFF);
        __syncthreads();

        if (wid == 0) {
            u64 cv0 = c_pk[lane];
            u64 cv1 = c_pk[lane + 64];
            u64 cv2 = (lane == 0) ? c_pk[128] : DEADPK;

            int mpos_reg = -1;
            int prev_p = -1, prev_pv = -1, prev_nk = -1;
            int pvok = 0, nkok = 0;
            float4 mm0, mm1, pva0, pva1, pnk0, pnk1;

            for (int step = 0; step < NMERGE; ++step) {
                u64 m = (cv0 < cv1) ? cv0 : cv1;
                m = (m < cv2) ? m : cv2;
                m = lexmin_wave_u64(m);
                const int p = (int)(m & 0x3FFFULL);

                const bool hitA = pvok && (p == prev_pv);
                const bool hitB = nkok && (p == prev_p);

                int k, nk;
                float4 a0, a1, b0, b1;
                if (hitA) {
                    k = prev_p; nk = prev_nk;
                    a0 = pva0; a1 = pva1; b0 = mm0; b1 = mm1;
                } else if (hitB) {
                    k = prev_nk; nk = G.s_next[k];
                    a0 = mm0; a1 = mm1; b0 = pnk0; b1 = pnk1;
                } else {
                    k = G.s_next[p]; nk = G.s_next[k];
                    unsigned long long bA = __ballot((lane < step) && (mpos_reg == p));
                    const int ia = bA ? (S_TOT + 63 - __clzll(bA)) : p;
                    unsigned long long bB = __ballot((lane < step) && (mpos_reg == k));
                    const int ib = bB ? (S_TOT + 63 - __clzll(bB)) : k;
                    if (ia < S_TOT) { const float4* g = (const float4*)slot_gptr(ia, b, bank, refresh);
                                      a0 = g[2 * lane]; a1 = g[2 * lane + 1]; }
                    else            { const float4* g = (const float4*)&G.s_mvec[ia - S_TOT][0];
                                      a0 = g[2 * lane]; a1 = g[2 * lane + 1]; }
                    if (ib < S_TOT) { const float4* g = (const float4*)slot_gptr(ib, b, bank, refresh);
                                      b0 = g[2 * lane]; b1 = g[2 * lane + 1]; }
                    else            { const float4* g = (const float4*)&G.s_mvec[ib - S_TOT][0];
                                      b0 = g[2 * lane]; b1 = g[2 * lane + 1]; }
                }

                int pv;
                if (hitB) {
                    pv = prev_pv;
                } else {
                    int jq = p - 1 - lane;
                    bool plive = (jq >= 0) && (s_imp[jq] < 1e300);
                    unsigned long long pb = __ballot(plive);
                    pv = pb ? (p - __ffsll((unsigned long long)pb)) : -1;
                }

                const double imp_nk = s_imp[(nk != 0xFFFF) ? nk : 0];
                const double imp_pv = s_imp[(pv >= 0) ? pv : 0];
                const int chp = p >> 6, chk = k >> 6;
                const int chv = (pv >= 0) ? (pv >> 6) : -1;
                const int csB = (chk != chp) ? chk : -1;
                const int csC = (chv >= 0 && chv != chp && chv != chk) ? chv : -1;
                const int jjA = chp * 64 + lane;
                const bool validA = (jjA < S_TOT) && (jjA != k);
                const int rawNxtA = validA ? (int)G.s_next[jjA] : 0xFFFF;
                const double impA = validA ? s_imp[jjA] : INF;
                const int nxtA = (jjA == p) ? nk : rawNxtA;
                const double impNxtA = (nxtA != 0xFFFF) ? s_imp[nxtA] : INF;

                float4 m0, m1;
                m0.x = 0.5f * (a0.x + b0.x); m0.y = 0.5f * (a0.y + b0.y);
                m0.z = 0.5f * (a0.z + b0.z); m0.w = 0.5f * (a0.w + b0.w);
                m1.x = 0.5f * (a1.x + b1.x); m1.y = 0.5f * (a1.y + b1.y);
                m1.z = 0.5f * (a1.z + b1.z); m1.w = 0.5f * (a1.w + b1.w);
                {
                    float4* dst = (float4*)&G.s_mvec[step][0];
                    dst[2 * lane] = m0; dst[2 * lane + 1] = m1;
                }
                if (lane == step) mpos_reg = p;

                if (step + 1 < NMERGE) {
                    prev_p = p; prev_pv = pv; prev_nk = nk;
                    mm0 = m0; mm1 = m1;
                    pvok = (pv >= 0); nkok = (nk != 0xFFFF);
                    unsigned long long bpv = __ballot((lane <= step) && (mpos_reg == pv));
                    const int ipv = bpv ? (S_TOT + 63 - __clzll(bpv)) : pv;
                    unsigned long long bnk = __ballot((lane <= step) && (mpos_reg == nk));
                    const int ink = bnk ? (S_TOT + 63 - __clzll(bnk)) : nk;
                    if (pvok) {
                        if (ipv < S_TOT) { const float4* g = (const float4*)slot_gptr(ipv, b, bank, refresh);
                                           pva0 = g[2 * lane]; pva1 = g[2 * lane + 1]; }
                        else             { const float4* g = (const float4*)&G.s_mvec[ipv - S_TOT][0];
                                           pva0 = g[2 * lane]; pva1 = g[2 * lane + 1]; }
                    }
                    if (nkok) {
                        if (ink < S_TOT) { const float4* g = (const float4*)slot_gptr(ink, b, bank, refresh);
                                           pnk0 = g[2 * lane]; pnk1 = g[2 * lane + 1]; }
                        else             { const float4* g = (const float4*)&G.s_mvec[ink - S_TOT][0];
                                           pnk0 = g[2 * lane]; pnk1 = g[2 * lane + 1]; }
                    }
                }

                double ss = 0.0;
                ss += (double)m0.x * m0.x + (double)m0.y * m0.y + (double)m0.z * m0.z + (double)m0.w * m0.w;
                ss += (double)m1.x * m1.x + (double)m1.y * m1.y + (double)m1.z * m1.z + (double)m1.w * m1.w;
                const double nrm = sqrt(sum_wave(ss));

                if (lane == 0) {
                    G.s_next[p]    = (unsigned short)nk;
                    s_imp[k]       = INF;
                    s_imp[p]       = nrm;
                    G.s_mpos[step] = (unsigned short)p;
                    G.s_dead[step] = (unsigned short)k;
                }

                {
                    u64 sc = DEADPK;
                    if (validA && nxtA != 0xFFFF) {
                        double a0d = (jjA == p) ? nrm : impA;
                        if (a0d < 1e300) {
                            double a1d = (nxtA == p) ? nrm : impNxtA;
                            sc = pack_score(a0d + a1d, jjA);
                        }
                    }
                    sc = lexmin_wave_u64(sc);
                    if (chp < 64)       { if (lane == chp)      cv0 = sc; }
                    else if (chp < 128) { if (lane == chp - 64) cv1 = sc; }
                    else                { if (lane == 0)        cv2 = sc; }
                }
                if (csB >= 0) {
                    int jj = csB * 64 + lane;
                    u64 sc = DEADPK;
                    if (jj < S_TOT && jj != k) {
                        int nxt = (int)G.s_next[jj];
                        if (nxt != 0xFFFF) {
                            double a0d = s_imp[jj];
                            if (a0d < 1e300) sc = pack_score(a0d + s_imp[nxt], jj);
                        }
                    }
                    sc = lexmin_wave_u64(sc);
                    if (csB < 64)       { if (lane == csB)      cv0 = sc; }
                    else if (csB < 128) { if (lane == csB - 64) cv1 = sc; }
                    else                { if (lane == 0)        cv2 = sc; }
                }
                if (csC >= 0) {
                    int jj = csC * 64 + lane;
                    u64 sc = DEADPK;
                    if (jj < S_TOT && jj != k) {
                        int nxt = (int)G.s_next[jj];
                        if (nxt != 0xFFFF) {
                            double a0d = s_imp[jj];
                            if (a0d < 1e300) sc = pack_score(a0d + s_imp[nxt], jj);
                        }
                    }
                    sc = lexmin_wave_u64(sc);
                    if (csC < 64)       { if (lane == csC)      cv0 = sc; }
                    else if (csC < 128) { if (lane == csC - 64) cv1 = sc; }
                    else                { if (lane == 0)        cv2 = sc; }
                }
            }
        }
        __syncthreads();

        {
            const float4* src = (const float4*)&G.s_mvec[0][0];
            float4* dst = (float4*)(merged + (size_t)b * NMERGE * D);
            for (int i = t; i < NMERGE * D / 4; i += 256) dst[i] = src[i];
        }
        for (int j = t; j < S_TOT; j += 256) G.s_next[j] = 0xFFFF;
        __syncthreads();
        if (t == 0)
            for (int m2 = 0; m2 < NMERGE; ++m2) G.s_next[G.s_mpos[m2]] = (unsigned short)m2;
        __syncthreads();
        for (int j = t; j < S_TOT; j += 256) {
            if (s_imp[j] < 1e300) {
                int r = j;
                #pragma unroll
                for (int m2 = 0; m2 < NMERGE; ++m2) r -= (G.s_dead[m2] < j) ? 1 : 0;
                unsigned short lut = G.s_next[j];
                idx_out[b * S_BANK + r] = (lut != 0xFFFF) ? (unsigned short)(S_TOT + lut)
                                                          : (unsigned short)j;
            }
        }
    }
}

// ---------------- Kernel 3: gather/write output (float4, NT stores) ----------
__global__ __launch_bounds__(256) void gather_kernel(const vfloat4* __restrict__ bank,
        const vfloat4* __restrict__ refresh, const vfloat4* __restrict__ merged,
        const unsigned short* __restrict__ idx, vfloat4* __restrict__ out) {
    size_t tid = (size_t)blockIdx.x * 256 + threadIdx.x;
    int slot = (int)(tid >> 7);
    int c    = (int)(tid & 127);
    int b    = slot >> 13;
    int src  = idx[slot];
    const vfloat4* sp;
    if (src < S_BANK)     sp = bank    + ((size_t)b * S_BANK + src) * (D / 4);
    else if (src < S_TOT) sp = refresh + ((size_t)b * S_REF + (src - S_BANK)) * (D / 4);
    else                  sp = merged  + ((size_t)b * NMERGE + (src - S_TOT)) * (D / 4);
    vfloat4 v = sp[c];
    __builtin_nontemporal_store(v, &out[tid]);
}

// ------------------------------------------------------------------------------
extern "C" void kernel_launch(void* const* d_in, const int* in_sizes, int n_in,
                              void* d_out, int out_size, void* d_ws, size_t ws_size,
                              hipStream_t stream) {
    const float* bank    = (const float*)d_in[0];
    const float* refresh = (const float*)d_in[1];

    double*         norms  = (double*)d_ws;
    float*          merged = (float*)((char*)d_ws + (size_t)B_DIM * S_TOT * sizeof(double));
    unsigned short* idx    = (unsigned short*)((char*)merged + (size_t)B_DIM * NMERGE * D * sizeof(float));
    u64*            c_pk_g = (u64*)((char*)idx + (size_t)B_DIM * S_BANK * sizeof(unsigned short));
    float*          out    = (float*)d_out;

    norms_kernel<<<(B_DIM * S_TOT) / 4, 256, 0, stream>>>(bank, refresh, norms);
    chunkmin_kernel<<<(B_DIM * NCH * 64 + 255) / 256, 256, 0, stream>>>(norms, c_pk_g);
    merge_kernel<<<B_DIM, 256, 0, stream>>>(bank, refresh, norms, c_pk_g, merged, idx);
    gather_kernel<<<(size_t)B_DIM * S_BANK * (D / 4) / 256, 256, 0, stream>>>(
        (const vfloat4*)bank, (const vfloat4*)refresh, (const vfloat4*)merged, idx, (vfloat4*)out);
}

// Round 14
// 131.181 us; speedup vs baseline: 2.7570x; 1.1049x over previous
//
#include <hip/hip_runtime.h>
#include <cstdint>
#include <cstddef>

#define B_DIM  16
#define S_BANK 8192
#define S_REF  32
#define S_TOT  8224   // S_BANK + S_REF
#define NMERGE 32     // S_TOT - MAX_SLOTS
#define D      512
#define NCH    129    // ceil(S_TOT / 64)

typedef float vfloat4 __attribute__((ext_vector_type(4)));  // NT-store capable
typedef unsigned long long u64;
#define DEADPK 0xFFFFFFFFFFFFFFFFULL   // +inf sentinel in u64 ordering

// ---------------- bit helpers ------------------------------------------------
__device__ __forceinline__ int d_lo(double d){ union{double d; int i[2];}u; u.d=d; return u.i[0]; }
__device__ __forceinline__ int d_hi(double d){ union{double d; int i[2];}u; u.d=d; return u.i[1]; }
__device__ __forceinline__ double d_mk(int hi,int lo){ union{double d; int i[2];}u; u.i[0]=lo;u.i[1]=hi; return u.d; }
__device__ __forceinline__ int u_lo(u64 v){ return (int)(v & 0xFFFFFFFFULL); }
__device__ __forceinline__ int u_hi(u64 v){ return (int)(v >> 32); }
__device__ __forceinline__ u64 u_mk(int hi,int lo){ return ((u64)(unsigned)hi << 32) | (u64)(unsigned)lo; }
__device__ __forceinline__ u64 d_bits(double d){ union{double d; u64 u;}x; x.d=d; return x.u; }

// pack (positive f64 score, idx<16384) into one sortable u64 (low 14 mantissa
// bits replaced by idx => unsigned compare == lexicographic (score,idx)).
__device__ __forceinline__ u64 pack_score(double s, int j) {
    return (d_bits(s) & ~0x3FFFULL) | (u64)(unsigned)j;
}

// ---------------- DPP wave64 reductions / scans (VALU pipe) ------------------
template<int CTRL, int ROWM>
__device__ __forceinline__ u64 dpp_u64(u64 v) {
    int lo = __builtin_amdgcn_update_dpp(u_lo(v), u_lo(v), CTRL, ROWM, 0xF, false);
    int hi = __builtin_amdgcn_update_dpp(u_hi(v), u_hi(v), CTRL, ROWM, 0xF, false);
    return u_mk(hi, lo);
}
__device__ __forceinline__ u64 rl_u64(u64 v, int l) {
    int lo = __builtin_amdgcn_readlane(u_lo(v), l);
    int hi = __builtin_amdgcn_readlane(u_hi(v), l);
    return u_mk(hi, lo);
}
// reduction min over 64 lanes, broadcast
__device__ __forceinline__ u64 lexmin_wave_u64(u64 v) {
    u64 w;
    w = dpp_u64<0x111,0xF>(v); if (w < v) v = w;
    w = dpp_u64<0x112,0xF>(v); if (w < v) v = w;
    w = dpp_u64<0x114,0xF>(v); if (w < v) v = w;
    w = dpp_u64<0x118,0xF>(v); if (w < v) v = w;
    w = dpp_u64<0x142,0xF>(v); if (w < v) v = w;
    w = dpp_u64<0x143,0xF>(v); if (w < v) v = w;
    return rl_u64(v, 63);
}
// inclusive prefix-min scan (ascending lanes)
__device__ __forceinline__ u64 scan_min_incl(u64 v) {
    u64 w;
    w = dpp_u64<0x111,0xF>(v); if (w < v) v = w;   // row_shr:1
    w = dpp_u64<0x112,0xF>(v); if (w < v) v = w;
    w = dpp_u64<0x114,0xF>(v); if (w < v) v = w;
    w = dpp_u64<0x118,0xF>(v); if (w < v) v = w;
    w = dpp_u64<0x142,0xA>(v); if (w < v) v = w;   // bcast15 -> rows 1,3
    w = dpp_u64<0x143,0xC>(v); if (w < v) v = w;   // bcast31 -> rows 2,3
    return v;
}
// inclusive suffix-min scan (descending)
__device__ __forceinline__ u64 scan_min_suffix(u64 v, int lane) {
    u64 w;
    w = dpp_u64<0x101,0xF>(v); if (w < v) v = w;   // row_shl:1
    w = dpp_u64<0x102,0xF>(v); if (w < v) v = w;
    w = dpp_u64<0x104,0xF>(v); if (w < v) v = w;
    w = dpp_u64<0x108,0xF>(v); if (w < v) v = w;
    u64 t16 = rl_u64(v, 16), t32 = rl_u64(v, 32), t48 = rl_u64(v, 48);
    u64 s3 = t48;
    u64 s2 = (t32 < s3) ? t32 : s3;
    u64 s1 = (t16 < s2) ? t16 : s2;
    int row = lane >> 4;
    u64 add = (row == 0) ? s1 : (row == 1) ? s2 : (row == 2) ? s3 : DEADPK;
    if (add < v) v = add;
    return v;
}
template<int CTRL>
__device__ __forceinline__ void sum_level(double& v) {
    int lo2 = __builtin_amdgcn_update_dpp(0, d_lo(v), CTRL, 0xF, 0xF, true);
    int hi2 = __builtin_amdgcn_update_dpp(0, d_hi(v), CTRL, 0xF, 0xF, true);
    v += d_mk(hi2, lo2);
}
__device__ __forceinline__ double sum_wave(double v) {
    sum_level<0x111>(v); sum_level<0x112>(v); sum_level<0x114>(v);
    sum_level<0x118>(v); sum_level<0x142>(v); sum_level<0x143>(v);
    int lo = __builtin_amdgcn_readlane(d_lo(v), 63);
    int hi = __builtin_amdgcn_readlane(d_hi(v), 63);
    return d_mk(hi, lo);
}

// ---------------- Kernel 1: per-slot L2 norms (f64), reverse order -----------
__global__ __launch_bounds__(256) void norms_kernel(const float* __restrict__ bank,
                                                    const float* __restrict__ refresh,
                                                    double* __restrict__ norms) {
    int gw_lin = (int)((blockIdx.x * 256 + threadIdx.x) >> 6);
    int gw   = B_DIM * S_TOT - 1 - gw_lin;
    int lane = threadIdx.x & 63;
    int b = gw / S_TOT;
    int s = gw - b * S_TOT;
    const float4* src = (const float4*)(s < S_BANK
        ? bank    + ((size_t)b * S_BANK + s) * D
        : refresh + ((size_t)b * S_REF + (s - S_BANK)) * D);
    float4 f0 = src[lane];
    float4 f1 = src[lane + 64];
    double acc = 0.0;
    acc += (double)f0.x * f0.x + (double)f0.y * f0.y + (double)f0.z * f0.z + (double)f0.w * f0.w;
    acc += (double)f1.x * f1.x + (double)f1.y * f1.y + (double)f1.z * f1.z + (double)f1.w * f1.w;
    acc = sum_wave(acc);
    if (lane == 0) norms[gw] = sqrt(acc);
}

// ---------------- Kernel 1.5: packed chunk minima (parallel, whole chip) -----
__global__ __launch_bounds__(256) void chunkmin_kernel(const double* __restrict__ norms,
                                                       u64* __restrict__ c_pk_g) {
    int w    = (int)((blockIdx.x * 256 + threadIdx.x) >> 6);
    int lane = threadIdx.x & 63;
    if (w >= B_DIM * NCH) return;
    int b = w / NCH;
    int c = w - b * NCH;
    int j = c * 64 + lane;
    u64 pk = DEADPK;
    if (j <= S_TOT - 2) {
        double a = norms[b * S_TOT + j];
        double d = norms[b * S_TOT + j + 1];
        pk = pack_score(a + d, j);
    }
    pk = lexmin_wave_u64(pk);
    if (lane == 0) c_pk_g[b * NCH + c] = pk;
}

// ---------------- Kernel 2: fused walk + bulk gather -------------------------
__device__ __forceinline__ const float* slot_gptr(int id, int b,
        const float* bank, const float* refresh) {
    return (id < S_BANK) ? bank    + ((size_t)b * S_BANK + id) * D
                         : refresh + ((size_t)b * S_REF + (id - S_BANK)) * D;
}

#define NBULK (B_DIM * 4096)   // 65536 bulk blocks (2 output rows each)

__global__ __launch_bounds__(256) void fused_kernel(const float* __restrict__ bank,
        const float* __restrict__ refresh, const double* __restrict__ norms,
        const u64* __restrict__ c_pk_g, int* __restrict__ flag_g,
        vfloat4* __restrict__ out) {
    // small LDS (shared by both roles; keeps bulk occupancy high)
    __shared__ double s_wimp[194];     // window imps, index g - wlo
    __shared__ u64    c_pk[NCH];
    __shared__ u64    pref[192], suf[192];
    __shared__ int    rec_L[NMERGE], rec_R[NMERGE];
    __shared__ u64    rec_chosen[NMERGE];
    __shared__ u64    s_PL, s_SR;
    __shared__ int    s_flag;
    __shared__ int    sh_p0;

    const int t    = threadIdx.x;
    const int lane = t & 63;
    const int wid  = t >> 6;
    const double INF = __builtin_inf();

    if (blockIdx.x >= 16) {
        // ================= BULK GATHER BLOCK =================
        int e  = blockIdx.x - 16;
        int b  = e >> 12;                 // 4096 blocks per batch
        int pr = (e & 4095) << 1;         // rows pr, pr+1 (same batch)
        if (wid == 0) {                   // p0 via wave-argmin over L2-hot c_pk_g
            u64 a  = (lane < NCH) ? c_pk_g[b * NCH + lane] : DEADPK;
            u64 b2 = (lane + 64 < NCH) ? c_pk_g[b * NCH + lane + 64] : DEADPK;
            u64 m = (a < b2) ? a : b2;
            u64 c2 = (lane == 0) ? c_pk_g[b * NCH + 128] : DEADPK;
            m = (m < c2) ? m : c2;
            m = lexmin_wave_u64(m);
            if (lane == 0) sh_p0 = (int)(m & 0x3FFFULL);
        }
        __syncthreads();
        const int p0 = sh_p0;
        int r = pr + (t >> 7);
        int c = t & 127;
        // rows outside the 32-row ambiguous zone [p0-31, p0] are walk-independent
        int s = -1;
        if (r < p0 - 31)      s = r;
        else if (r > p0)      s = r + 32;
        if (s >= 0) {
            const vfloat4* sp = (const vfloat4*)slot_gptr(s, b, bank, refresh);
            vfloat4 v = sp[c];
            __builtin_nontemporal_store(v, &out[((size_t)b * S_BANK + r) * (D / 4) + c]);
        }
        return;
    }

    // ================= WALK BLOCK (b = blockIdx.x) =================
    const int b = blockIdx.x;

    if (t < NCH) c_pk[t] = c_pk_g[b * NCH + t];
    __syncthreads();

    u64 pk_min0;
    {
        u64 a = c_pk[lane];
        u64 bq = c_pk[lane + 64];
        u64 c = (lane == 0) ? c_pk[128] : DEADPK;
        u64 m = (a < bq) ? a : bq;
        m = (m < c) ? m : c;
        pk_min0 = lexmin_wave_u64(m);
    }
    const int p0 = (int)(pk_min0 & 0x3FFFULL);

    const int cmid = p0 >> 6;
    int wsx = cmid - 1;
    if (wsx < 0) wsx = 0;
    if (wsx > NCH - 3) wsx = NCH - 3;
    const int ws  = wsx;
    const int wlo = ws * 64;

    // stage ONLY the window imps (194 doubles)
    for (int j = t; j < 194; j += 256) {
        int g = wlo + j;
        if (g < S_TOT) s_wimp[j] = norms[b * S_TOT + g];
    }
    __syncthreads();

    float4 m0r, m1r;           // final merged vector (wave 0)

    if (wid == 0) {
        // ---- wave 0: cascade walk with register prefetch pipeline ----
        const float4* gA = (const float4*)slot_gptr(p0, b, bank, refresh);
        const float4* gB = (const float4*)slot_gptr(p0 + 1, b, bank, refresh);
        float4 a0 = gA[2 * lane], a1 = gA[2 * lane + 1];
        float4 b0 = gB[2 * lane], b1 = gB[2 * lane + 1];
        int q;
        q = (p0 - 1 >= 0) ? p0 - 1 : 0;
        const float4* gq = (const float4*)slot_gptr(q, b, bank, refresh);
        float4 cL0 = gq[2 * lane], cL1 = gq[2 * lane + 1];
        q = (p0 + 2 <= S_TOT - 1) ? p0 + 2 : S_TOT - 1;
        gq = (const float4*)slot_gptr(q, b, bank, refresh);
        float4 cR0 = gq[2 * lane], cR1 = gq[2 * lane + 1];
        q = (p0 - 2 >= 0) ? p0 - 2 : 0;
        gq = (const float4*)slot_gptr(q, b, bank, refresh);
        float4 fL0 = gq[2 * lane], fL1 = gq[2 * lane + 1];
        q = (p0 + 3 <= S_TOT - 1) ? p0 + 3 : S_TOT - 1;
        gq = (const float4*)slot_gptr(q, b, bank, refresh);
        float4 fR0 = gq[2 * lane], fR1 = gq[2 * lane + 1];

        m0r.x = 0.5f * (a0.x + b0.x); m0r.y = 0.5f * (a0.y + b0.y);
        m0r.z = 0.5f * (a0.z + b0.z); m0r.w = 0.5f * (a0.w + b0.w);
        m1r.x = 0.5f * (a1.x + b1.x); m1r.y = 0.5f * (a1.y + b1.y);
        m1r.z = 0.5f * (a1.z + b1.z); m1r.w = 0.5f * (a1.w + b1.w);
        double ss = 0.0;
        ss += (double)m0r.x * m0r.x + (double)m0r.y * m0r.y + (double)m0r.z * m0r.z + (double)m0r.w * m0r.w;
        ss += (double)m1r.x * m1r.x + (double)m1r.y * m1r.y + (double)m1r.z * m1r.z + (double)m1r.w * m1r.w;
        double nrm = sqrt(sum_wave(ss));
        int L = p0, R = p0 + 1;
        if (t == 0) { rec_L[0] = L; rec_R[0] = R; rec_chosen[0] = pk_min0; }

        for (int step = 1; step < NMERGE; ++step) {
            const int cl = L - 1, cr = R + 1;
            const bool hasL = (cl >= 0);
            const bool hasR = (cr < S_TOT);
            const double il = hasL ? s_wimp[cl - wlo] : INF;
            const double ir = hasR ? s_wimp[cr - wlo] : INF;
            const u64 pkL = hasL ? pack_score(il + nrm, cl) : DEADPK;
            const u64 pkR = hasR ? pack_score(nrm + ir, L)  : DEADPK;
            const bool goL = (pkL < pkR);
            const u64 chosen = goL ? pkL : pkR;
            float4 a0s, a1s, b0s, b1s;
            if (goL) { a0s = cL0; a1s = cL1; b0s = m0r; b1s = m1r; }
            else     { a0s = m0r; a1s = m1r; b0s = cR0; b1s = cR1; }
            m0r.x = 0.5f * (a0s.x + b0s.x); m0r.y = 0.5f * (a0s.y + b0s.y);
            m0r.z = 0.5f * (a0s.z + b0s.z); m0r.w = 0.5f * (a0s.w + b0s.w);
            m1r.x = 0.5f * (a1s.x + b1s.x); m1r.y = 0.5f * (a1s.y + b1s.y);
            m1r.z = 0.5f * (a1s.z + b1s.z); m1r.w = 0.5f * (a1s.w + b1s.w);
            if (goL) {
                L = cl;
                cL0 = fL0; cL1 = fL1;
                int nq = (L - 2 >= 0) ? L - 2 : 0;
                const float4* gp = (const float4*)slot_gptr(nq, b, bank, refresh);
                fL0 = gp[2 * lane]; fL1 = gp[2 * lane + 1];
            } else {
                R = cr;
                cR0 = fR0; cR1 = fR1;
                int nq = (R + 2 <= S_TOT - 1) ? R + 2 : S_TOT - 1;
                const float4* gp = (const float4*)slot_gptr(nq, b, bank, refresh);
                fR0 = gp[2 * lane]; fR1 = gp[2 * lane + 1];
            }
            double ss2 = 0.0;
            ss2 += (double)m0r.x * m0r.x + (double)m0r.y * m0r.y + (double)m0r.z * m0r.z + (double)m0r.w * m0r.w;
            ss2 += (double)m1r.x * m1r.x + (double)m1r.y * m1r.y + (double)m1r.z * m1r.z + (double)m1r.w * m1r.w;
            nrm = sqrt(sum_wave(ss2));
            if (t == 0) { rec_L[step] = L; rec_R[step] = R; rec_chosen[step] = chosen; }
        }
    } else {
        // ---- waves 1-3: validation precompute, CONCURRENT with walk ----
        int c = ws + (wid - 1);
        int idx = c * 64 + lane;
        u64 pk0 = (idx <= S_TOT - 2)
                    ? pack_score(s_wimp[idx - wlo] + s_wimp[idx + 1 - wlo], idx)
                    : DEADPK;
        pref[idx - wlo] = scan_min_incl(pk0);
        suf[idx - wlo]  = scan_min_suffix(pk0, lane);
        if (wid == 1) {
            u64 x0 = (lane < ws) ? c_pk[lane] : DEADPK;
            u64 x1 = (lane + 64 < ws) ? c_pk[lane + 64] : DEADPK;
            u64 pl = (x0 < x1) ? x0 : x1;
            pl = lexmin_wave_u64(pl);
            if (lane == 0) s_PL = pl;
        }
        if (wid == 2) {
            u64 y0 = (lane > ws + 2) ? c_pk[lane] : DEADPK;
            u64 y1 = (lane + 64 > ws + 2) ? c_pk[lane + 64] : DEADPK;
            u64 y2 = (lane == 0 && 128 > ws + 2) ? c_pk[128] : DEADPK;
            u64 sr = (y0 < y1) ? y0 : y1;
            sr = (sr < y2) ? sr : y2;
            sr = lexmin_wave_u64(sr);
            if (lane == 0) s_SR = sr;
        }
    }
    __syncthreads();

    // ---- per-step exact checks (wave 0) ----
    if (wid == 0) {
        u64 cf0 = pref[63], cf1 = pref[127];
        u64 sf1 = suf[64],  sf2 = suf[128];
        u64 PL = s_PL, SR = s_SR;
        bool ok = true;
        if (lane >= 1 && lane < NMERGE) {
            int Lp = rec_L[lane - 1], Rp = rec_R[lane - 1];
            int q1 = Lp - 2 - wlo;
            u64 ol = DEADPK;
            if (q1 >= 0) {
                ol = pref[q1];
                int r1 = q1 >> 6;
                if (r1 >= 1 && cf0 < ol) ol = cf0;
                if (r1 >= 2 && cf1 < ol) ol = cf1;
            }
            if (PL < ol) ol = PL;
            int q2 = Rp + 1 - wlo;
            u64 orr = suf[q2];
            int r2 = q2 >> 6;
            if (r2 <= 0 && sf1 < orr) orr = sf1;
            if (r2 <= 1 && sf2 < orr) orr = sf2;
            if (SR < orr) orr = SR;
            u64 O = (ol < orr) ? ol : orr;
            ok = rec_chosen[lane] < O;
        }
        if (lane == 0) ok = ok && (rec_R[NMERGE - 1] - rec_L[NMERGE - 1] == NMERGE);
        unsigned long long bad = __ballot(!ok);
        if (lane == 0) s_flag = (bad != 0ULL) ? 1 : 0;
    }
    __syncthreads();

    if (t == 0) flag_g[b] = s_flag;
    if (s_flag != 0) return;            // fallback kernel redoes this batch

    // ---- fast epilogue: write merged row + ambiguous rows directly ----
    const int Ls = rec_L[NMERGE - 1];
    if (wid == 0) {
        vfloat4 v0, v1;
        v0.x = m0r.x; v0.y = m0r.y; v0.z = m0r.z; v0.w = m0r.w;
        v1.x = m1r.x; v1.y = m1r.y; v1.z = m1r.z; v1.w = m1r.w;
        __builtin_nontemporal_store(v0, &out[((size_t)b * S_BANK + Ls) * (D / 4) + 2 * lane]);
        __builtin_nontemporal_store(v1, &out[((size_t)b * S_BANK + Ls) * (D / 4) + 2 * lane + 1]);
    }
    const int lo = (p0 - 31 > 0) ? p0 - 31 : 0;
    const int hi = (p0 < S_BANK - 1) ? p0 : S_BANK - 1;
    for (int r = lo + wid; r <= hi; r += 4) {
        if (r == Ls) continue;
        int s = (r < Ls) ? r : r + 32;
        const vfloat4* sp = (const vfloat4*)slot_gptr(s, b, bank, refresh);
        vfloat4 v0 = sp[2 * lane], v1 = sp[2 * lane + 1];
        __builtin_nontemporal_store(v0, &out[((size_t)b * S_BANK + r) * (D / 4) + 2 * lane]);
        __builtin_nontemporal_store(v1, &out[((size_t)b * S_BANK + r) * (D / 4) + 2 * lane + 1]);
    }
}

// ---------------- Kernel 3: fallback (v11 merge + full-batch gather) ---------
struct FallLds {
    unsigned short s_next[S_TOT];
    float          s_mvec[NMERGE][D];
    unsigned short s_mpos[NMERGE];
    unsigned short s_dead[NMERGE];
};

__global__ __launch_bounds__(256) void fallback_kernel(const float* __restrict__ bank,
        const float* __restrict__ refresh, const double* __restrict__ norms,
        const u64* __restrict__ c_pk_g, const int* __restrict__ flag_g,
        unsigned short* __restrict__ idx_out, vfloat4* __restrict__ out) {
    const int b = blockIdx.x;
    if (flag_g[b] == 0) return;

    __shared__ double  s_imp[S_TOT];
    __shared__ u64     c_pk[NCH];
    __shared__ FallLds G;

    const int t    = threadIdx.x;
    const int lane = t & 63;
    const int wid  = t >> 6;
    const double INF = __builtin_inf();

    if (t < NCH) c_pk[t] = c_pk_g[b * NCH + t];
    for (int j = t; j < S_TOT; j += 256) {
        s_imp[j] = norms[b * S_TOT + j];
        G.s_next[j] = (unsigned short)((j + 1 < S_TOT) ? (j + 1) : 0xFFFF);
    }
    __syncthreads();

    if (wid == 0) {
        u64 cv0 = c_pk[lane];
        u64 cv1 = c_pk[lane + 64];
        u64 cv2 = (lane == 0) ? c_pk[128] : DEADPK;

        int mpos_reg = -1;
        int prev_p = -1, prev_pv = -1, prev_nk = -1;
        int pvok = 0, nkok = 0;
        float4 mm0, mm1, pva0, pva1, pnk0, pnk1;

        for (int step = 0; step < NMERGE; ++step) {
            u64 m = (cv0 < cv1) ? cv0 : cv1;
            m = (m < cv2) ? m : cv2;
            m = lexmin_wave_u64(m);
            const int p = (int)(m & 0x3FFFULL);

            const bool hitA = pvok && (p == prev_pv);
            const bool hitB = nkok && (p == prev_p);

            int k, nk;
            float4 a0, a1, b0, b1;
            if (hitA) {
                k = prev_p; nk = prev_nk;
                a0 = pva0; a1 = pva1; b0 = mm0; b1 = mm1;
            } else if (hitB) {
                k = prev_nk; nk = G.s_next[k];
                a0 = mm0; a1 = mm1; b0 = pnk0; b1 = pnk1;
            } else {
                k = G.s_next[p]; nk = G.s_next[k];
                unsigned long long bA = __ballot((lane < step) && (mpos_reg == p));
                const int ia = bA ? (S_TOT + 63 - __clzll(bA)) : p;
                unsigned long long bB = __ballot((lane < step) && (mpos_reg == k));
                const int ib = bB ? (S_TOT + 63 - __clzll(bB)) : k;
                if (ia < S_TOT) { const float4* g = (const float4*)slot_gptr(ia, b, bank, refresh);
                                  a0 = g[2 * lane]; a1 = g[2 * lane + 1]; }
                else            { const float4* g = (const float4*)&G.s_mvec[ia - S_TOT][0];
                                  a0 = g[2 * lane]; a1 = g[2 * lane + 1]; }
                if (ib < S_TOT) { const float4* g = (const float4*)slot_gptr(ib, b, bank, refresh);
                                  b0 = g[2 * lane]; b1 = g[2 * lane + 1]; }
                else            { const float4* g = (const float4*)&G.s_mvec[ib - S_TOT][0];
                                  b0 = g[2 * lane]; b1 = g[2 * lane + 1]; }
            }

            int pv;
            if (hitB) {
                pv = prev_pv;
            } else {
                int jq = p - 1 - lane;
                bool plive = (jq >= 0) && (s_imp[jq] < 1e300);
                unsigned long long pb = __ballot(plive);
                pv = pb ? (p - __ffsll((unsigned long long)pb)) : -1;
            }

            const double imp_nk = s_imp[(nk != 0xFFFF) ? nk : 0];
            const double imp_pv = s_imp[(pv >= 0) ? pv : 0];
            const int chp = p >> 6, chk = k >> 6;
            const int chv = (pv >= 0) ? (pv >> 6) : -1;
            const int csB = (chk != chp) ? chk : -1;
            const int csC = (chv >= 0 && chv != chp && chv != chk) ? chv : -1;
            const int jjA = chp * 64 + lane;
            const bool validA = (jjA < S_TOT) && (jjA != k);
            const int rawNxtA = validA ? (int)G.s_next[jjA] : 0xFFFF;
            const double impA = validA ? s_imp[jjA] : INF;
            const int nxtA = (jjA == p) ? nk : rawNxtA;
            const double impNxtA = (nxtA != 0xFFFF) ? s_imp[nxtA] : INF;

            float4 m0, m1;
            m0.x = 0.5f * (a0.x + b0.x); m0.y = 0.5f * (a0.y + b0.y);
            m0.z = 0.5f * (a0.z + b0.z); m0.w = 0.5f * (a0.w + b0.w);
            m1.x = 0.5f * (a1.x + b1.x); m1.y = 0.5f * (a1.y + b1.y);
            m1.z = 0.5f * (a1.z + b1.z); m1.w = 0.5f * (a1.w + b1.w);
            {
                float4* dst = (float4*)&G.s_mvec[step][0];
                dst[2 * lane] = m0; dst[2 * lane + 1] = m1;
            }
            if (lane == step) mpos_reg = p;

            if (step + 1 < NMERGE) {
                prev_p = p; prev_pv = pv; prev_nk = nk;
                mm0 = m0; mm1 = m1;
                pvok = (pv >= 0); nkok = (nk != 0xFFFF);
                unsigned long long bpv = __ballot((lane <= step) && (mpos_reg == pv));
                const int ipv = bpv ? (S_TOT + 63 - __clzll(bpv)) : pv;
                unsigned long long bnk = __ballot((lane <= step) && (mpos_reg == nk));
                const int ink = bnk ? (S_TOT + 63 - __clzll(bnk)) : nk;
                if (pvok) {
                    if (ipv < S_TOT) { const float4* g = (const float4*)slot_gptr(ipv, b, bank, refresh);
                                       pva0 = g[2 * lane]; pva1 = g[2 * lane + 1]; }
                    else             { const float4* g = (const float4*)&G.s_mvec[ipv - S_TOT][0];
                                       pva0 = g[2 * lane]; pva1 = g[2 * lane + 1]; }
                }
                if (nkok) {
                    if (ink < S_TOT) { const float4* g = (const float4*)slot_gptr(ink, b, bank, refresh);
                                       pnk0 = g[2 * lane]; pnk1 = g[2 * lane + 1]; }
                    else             { const float4* g = (const float4*)&G.s_mvec[ink - S_TOT][0];
                                       pnk0 = g[2 * lane]; pnk1 = g[2 * lane + 1]; }
                }
            }

            double ss = 0.0;
            ss += (double)m0.x * m0.x + (double)m0.y * m0.y + (double)m0.z * m0.z + (double)m0.w * m0.w;
            ss += (double)m1.x * m1.x + (double)m1.y * m1.y + (double)m1.z * m1.z + (double)m1.w * m1.w;
            const double nrm = sqrt(sum_wave(ss));

            if (lane == 0) {
                G.s_next[p]    = (unsigned short)nk;
                s_imp[k]       = INF;
                s_imp[p]       = nrm;
                G.s_mpos[step] = (unsigned short)p;
                G.s_dead[step] = (unsigned short)k;
            }

            {
                u64 sc = DEADPK;
                if (validA && nxtA != 0xFFFF) {
                    double a0d = (jjA == p) ? nrm : impA;
                    if (a0d < 1e300) {
                        double a1d = (nxtA == p) ? nrm : impNxtA;
                        sc = pack_score(a0d + a1d, jjA);
                    }
                }
                sc = lexmin_wave_u64(sc);
                if (chp < 64)       { if (lane == chp)      cv0 = sc; }
                else if (chp < 128) { if (lane == chp - 64) cv1 = sc; }
                else                { if (lane == 0)        cv2 = sc; }
            }
            if (csB >= 0) {
                int jj = csB * 64 + lane;
                u64 sc = DEADPK;
                if (jj < S_TOT && jj != k) {
                    int nxt = (int)G.s_next[jj];
                    if (nxt != 0xFFFF) {
                        double a0d = s_imp[jj];
                        if (a0d < 1e300) sc = pack_score(a0d + s_imp[nxt], jj);
                    }
                }
                sc = lexmin_wave_u64(sc);
                if (csB < 64)       { if (lane == csB)      cv0 = sc; }
                else if (csB < 128) { if (lane == csB - 64) cv1 = sc; }
                else                { if (lane == 0)        cv2 = sc; }
            }
            if (csC >= 0) {
                int jj = csC * 64 + lane;
                u64 sc = DEADPK;
                if (jj < S_TOT && jj != k) {
                    int nxt = (int)G.s_next[jj];
                    if (nxt != 0xFFFF) {
                        double a0d = s_imp[jj];
                        if (a0d < 1e300) sc = pack_score(a0d + s_imp[nxt], jj);
                    }
                }
                sc = lexmin_wave_u64(sc);
                if (csC < 64)       { if (lane == csC)      cv0 = sc; }
                else if (csC < 128) { if (lane == csC - 64) cv1 = sc; }
                else                { if (lane == 0)        cv2 = sc; }
            }
        }
    }
    __syncthreads();

    // identity LUT + compacted index map (to global idx_out)
    for (int j = t; j < S_TOT; j += 256) G.s_next[j] = 0xFFFF;
    __syncthreads();
    if (t == 0)
        for (int m2 = 0; m2 < NMERGE; ++m2) G.s_next[G.s_mpos[m2]] = (unsigned short)m2;
    __syncthreads();
    for (int j = t; j < S_TOT; j += 256) {
        if (s_imp[j] < 1e300) {
            int r = j;
            #pragma unroll
            for (int m2 = 0; m2 < NMERGE; ++m2) r -= (G.s_dead[m2] < j) ? 1 : 0;
            unsigned short lut = G.s_next[j];
            idx_out[b * S_BANK + r] = (lut != 0xFFFF) ? (unsigned short)(S_TOT + lut)
                                                      : (unsigned short)j;
        }
    }
    __syncthreads();

    // full-batch gather (rare path; correctness over speed)
    for (int w = t; w < S_BANK * (D / 4); w += 256) {
        int r = w >> 7, c = w & 127;
        int src = idx_out[b * S_BANK + r];
        vfloat4 v;
        if (src < S_TOT) {
            const vfloat4* sp = (const vfloat4*)slot_gptr(src, b, bank, refresh);
            v = sp[c];
        } else {
            const vfloat4* sp = (const vfloat4*)&G.s_mvec[src - S_TOT][0];
            v = sp[c];
        }
        __builtin_nontemporal_store(v, &out[((size_t)b * S_BANK + r) * (D / 4) + c]);
    }
}

// ------------------------------------------------------------------------------
extern "C" void kernel_launch(void* const* d_in, const int* in_sizes, int n_in,
                              void* d_out, int out_size, void* d_ws, size_t ws_size,
                              hipStream_t stream) {
    const float* bank    = (const float*)d_in[0];
    const float* refresh = (const float*)d_in[1];

    double*         norms  = (double*)d_ws;
    u64*            c_pk_g = (u64*)((char*)d_ws + (size_t)B_DIM * S_TOT * sizeof(double));
    int*            flag_g = (int*)((char*)c_pk_g + (size_t)B_DIM * NCH * sizeof(u64));
    unsigned short* idx    = (unsigned short*)((char*)flag_g + 64 * sizeof(int));
    vfloat4*        out    = (vfloat4*)d_out;

    norms_kernel<<<(B_DIM * S_TOT) / 4, 256, 0, stream>>>(bank, refresh, norms);
    chunkmin_kernel<<<(B_DIM * NCH * 64 + 255) / 256, 256, 0, stream>>>(norms, c_pk_g);
    fused_kernel<<<16 + NBULK, 256, 0, stream>>>(bank, refresh, norms, c_pk_g, flag_g, out);
    fallback_kernel<<<B_DIM, 256, 0, stream>>>(bank, refresh, norms, c_pk_g, flag_g, idx, out);
}